// Round 7
// baseline (899.897 us; speedup 1.0000x reference)
//
#include <hip/hip_runtime.h>
#include <cstddef>

#define EDIM 512
#define KDIM 768
#define NB 64
#define NV 196
#define NT 64
#define MROWS_V (NB * NV) /* 12544 */
#define MROWS_T (NB * NT) /* 4096  */

typedef __attribute__((ext_vector_type(8))) short bf16x8;
typedef __attribute__((ext_vector_type(4))) float f32x4;

static __device__ inline unsigned short f2bf(float f) {  // round-to-nearest-even
  unsigned u = __float_as_uint(f);
  unsigned r = (u + 0x7fff + ((u >> 16) & 1)) >> 16;
  return (unsigned short)r;
}
static __device__ inline float bf2f(short s) {
  return __uint_as_float(((unsigned)(unsigned short)s) << 16);
}

// async global->LDS, 16B per lane; LDS dest = wave-uniform base + lane*16
static __device__ __forceinline__ void gload16(const void* g, void* l) {
  __builtin_amdgcn_global_load_lds(
      (const __attribute__((address_space(1))) void*)g,
      (__attribute__((address_space(3))) void*)l, 16, 0, 0);
}

// ---------------- fp32 -> bf16 elementwise (8 elems/thread) ----------------
__global__ void k_tobf16(const float* __restrict__ in, short* __restrict__ outp, int n8) {
  int i = blockIdx.x * 256 + threadIdx.x;
  if (i >= n8) return;
  float4 a = *(const float4*)(in + (size_t)i * 8);
  float4 b = *(const float4*)(in + (size_t)i * 8 + 4);
  bf16x8 v;
  v[0] = (short)f2bf(a.x); v[1] = (short)f2bf(a.y);
  v[2] = (short)f2bf(a.z); v[3] = (short)f2bf(a.w);
  v[4] = (short)f2bf(b.x); v[5] = (short)f2bf(b.y);
  v[6] = (short)f2bf(b.z); v[7] = (short)f2bf(b.w);
  *(bf16x8*)(outp + (size_t)i * 8) = v;
}

// ---------------- transpose W [768x512] fp32 -> WT [512x768] bf16 ----------------
__global__ void k_transpose_bf(const float* __restrict__ W0, const float* __restrict__ W1,
                               short* __restrict__ T0, short* __restrict__ T1) {
  __shared__ float tile[32][33];
  const float* W = blockIdx.z ? W1 : W0;
  short*       T = blockIdx.z ? T1 : T0;
  int k0 = blockIdx.x * 32;
  int n0 = blockIdx.y * 32;
  int tx = threadIdx.x, ty = threadIdx.y;
  for (int i = ty; i < 32; i += 8)
    tile[i][tx] = W[(size_t)(k0 + i) * EDIM + n0 + tx];
  __syncthreads();
  for (int i = ty; i < 32; i += 8)
    T[(size_t)(n0 + i) * KDIM + k0 + tx] = (short)f2bf(tile[tx][i]);
}

// ---------- MFMA projection: Mbf[r,n] = bf16(sum_k X[r,k]*WT[n,k] + bias[n]) ----
// dbuf + prefetch: stage(kc+1) issued before compute(kc); one barrier/kc.
__global__ __launch_bounds__(256, 4) void k_proj_mfma(
    const short* __restrict__ Xbf, const short* __restrict__ WT,
    const float* __restrict__ bias, short* __restrict__ Mbf) {
  __shared__ short As[2][128 * 32];   // linear 64B rows
  __shared__ short Bs[2][64 * 32];
  int n0 = blockIdx.x * 64;
  int r0 = blockIdx.y * 128;
  int tid = threadIdx.x;
  int w = tid >> 6, lane = tid & 63, lg = lane >> 4, li = lane & 15;
  int swz = li & 3;

  auto stage = [&](int bb, int kc) {
    int k0 = kc << 5;
    short* Ad = &As[bb][0];
    short* Bd = &Bs[bb][0];
#pragma unroll
    for (int uu = 0; uu < 2; ++uu) {   // A: 128 rows x 4 segs = 512 units
      int u0 = uu * 256 + w * 64;
      int u = u0 + lane;
      int row = u >> 2, seg = u & 3;
      int ss = seg ^ (row & 3);
      gload16(Xbf + (size_t)(r0 + row) * KDIM + k0 + ss * 8, Ad + u0 * 8);
    }
    {                                   // B: 64 rows x 4 segs = 256 units
      int u0 = w * 64;
      int u = u0 + lane;
      int row = u >> 2, seg = u & 3;
      int ss = seg ^ (row & 3);
      gload16(WT + (size_t)(n0 + row) * KDIM + k0 + ss * 8, Bd + u0 * 8);
    }
  };

  f32x4 acc[2][4];
#pragma unroll
  for (int i = 0; i < 2; ++i)
#pragma unroll
    for (int j = 0; j < 4; ++j) acc[i][j] = (f32x4){0.f, 0.f, 0.f, 0.f};

  stage(0, 0);
  __syncthreads();
  int cur = 0;
  for (int kc = 0; kc < KDIM / 32; ++kc) {
    if (kc < KDIM / 32 - 1) stage(cur ^ 1, kc + 1);
    const short* Ab = &As[cur][0];
    const short* Bb = &Bs[cur][0];
    bf16x8 bfr[4];
#pragma unroll
    for (int j = 0; j < 4; ++j)
      bfr[j] = *(const bf16x8*)(Bb + (j * 16 + li) * 32 + (lg ^ swz) * 8);
#pragma unroll
    for (int i = 0; i < 2; ++i) {
      bf16x8 afr = *(const bf16x8*)(Ab + ((w * 2 + i) * 16 + li) * 32 + (lg ^ swz) * 8);
#pragma unroll
      for (int j = 0; j < 4; ++j)
        acc[i][j] = __builtin_amdgcn_mfma_f32_16x16x32_bf16(afr, bfr[j], acc[i][j], 0, 0, 0);
    }
    __syncthreads();
    cur ^= 1;
  }
#pragma unroll
  for (int j = 0; j < 4; ++j) {
    int n = n0 + j * 16 + li;
    float bb = bias[n];
#pragma unroll
    for (int i = 0; i < 2; ++i)
#pragma unroll
      for (int reg = 0; reg < 4; ++reg)
        Mbf[(size_t)(r0 + (w * 2 + i) * 16 + lg * 4 + reg) * EDIM + n] =
            (short)f2bf(acc[i][j][reg] + bb);
  }
}

// ------- per-row (bf16 in place): fc scalar (pre-norm) + l2 normalize -------
__global__ void k_normfc(short* __restrict__ Mbf, const float* __restrict__ fcw,
                         const float* __restrict__ fcb, float* __restrict__ wout,
                         int nrows) {
  int row = blockIdx.x * 4 + (threadIdx.x >> 6);
  int lane = threadIdx.x & 63;
  if (row >= nrows) return;
  short* p = Mbf + (size_t)row * EDIM + lane * 8;
  bf16x8 v = *(bf16x8*)p;
  float4 w0 = *(const float4*)(fcw + lane * 8);
  float4 w1 = *(const float4*)(fcw + lane * 8 + 4);
  float a[8];
#pragma unroll
  for (int j = 0; j < 8; ++j) a[j] = bf2f(v[j]);
  float dot = a[0] * w0.x + a[1] * w0.y + a[2] * w0.z + a[3] * w0.w +
              a[4] * w1.x + a[5] * w1.y + a[6] * w1.z + a[7] * w1.w;
  float ss = a[0] * a[0] + a[1] * a[1] + a[2] * a[2] + a[3] * a[3] +
             a[4] * a[4] + a[5] * a[5] + a[6] * a[6] + a[7] * a[7];
  for (int s = 1; s < 64; s <<= 1) {
    dot += __shfl_xor(dot, s);
    ss += __shfl_xor(ss, s);
  }
  float inv = 1.0f / fmaxf(sqrtf(ss), 1e-12f);
#pragma unroll
  for (int j = 0; j < 8; ++j) v[j] = (short)f2bf(a[j] * inv);
  *(bf16x8*)p = v;
  if (lane == 0) wout[row] = dot + fcb[0];
}

// ---------------- softmax: blocks 0..63 vw rows (196), 64..127 tw rows (64, masked) ----
__global__ void k_softmax(float* __restrict__ vwf, float* __restrict__ twf,
                          const int* __restrict__ tlen) {
  __shared__ float red[8];
  int tid = threadIdx.x;
  if (blockIdx.x < 64) {
    int b = blockIdx.x;
    float x = (tid < NV) ? vwf[b * NV + tid] : -1e30f;
    float m = x;
    for (int s = 1; s < 64; s <<= 1) m = fmaxf(m, __shfl_xor(m, s));
    if ((tid & 63) == 0) red[tid >> 6] = m;
    __syncthreads();
    m = fmaxf(fmaxf(red[0], red[1]), fmaxf(red[2], red[3]));
    float e = (tid < NV) ? expf(x - m) : 0.0f;
    float s = e;
    for (int st = 1; st < 64; st <<= 1) s += __shfl_xor(s, st);
    if ((tid & 63) == 0) red[4 + (tid >> 6)] = s;
    __syncthreads();
    s = red[4] + red[5] + red[6] + red[7];
    if (tid < NV) vwf[b * NV + tid] = e / s;
  } else {
    int b = blockIdx.x - 64;
    if (tid < 64) {
      int len = tlen[b];
      float x = twf[b * NT + tid];
      bool valid = tid < len;
      float xv = valid ? x : -1e30f;
      float m = xv;
      for (int s = 1; s < 64; s <<= 1) m = fmaxf(m, __shfl_xor(m, s));
      float e = valid ? expf(x - m) : 0.0f;
      float s = e;
      for (int st = 1; st < 64; st <<= 1) s += __shfl_xor(s, st);
      twf[b * NT + tid] = e / s;
    }
  }
}

// ---------------- MFMA sim kernel: one block per (b, q-pair), XCD-chunked -----------
// Single-buffered 28.7KB LDS -> 4 blocks/CU (TLP covers barrier drains, m114-style).
__global__ __launch_bounds__(256, 4) void k_sim(
    const short* __restrict__ ve_bf, const short* __restrict__ te_bf,
    const float* __restrict__ vwf, const float* __restrict__ twf,
    float* __restrict__ out, int* __restrict__ gMT, int* __restrict__ gMV) {
  __shared__ short As[256 * 32];   // linear, 64B row stride
  __shared__ short Bs[128 * 32];
  __shared__ float colv[4][128];
  __shared__ int   coli[4][128];
  __shared__ float redp0[4], redp1[4];
  int n = blockIdx.x;
  int xcd = n & 7, idx = n >> 3;
  int b = xcd * 8 + (idx & 7);       // b-fastest within XCD chunk
  int qq = idx >> 3;                 // 0..31
  int tid = threadIdx.x;
  int w = tid >> 6, lane = tid & 63, lg = lane >> 4, li = lane & 15;
  const short* Abf = ve_bf + (size_t)b * NV * EDIM;
  const short* Bbf = te_bf + (size_t)qq * 128 * EDIM;
  int swz = li & 3;

  f32x4 acc[4][8];
#pragma unroll
  for (int i = 0; i < 4; ++i)
#pragma unroll
    for (int j = 0; j < 8; ++j) acc[i][j] = (f32x4){0.f, 0.f, 0.f, 0.f};

  for (int kc = 0; kc < 16; ++kc) {
    int k0 = kc << 5;
    __syncthreads();   // prior kc's frag reads done before overwrite
#pragma unroll
    for (int uu = 0; uu < 2; ++uu) {   // B: 128 rows x 4 segs = 512 units
      int u0 = uu * 256 + w * 64;
      int u = u0 + lane;
      int row = u >> 2, seg = u & 3;
      int ss = seg ^ (row & 3);
      gload16(Bbf + (size_t)row * EDIM + k0 + ss * 8, Bs + u0 * 8);
    }
#pragma unroll
    for (int uu = 0; uu < 4; ++uu) {   // A: 784 valid units (rows clamped past 195)
      int u0 = uu * 256 + w * 64;
      if (u0 < NV * 4) {
        int u = u0 + lane;
        int row = u >> 2;
        if (row > NV - 1) row = NV - 1;
        int seg = u & 3;
        int ss = seg ^ (row & 3);
        gload16(Abf + (size_t)row * EDIM + k0 + ss * 8, As + u0 * 8);
      }
    }
    __syncthreads();   // vmcnt(0) drain -> tile visible
    bf16x8 bfr[8];
#pragma unroll
    for (int j = 0; j < 8; ++j)
      bfr[j] = *(const bf16x8*)(Bs + (j * 16 + li) * 32 + (lg ^ swz) * 8);
#pragma unroll
    for (int i = 0; i < 4; ++i) {
      bf16x8 afr = *(const bf16x8*)(As + ((w * 4 + i) * 16 + li) * 32 + (lg ^ swz) * 8);
#pragma unroll
      for (int j = 0; j < 8; ++j)
        acc[i][j] = __builtin_amdgcn_mfma_f32_16x16x32_bf16(afr, bfr[j], acc[i][j], 0, 0, 0);
    }
  }

  bool diag0 = (b == 2 * qq), diag1 = (b == 2 * qq + 1);
  // ---- row (over t) max+argmax per q; C layout: row=tile*16+lg*4+reg, col=j*16+li
  float ip0 = 0.f, ip1 = 0.f;
#pragma unroll
  for (int i = 0; i < 4; ++i) {
#pragma unroll
    for (int reg = 0; reg < 4; ++reg) {
      int v = (w * 4 + i) * 16 + lg * 4 + reg;
      float m = acc[i][0][reg];
      int ti = li;
#pragma unroll
      for (int j = 1; j < 4; ++j) {
        float vv = acc[i][j][reg];
        int t = j * 16 + li;
        if (vv > m) { m = vv; ti = t; }   // t ascending -> first-index kept
      }
      for (int d = 1; d < 16; d <<= 1) {  // within li-group (same row)
        float om = __shfl_xor(m, d);
        int oi = __shfl_xor(ti, d);
        if (om > m || (om == m && oi < ti)) { m = om; ti = oi; }
      }
      float m1 = acc[i][4][reg];
      int ti1 = li;
#pragma unroll
      for (int j = 5; j < 8; ++j) {
        float vv = acc[i][j][reg];
        int t = (j - 4) * 16 + li;
        if (vv > m1) { m1 = vv; ti1 = t; }
      }
      for (int d = 1; d < 16; d <<= 1) {
        float om = __shfl_xor(m1, d);
        int oi = __shfl_xor(ti1, d);
        if (om > m1 || (om == m1 && oi < ti1)) { m1 = om; ti1 = oi; }
      }
      if (li == 0 && v < NV) {
        float wv = vwf[b * NV + v];
        ip0 += wv * m;
        ip1 += wv * m1;
        if (diag0) gMT[b * NV + v] = b * NT + ti;
        if (diag1) gMT[b * NV + v] = b * NT + ti1;
      }
    }
  }
  for (int d = 1; d < 64; d <<= 1) {
    ip0 += __shfl_xor(ip0, d);
    ip1 += __shfl_xor(ip1, d);
  }
  if (lane == 0) { redp0[w] = ip0; redp1[w] = ip1; }
  // ---- col (over v) max+argmax for this wave's rows, all 128 cols
  float cm[8]; int cv[8];
#pragma unroll
  for (int j = 0; j < 8; ++j) { cm[j] = -3.0e38f; cv[j] = 0; }
#pragma unroll
  for (int i = 0; i < 4; ++i)
#pragma unroll
    for (int reg = 0; reg < 4; ++reg) {
      int v = (w * 4 + i) * 16 + lg * 4 + reg;
      bool ok = v < NV;
#pragma unroll
      for (int j = 0; j < 8; ++j) {
        float s = ok ? acc[i][j][reg] : -3.0e38f;
        if (s > cm[j]) { cm[j] = s; cv[j] = v; }  // v ascending per lane
      }
    }
#pragma unroll
  for (int j = 0; j < 8; ++j) {
    for (int d = 16; d < 64; d <<= 1) {   // mixes lg groups (same col)
      float om = __shfl_xor(cm[j], d);
      int ov = __shfl_xor(cv[j], d);
      if (om > cm[j] || (om == cm[j] && ov < cv[j])) { cm[j] = om; cv[j] = ov; }
    }
    if (lg == 0) { colv[w][j * 16 + li] = cm[j]; coli[w][j * 16 + li] = cv[j]; }
  }
  __syncthreads();
  if (tid < 128) {
    int t = tid;
    float m = colv[0][t];
    int bi = coli[0][t];
#pragma unroll
    for (int w2 = 1; w2 < 4; ++w2) {
      float om = colv[w2][t];
      int ov = coli[w2][t];
      if (om > m || (om == m && ov < bi)) { m = om; bi = ov; }
    }
    int q = 2 * qq + (t >> 6);
    int tt = t & 63;
    if (b == q) gMV[b * NT + tt] = b * NV + bi;
    float p = twf[q * NT + tt] * m;
    for (int d = 1; d < 64; d <<= 1) p += __shfl_xor(p, d);
    if ((tid & 63) == 0) out[4096 + b * 64 + q] = p;
  }
  if (tid == 0) {
    out[b * 64 + 2 * qq]     = redp0[0] + redp0[1] + redp0[2] + redp0[3];
    out[b * 64 + 2 * qq + 1] = redp1[0] + redp1[1] + redp1[2] + redp1[3];
  }
}

// ---------------- column stats from bf16 (sum, sumsq, weighted sum) ------
__global__ void k_stats(const short* __restrict__ ve_bf, const short* __restrict__ te_bf,
                        const int* __restrict__ gMT, const int* __restrict__ gMV,
                        const float* __restrict__ vwf, const float* __restrict__ twf,
                        float* __restrict__ statPart) {
  int stripe = blockIdx.x, chunk = blockIdx.y, m = blockIdx.z;
  int R = (m < 2) ? MROWS_T : MROWS_V;
  int nchunk = (R + 1023) >> 10;
  if (chunk >= nchunk) return;
  const short* M; const int* g; const float* w;
  if (m == 0)      { M = te_bf; g = 0;   w = twf; }
  else if (m == 1) { M = ve_bf; g = gMV; w = twf; }
  else if (m == 2) { M = ve_bf; g = 0;   w = vwf; }
  else             { M = te_bf; g = gMT; w = vwf; }
  int col = stripe * 64 + (threadIdx.x & 63);
  int rg = threadIdx.x >> 6;
  int r0 = chunk << 10;
  int r1 = min(r0 + 1024, R);
  float s = 0, ss = 0, sw = 0;
  for (int r = r0 + rg; r < r1; r += 4) {
    int row = g ? g[r] : r;
    float x = bf2f(M[(size_t)row * EDIM + col]);
    s += x; ss += x * x; sw += w[r] * x;
  }
  __shared__ float red[3][256];
  red[0][threadIdx.x] = s; red[1][threadIdx.x] = ss; red[2][threadIdx.x] = sw;
  __syncthreads();
  if (threadIdx.x < 64) {
    int c = threadIdx.x;
    float S  = red[0][c] + red[0][c + 64] + red[0][c + 128] + red[0][c + 192];
    float SS = red[1][c] + red[1][c + 64] + red[1][c + 128] + red[1][c + 192];
    float SW = red[2][c] + red[2][c + 64] + red[2][c + 128] + red[2][c + 192];
    size_t idx = ((size_t)(m * 13 + chunk) * 512 + stripe * 64 + c) * 3;
    statPart[idx] = S; statPart[idx + 1] = SS; statPart[idx + 2] = SW;
  }
}

__global__ void k_statfin(const float* __restrict__ statPart, float* __restrict__ stats) {
  int m = blockIdx.x, c = threadIdx.x;
  int R = (m < 2) ? MROWS_T : MROWS_V;
  int nchunk = (R + 1023) >> 10;
  float s = 0, ss = 0, sw = 0;
  for (int ch = 0; ch < nchunk; ch++) {
    size_t idx = ((size_t)(m * 13 + ch) * 512 + c) * 3;
    s += statPart[idx]; ss += statPart[idx + 1]; sw += statPart[idx + 2];
  }
  float mean = s / R;
  float var = (ss - s * mean) / (R - 1);  // ddof=1
  float rstd = 1.0f / sqrtf(var);
  stats[(m * 3 + 0) * 512 + c] = mean;
  stats[(m * 3 + 1) * 512 + c] = rstd;
  stats[(m * 3 + 2) * 512 + c] = sw;
}

// ------- transpose-materialize a-contiguous bf16 operands (w and gathers folded) ----
__global__ void k_materialize(const short* __restrict__ ve_bf, const short* __restrict__ te_bf,
                              const int* __restrict__ gMT, const int* __restrict__ gMV,
                              const float* __restrict__ vwf, const float* __restrict__ twf,
                              short* __restrict__ tTw, short* __restrict__ mvT,
                              short* __restrict__ vTw, short* __restrict__ mtT) {
  int z = blockIdx.z;
  int at = blockIdx.x, ct = blockIdx.y;
  int K = (z == 2 || z == 3) ? MROWS_V : MROWS_T;
  if (at * 64 >= K) return;
  const short* src; const int* g = 0; const float* w = 0; short* dst;
  if (z == 0)      { src = te_bf; w = twf; dst = tTw; }
  else if (z == 1) { src = ve_bf; g = gMV; dst = mvT; }
  else if (z == 2) { src = ve_bf; w = vwf; dst = vTw; }
  else             { src = te_bf; g = gMT; dst = mtT; }
  __shared__ float tile[64][67];
  int tid = threadIdx.x;
  for (int u = tid; u < 512; u += 256) {
    int a = u >> 3, cseg = (u & 7) << 3;
    int ga = at * 64 + a;
    int row = g ? g[ga] : ga;
    bf16x8 vv = *(const bf16x8*)(src + (size_t)row * EDIM + ct * 64 + cseg);
    float wa = w ? w[ga] : 1.0f;
#pragma unroll
    for (int j = 0; j < 8; j++) tile[a][cseg + j] = wa * bf2f(vv[j]);
  }
  __syncthreads();
  for (int u = tid; u < 512; u += 256) {
    int c = u >> 3, aseg = (u & 7) << 3;
    bf16x8 ov;
#pragma unroll
    for (int j = 0; j < 8; j++) ov[j] = (short)f2bf(tile[aseg + j][c]);
    *(bf16x8*)(dst + (size_t)(ct * 64 + c) * K + at * 64 + aseg) = ov;
  }
}

// ------- MFMA weighted GEMM: Spart[z][c][d] = sum_a AT[c][a]*BT[d][a] (split-K 4) ----
__global__ __launch_bounds__(256, 4) void k_wgemm2(
    const short* __restrict__ tTw, const short* __restrict__ mvT,
    const short* __restrict__ vTw, const short* __restrict__ mtT,
    float* __restrict__ Spart) {
  __shared__ short As[128 * 44];
  __shared__ short Bs[64 * 44];
  int c0 = blockIdx.x * 128, d0 = blockIdx.y * 64;
  int z = blockIdx.z;
  int which = z >> 2, slice = z & 3;
  const short* A = which ? vTw : tTw;
  const short* B = which ? mtT : mvT;
  int K = which ? MROWS_V : MROWS_T;
  int nch = (K >> 2) >> 5;             // 98 or 32 chunks of 32
  int a0 = slice * (K >> 2);
  int tid = threadIdx.x;
  int w = tid >> 6, lane = tid & 63, lg = lane >> 4, li = lane & 15;
  f32x4 acc[2][4];
#pragma unroll
  for (int i = 0; i < 2; ++i)
#pragma unroll
    for (int j = 0; j < 4; ++j) acc[i][j] = (f32x4){0.f, 0.f, 0.f, 0.f};
  for (int ch = 0; ch < nch; ++ch) {
    int ak = a0 + (ch << 5);
    __syncthreads();
#pragma unroll
    for (int uu = 0; uu < 2; ++uu) {
      int u = tid + uu * 256;
      int r = u >> 2, seg = (u & 3) << 3;
      *(bf16x8*)(As + r * 44 + seg) = *(const bf16x8*)(A + (size_t)(c0 + r) * K + ak + seg);
    }
    {
      int t = tid >> 2, seg = (tid & 3) << 3;
      *(bf16x8*)(Bs + t * 44 + seg) = *(const bf16x8*)(B + (size_t)(d0 + t) * K + ak + seg);
    }
    __syncthreads();
    bf16x8 bfr[4];
#pragma unroll
    for (int j = 0; j < 4; ++j)
      bfr[j] = *(const bf16x8*)(Bs + (j * 16 + li) * 44 + lg * 8);
#pragma unroll
    for (int i = 0; i < 2; ++i) {
      bf16x8 afr = *(const bf16x8*)(As + ((w * 2 + i) * 16 + li) * 44 + lg * 8);
#pragma unroll
      for (int j = 0; j < 4; ++j)
        acc[i][j] = __builtin_amdgcn_mfma_f32_16x16x32_bf16(afr, bfr[j], acc[i][j], 0, 0, 0);
    }
  }
  float* outp = Spart + (size_t)z * 512 * 512;
#pragma unroll
  for (int j = 0; j < 4; ++j) {
    int d = d0 + j * 16 + li;
#pragma unroll
    for (int i = 0; i < 2; ++i)
#pragma unroll
      for (int reg = 0; reg < 4; ++reg)
        outp[(size_t)(c0 + (w * 2 + i) * 16 + lg * 4 + reg) * 512 + d] = acc[i][j][reg];
  }
}

// ---------------- assemble c = (c1+c2)/2 from closed form; loss partials ----------
__global__ void k_assemble(const float* __restrict__ Spart, const float* __restrict__ stats,
                           float* __restrict__ lossPart) {
  int c = blockIdx.x, tid = threadIdx.x;
  float muT = stats[0 * 512 + c], rsT = stats[1 * 512 + c], swT = stats[2 * 512 + c];
  float muV = stats[6 * 512 + c], rsV = stats[7 * 512 + c], swV = stats[8 * 512 + c];
  const float W = 64.0f, invB = 1.0f / 64.0f;
  float on = 0, off = 0;
  for (int d = tid; d < 512; d += 256) {
    float s1 = 0, s2 = 0;
    for (int sl = 0; sl < 4; sl++) {
      s1 += Spart[((size_t)sl * 512 + c) * 512 + d];
      s2 += Spart[((size_t)(4 + sl) * 512 + c) * 512 + d];
    }
    float muMV = stats[3 * 512 + d], rsMV = stats[4 * 512 + d], swMV = stats[5 * 512 + d];
    float muMT = stats[9 * 512 + d], rsMT = stats[10 * 512 + d], swMT = stats[11 * 512 + d];
    float c1 = (s1 - muT * swMV - muMV * swT + muT * muMV * W) * rsT * rsMV * invB;
    float c2 = (s2 - muV * swMT - muMT * swV + muV * muMT * W) * rsV * rsMT * invB;
    float cc = 0.5f * (c1 + c2);
    if (d == c) { float dd = cc - 1.0f; on += dd * dd; }
    else off += cc * cc;
  }
  __shared__ float r1[4], r2[4];
  for (int s = 1; s < 64; s <<= 1) { on += __shfl_xor(on, s); off += __shfl_xor(off, s); }
  if ((tid & 63) == 0) { r1[tid >> 6] = on; r2[tid >> 6] = off; }
  __syncthreads();
  if (tid == 0) {
    lossPart[c * 2] = r1[0] + r1[1] + r1[2] + r1[3];
    lossPart[c * 2 + 1] = r2[0] + r2[1] + r2[2] + r2[3];
  }
}

__global__ void k_loss(const float* __restrict__ lossPart, float* __restrict__ out) {
  int tid = threadIdx.x;
  float on = 0, off = 0;
  for (int i = tid; i < 512; i += 256) { on += lossPart[2 * i]; off += lossPart[2 * i + 1]; }
  __shared__ float r1[4], r2[4];
  for (int s = 1; s < 64; s <<= 1) { on += __shfl_xor(on, s); off += __shfl_xor(off, s); }
  if ((tid & 63) == 0) { r1[tid >> 6] = on; r2[tid >> 6] = off; }
  __syncthreads();
  if (tid == 0)
    out[8192] = 0.1f * ((r1[0] + r1[1] + r1[2] + r1[3]) +
                        0.06f * (r2[0] + r2[1] + r2[2] + r2[3]));
}

extern "C" void kernel_launch(void* const* d_in, const int* in_sizes, int n_in,
                              void* d_out, int out_size, void* d_ws, size_t ws_size,
                              hipStream_t stream) {
  (void)in_sizes; (void)n_in; (void)out_size; (void)ws_size;
  const float* v_tok  = (const float*)d_in[1];
  const float* t_tok  = (const float*)d_in[3];
  const float* Wv_tok = (const float*)d_in[8];
  const float* Wt_tok = (const float*)d_in[10];
  const float* bv_tok = (const float*)d_in[9];
  const float* bt_tok = (const float*)d_in[11];
  const float* wv_fc  = (const float*)d_in[12];
  const float* bv_fc  = (const float*)d_in[13];
  const float* wt_fc  = (const float*)d_in[14];
  const float* bt_fc  = (const float*)d_in[15];
  const int*   tlen   = (const int*)d_in[16];
  float* out = (float*)d_out;

  char* wsb = (char*)d_ws;
  // --- P [0, 27,131,904): phase1 {v_tok_bf, t_tok_bf, WvT, WtT} (dead after proj);
  //     phase2 (materialize on): {tTw, mvT, vTw} (21,233,664 B)
  short* v_tok_bf = (short*)wsb;                       // 9,633,792 sh
  short* t_tok_bf = v_tok_bf + (size_t)9633792;        // 3,145,728 sh
  short* WvT      = t_tok_bf + (size_t)3145728;        //   393,216 sh
  short* WtT      = WvT + (size_t)393216;              //   393,216 sh
  short* tTw = (short*)wsb;                            // 512*4096 (alias, phase2)
  short* mvT = tTw + (size_t)2097152;                  // 512*4096
  short* vTw = mvT + (size_t)2097152;                  // 512*12544
  // --- Q [27,131,904, 44,171,264): phase-a {ve_bf, te_bf}; phase-b Spart
  short* ve_bf = (short*)(wsb + 27131904);             // 6,422,528 sh
  short* te_bf = ve_bf + (size_t)6422528;              // 2,097,152 sh
  float* Spart = (float*)(wsb + 27131904);             // 8*512*512 f (alias, phase-b)
  // --- mtT [44,171,264, 57,016,320)
  short* mtT = (short*)(wsb + 44171264);               // 512*12544
  // --- smalls at 57,016,320
  float* vwf = (float*)(wsb + 57016320);               // 12544
  float* twf = vwf + 12544;                            // 4096
  int* gMT = (int*)(twf + 4096);                       // 12544
  int* gMV = gMT + 12544;                              // 4096
  float* statPart = (float*)(gMV + 4096);              // 4*13*512*3
  float* stats = statPart + 79872;                     // 12*512
  float* lossPart = stats + 6144;                      // 1024

  k_tobf16<<<4704, 256, 0, stream>>>(v_tok, v_tok_bf, 1204224);
  k_tobf16<<<1536, 256, 0, stream>>>(t_tok, t_tok_bf, 393216);
  k_transpose_bf<<<dim3(24, 16, 2), dim3(32, 8), 0, stream>>>(Wv_tok, Wt_tok, WvT, WtT);
  k_proj_mfma<<<dim3(8, 98), 256, 0, stream>>>(v_tok_bf, WvT, bv_tok, ve_bf);
  k_proj_mfma<<<dim3(8, 32), 256, 0, stream>>>(t_tok_bf, WtT, bt_tok, te_bf);
  k_normfc<<<3136, 256, 0, stream>>>(ve_bf, wv_fc, bv_fc, vwf, 12544);
  k_normfc<<<1024, 256, 0, stream>>>(te_bf, wt_fc, bt_fc, twf, 4096);
  k_softmax<<<128, 256, 0, stream>>>(vwf, twf, tlen);
  k_sim<<<2048, 256, 0, stream>>>(ve_bf, te_bf, vwf, twf, out, gMT, gMV);
  k_stats<<<dim3(8, 13, 4), 256, 0, stream>>>(ve_bf, te_bf, gMT, gMV, vwf, twf, statPart);
  k_statfin<<<4, 512, 0, stream>>>(statPart, stats);
  k_materialize<<<dim3(196, 8, 4), 256, 0, stream>>>(ve_bf, te_bf, gMT, gMV, vwf, twf,
                                                     tTw, mvT, vTw, mtT);
  k_wgemm2<<<dim3(4, 8, 8), 256, 0, stream>>>(tTw, mvT, vTw, mtT, Spart);
  k_assemble<<<512, 256, 0, stream>>>(Spart, stats, lossPart);
  k_loss<<<1, 256, 0, stream>>>(lossPart, out);
}

// Round 8
// 361.093 us; speedup vs baseline: 2.4921x; 2.4921x over previous
//
#include <hip/hip_runtime.h>
#include <cstddef>

#define EDIM 512
#define KDIM 768
#define NB 64
#define NV 196
#define NT 64
#define MROWS_V (NB * NV) /* 12544 */
#define MROWS_T (NB * NT) /* 4096  */

typedef __attribute__((ext_vector_type(8))) short bf16x8;
typedef __attribute__((ext_vector_type(4))) float f32x4;

static __device__ inline unsigned short f2bf(float f) {  // round-to-nearest-even
  unsigned u = __float_as_uint(f);
  unsigned r = (u + 0x7fff + ((u >> 16) & 1)) >> 16;
  return (unsigned short)r;
}
static __device__ inline float bf2f(short s) {
  return __uint_as_float(((unsigned)(unsigned short)s) << 16);
}

// async global->LDS, 16B per lane; LDS dest = wave-uniform base + lane*16
static __device__ __forceinline__ void gload16(const void* g, void* l) {
  __builtin_amdgcn_global_load_lds(
      (const __attribute__((address_space(1))) void*)g,
      (__attribute__((address_space(3))) void*)l, 16, 0, 0);
}

// ---------------- fp32 -> bf16 elementwise (8 elems/thread) ----------------
__global__ void k_tobf16(const float* __restrict__ in, short* __restrict__ outp, int n8) {
  int i = blockIdx.x * 256 + threadIdx.x;
  if (i >= n8) return;
  float4 a = *(const float4*)(in + (size_t)i * 8);
  float4 b = *(const float4*)(in + (size_t)i * 8 + 4);
  bf16x8 v;
  v[0] = (short)f2bf(a.x); v[1] = (short)f2bf(a.y);
  v[2] = (short)f2bf(a.z); v[3] = (short)f2bf(a.w);
  v[4] = (short)f2bf(b.x); v[5] = (short)f2bf(b.y);
  v[6] = (short)f2bf(b.z); v[7] = (short)f2bf(b.w);
  *(bf16x8*)(outp + (size_t)i * 8) = v;
}

// ---------------- transpose W [768x512] fp32 -> WT [512x768] bf16 ----------------
__global__ void k_transpose_bf(const float* __restrict__ W0, const float* __restrict__ W1,
                               short* __restrict__ T0, short* __restrict__ T1) {
  __shared__ float tile[32][33];
  const float* W = blockIdx.z ? W1 : W0;
  short*       T = blockIdx.z ? T1 : T0;
  int k0 = blockIdx.x * 32;
  int n0 = blockIdx.y * 32;
  int tx = threadIdx.x, ty = threadIdx.y;
  for (int i = ty; i < 32; i += 8)
    tile[i][tx] = W[(size_t)(k0 + i) * EDIM + n0 + tx];
  __syncthreads();
  for (int i = ty; i < 32; i += 8)
    T[(size_t)(n0 + i) * KDIM + k0 + tx] = (short)f2bf(tile[tx][i]);
}

// ---------- MFMA projection: Mbf[r,n] = bf16(sum_k X[r,k]*WT[n,k] + bias[n]) ----
// dbuf + counted vmcnt: stage(kc+1) in flight across raw barriers (T3/T4-lite).
// Each wave issues exactly 3 loads/kc -> s_waitcnt vmcnt(3).
__global__ __launch_bounds__(256, 4) void k_proj_mfma(
    const short* __restrict__ Xbf, const short* __restrict__ WT,
    const float* __restrict__ bias, short* __restrict__ Mbf) {
  __shared__ short As[2][128 * 32];   // linear 64B rows
  __shared__ short Bs[2][64 * 32];
  int n0 = blockIdx.x * 64;
  int r0 = blockIdx.y * 128;
  int tid = threadIdx.x;
  int w = tid >> 6, lane = tid & 63, lg = lane >> 4, li = lane & 15;
  int swz = li & 3;

  auto stage = [&](int bb, int kc) {
    int k0 = kc << 5;
    short* Ad = &As[bb][0];
    short* Bd = &Bs[bb][0];
#pragma unroll
    for (int uu = 0; uu < 2; ++uu) {   // A: 128 rows x 4 segs = 512 units
      int u0 = uu * 256 + w * 64;
      int u = u0 + lane;
      int row = u >> 2, seg = u & 3;
      int ss = seg ^ (row & 3);
      gload16(Xbf + (size_t)(r0 + row) * KDIM + k0 + ss * 8, Ad + u0 * 8);
    }
    {                                   // B: 64 rows x 4 segs = 256 units
      int u0 = w * 64;
      int u = u0 + lane;
      int row = u >> 2, seg = u & 3;
      int ss = seg ^ (row & 3);
      gload16(WT + (size_t)(n0 + row) * KDIM + k0 + ss * 8, Bd + u0 * 8);
    }
  };

  f32x4 acc[2][4];
#pragma unroll
  for (int i = 0; i < 2; ++i)
#pragma unroll
    for (int j = 0; j < 4; ++j) acc[i][j] = (f32x4){0.f, 0.f, 0.f, 0.f};

  stage(0, 0);   // 3 loads in flight
  int cur = 0;
  const int NKC = KDIM / 32;  // 24
  for (int kc = 0; kc < NKC; ++kc) {
    __builtin_amdgcn_s_barrier();          // readers of buf[cur^1] (prev iter) done
    if (kc < NKC - 1) {
      stage(cur ^ 1, kc + 1);              // 3 new loads
      asm volatile("s_waitcnt vmcnt(3)" ::: "memory");  // old 3 complete, new in flight
    } else {
      asm volatile("s_waitcnt vmcnt(0)" ::: "memory");
    }
    __builtin_amdgcn_s_barrier();          // buf[cur] visible to all waves
    const short* Ab = &As[cur][0];
    const short* Bb = &Bs[cur][0];
    bf16x8 bfr[4];
#pragma unroll
    for (int j = 0; j < 4; ++j)
      bfr[j] = *(const bf16x8*)(Bb + (j * 16 + li) * 32 + (lg ^ swz) * 8);
#pragma unroll
    for (int i = 0; i < 2; ++i) {
      bf16x8 afr = *(const bf16x8*)(Ab + ((w * 2 + i) * 16 + li) * 32 + (lg ^ swz) * 8);
#pragma unroll
      for (int j = 0; j < 4; ++j)
        acc[i][j] = __builtin_amdgcn_mfma_f32_16x16x32_bf16(afr, bfr[j], acc[i][j], 0, 0, 0);
    }
    cur ^= 1;
  }
#pragma unroll
  for (int j = 0; j < 4; ++j) {
    int n = n0 + j * 16 + li;
    float bb = bias[n];
#pragma unroll
    for (int i = 0; i < 2; ++i)
#pragma unroll
      for (int reg = 0; reg < 4; ++reg)
        Mbf[(size_t)(r0 + (w * 2 + i) * 16 + lg * 4 + reg) * EDIM + n] =
            (short)f2bf(acc[i][j][reg] + bb);
  }
}

// ------- per-row (bf16 in place): fc scalar (pre-norm) + l2 normalize -------
__global__ void k_normfc(short* __restrict__ Mbf, const float* __restrict__ fcw,
                         const float* __restrict__ fcb, float* __restrict__ wout,
                         int nrows) {
  int row = blockIdx.x * 4 + (threadIdx.x >> 6);
  int lane = threadIdx.x & 63;
  if (row >= nrows) return;
  short* p = Mbf + (size_t)row * EDIM + lane * 8;
  bf16x8 v = *(bf16x8*)p;
  float4 w0 = *(const float4*)(fcw + lane * 8);
  float4 w1 = *(const float4*)(fcw + lane * 8 + 4);
  float a[8];
#pragma unroll
  for (int j = 0; j < 8; ++j) a[j] = bf2f(v[j]);
  float dot = a[0] * w0.x + a[1] * w0.y + a[2] * w0.z + a[3] * w0.w +
              a[4] * w1.x + a[5] * w1.y + a[6] * w1.z + a[7] * w1.w;
  float ss = a[0] * a[0] + a[1] * a[1] + a[2] * a[2] + a[3] * a[3] +
             a[4] * a[4] + a[5] * a[5] + a[6] * a[6] + a[7] * a[7];
  for (int s = 1; s < 64; s <<= 1) {
    dot += __shfl_xor(dot, s);
    ss += __shfl_xor(ss, s);
  }
  float inv = 1.0f / fmaxf(sqrtf(ss), 1e-12f);
#pragma unroll
  for (int j = 0; j < 8; ++j) v[j] = (short)f2bf(a[j] * inv);
  *(bf16x8*)p = v;
  if (lane == 0) wout[row] = dot + fcb[0];
}

// ---------------- softmax: blocks 0..63 vw rows (196), 64..127 tw rows (64, masked) ----
__global__ void k_softmax(float* __restrict__ vwf, float* __restrict__ twf,
                          const int* __restrict__ tlen) {
  __shared__ float red[8];
  int tid = threadIdx.x;
  if (blockIdx.x < 64) {
    int b = blockIdx.x;
    float x = (tid < NV) ? vwf[b * NV + tid] : -1e30f;
    float m = x;
    for (int s = 1; s < 64; s <<= 1) m = fmaxf(m, __shfl_xor(m, s));
    if ((tid & 63) == 0) red[tid >> 6] = m;
    __syncthreads();
    m = fmaxf(fmaxf(red[0], red[1]), fmaxf(red[2], red[3]));
    float e = (tid < NV) ? expf(x - m) : 0.0f;
    float s = e;
    for (int st = 1; st < 64; st <<= 1) s += __shfl_xor(s, st);
    if ((tid & 63) == 0) red[4 + (tid >> 6)] = s;
    __syncthreads();
    s = red[4] + red[5] + red[6] + red[7];
    if (tid < NV) vwf[b * NV + tid] = e / s;
  } else {
    int b = blockIdx.x - 64;
    if (tid < 64) {
      int len = tlen[b];
      float x = twf[b * NT + tid];
      bool valid = tid < len;
      float xv = valid ? x : -1e30f;
      float m = xv;
      for (int s = 1; s < 64; s <<= 1) m = fmaxf(m, __shfl_xor(m, s));
      float e = valid ? expf(x - m) : 0.0f;
      float s = e;
      for (int st = 1; st < 64; st <<= 1) s += __shfl_xor(s, st);
      twf[b * NT + tid] = e / s;
    }
  }
}

// ---------------- MFMA sim kernel: one block per (b, q-pair), XCD-chunked -----------
// dbuf + counted vmcnt (wave issues 5-6 loads/kc -> vmcnt(5)); raw barriers, no drain.
// 2 waves/SIMD is the register ceiling (acc[4][8]=128 f32) -- bounds(256,2).
__global__ __launch_bounds__(256, 2) void k_sim(
    const short* __restrict__ ve_bf, const short* __restrict__ te_bf,
    const float* __restrict__ vwf, const float* __restrict__ twf,
    float* __restrict__ out, int* __restrict__ gMT, int* __restrict__ gMV) {
  __shared__ short As[2][256 * 32];   // linear, 64B row stride
  __shared__ short Bs[2][128 * 32];
  __shared__ float colv[4][128];
  __shared__ int   coli[4][128];
  __shared__ float redp0[4], redp1[4];
  int n = blockIdx.x;
  int xcd = n & 7, idx = n >> 3;
  int b = xcd * 8 + (idx & 7);       // b-fastest within XCD chunk
  int qq = idx >> 3;                 // 0..31
  int tid = threadIdx.x;
  int w = tid >> 6, lane = tid & 63, lg = lane >> 4, li = lane & 15;
  const short* Abf = ve_bf + (size_t)b * NV * EDIM;
  const short* Bbf = te_bf + (size_t)qq * 128 * EDIM;
  int swz = li & 3;

  auto stage = [&](int bb, int kc) {
    int k0 = kc << 5;
    short* Ad = &As[bb][0];
    short* Bd = &Bs[bb][0];
#pragma unroll
    for (int uu = 0; uu < 2; ++uu) {   // B: 128 rows x 4 segs = 512 units (2/wave)
      int u0 = uu * 256 + w * 64;
      int u = u0 + lane;
      int row = u >> 2, seg = u & 3;
      int ss = seg ^ (row & 3);
      gload16(Bbf + (size_t)row * EDIM + k0 + ss * 8, Bd + u0 * 8);
    }
#pragma unroll
    for (int uu = 0; uu < 4; ++uu) {   // A: 784 valid units (3-4/wave, rows clamped)
      int u0 = uu * 256 + w * 64;
      if (u0 < NV * 4) {
        int u = u0 + lane;
        int row = u >> 2;
        if (row > NV - 1) row = NV - 1;
        int seg = u & 3;
        int ss = seg ^ (row & 3);
        gload16(Abf + (size_t)row * EDIM + k0 + ss * 8, Ad + u0 * 8);
      }
    }
  };

  f32x4 acc[4][8];
#pragma unroll
  for (int i = 0; i < 4; ++i)
#pragma unroll
    for (int j = 0; j < 8; ++j) acc[i][j] = (f32x4){0.f, 0.f, 0.f, 0.f};

  stage(0, 0);   // 5-6 loads in flight
  int cur = 0;
  for (int kc = 0; kc < 16; ++kc) {
    __builtin_amdgcn_s_barrier();          // prev iter's reads of buf[cur^1] done
    if (kc < 15) {
      stage(cur ^ 1, kc + 1);              // 5-6 new loads
      asm volatile("s_waitcnt vmcnt(5)" ::: "memory");  // buf[cur]'s loads complete
    } else {
      asm volatile("s_waitcnt vmcnt(0)" ::: "memory");
    }
    __builtin_amdgcn_s_barrier();          // buf[cur] visible to all waves
    const short* Ab2 = &As[cur][0];
    const short* Bb2 = &Bs[cur][0];
    bf16x8 bfr[8];
#pragma unroll
    for (int j = 0; j < 8; ++j)
      bfr[j] = *(const bf16x8*)(Bb2 + (j * 16 + li) * 32 + (lg ^ swz) * 8);
#pragma unroll
    for (int i = 0; i < 4; ++i) {
      bf16x8 afr = *(const bf16x8*)(Ab2 + ((w * 4 + i) * 16 + li) * 32 + (lg ^ swz) * 8);
#pragma unroll
      for (int j = 0; j < 8; ++j)
        acc[i][j] = __builtin_amdgcn_mfma_f32_16x16x32_bf16(afr, bfr[j], acc[i][j], 0, 0, 0);
    }
    cur ^= 1;
  }

  bool diag0 = (b == 2 * qq), diag1 = (b == 2 * qq + 1);
  // ---- row (over t) max+argmax per q; C layout: row=tile*16+lg*4+reg, col=j*16+li
  float ip0 = 0.f, ip1 = 0.f;
#pragma unroll
  for (int i = 0; i < 4; ++i) {
#pragma unroll
    for (int reg = 0; reg < 4; ++reg) {
      int v = (w * 4 + i) * 16 + lg * 4 + reg;
      float m = acc[i][0][reg];
      int ti = li;
#pragma unroll
      for (int j = 1; j < 4; ++j) {
        float vv = acc[i][j][reg];
        int t = j * 16 + li;
        if (vv > m) { m = vv; ti = t; }   // t ascending -> first-index kept
      }
      for (int d = 1; d < 16; d <<= 1) {  // within li-group (same row)
        float om = __shfl_xor(m, d);
        int oi = __shfl_xor(ti, d);
        if (om > m || (om == m && oi < ti)) { m = om; ti = oi; }
      }
      float m1 = acc[i][4][reg];
      int ti1 = li;
#pragma unroll
      for (int j = 5; j < 8; ++j) {
        float vv = acc[i][j][reg];
        int t = (j - 4) * 16 + li;
        if (vv > m1) { m1 = vv; ti1 = t; }
      }
      for (int d = 1; d < 16; d <<= 1) {
        float om = __shfl_xor(m1, d);
        int oi = __shfl_xor(ti1, d);
        if (om > m1 || (om == m1 && oi < ti1)) { m1 = om; ti1 = oi; }
      }
      if (li == 0 && v < NV) {
        float wv = vwf[b * NV + v];
        ip0 += wv * m;
        ip1 += wv * m1;
        if (diag0) gMT[b * NV + v] = b * NT + ti;
        if (diag1) gMT[b * NV + v] = b * NT + ti1;
      }
    }
  }
  for (int d = 1; d < 64; d <<= 1) {
    ip0 += __shfl_xor(ip0, d);
    ip1 += __shfl_xor(ip1, d);
  }
  if (lane == 0) { redp0[w] = ip0; redp1[w] = ip1; }
  // ---- col (over v) max+argmax for this wave's rows, all 128 cols
  float cm[8]; int cv[8];
#pragma unroll
  for (int j = 0; j < 8; ++j) { cm[j] = -3.0e38f; cv[j] = 0; }
#pragma unroll
  for (int i = 0; i < 4; ++i)
#pragma unroll
    for (int reg = 0; reg < 4; ++reg) {
      int v = (w * 4 + i) * 16 + lg * 4 + reg;
      bool ok = v < NV;
#pragma unroll
      for (int j = 0; j < 8; ++j) {
        float s = ok ? acc[i][j][reg] : -3.0e38f;
        if (s > cm[j]) { cm[j] = s; cv[j] = v; }  // v ascending per lane
      }
    }
#pragma unroll
  for (int j = 0; j < 8; ++j) {
    for (int d = 16; d < 64; d <<= 1) {   // mixes lg groups (same col)
      float om = __shfl_xor(cm[j], d);
      int ov = __shfl_xor(cv[j], d);
      if (om > cm[j] || (om == cm[j] && ov < cv[j])) { cm[j] = om; cv[j] = ov; }
    }
    if (lg == 0) { colv[w][j * 16 + li] = cm[j]; coli[w][j * 16 + li] = cv[j]; }
  }
  __syncthreads();
  if (tid < 128) {
    int t = tid;
    float m = colv[0][t];
    int bi = coli[0][t];
#pragma unroll
    for (int w2 = 1; w2 < 4; ++w2) {
      float om = colv[w2][t];
      int ov = coli[w2][t];
      if (om > m || (om == m && ov < bi)) { m = om; bi = ov; }
    }
    int q = 2 * qq + (t >> 6);
    int tt = t & 63;
    if (b == q) gMV[b * NT + tt] = b * NV + bi;
    float p = twf[q * NT + tt] * m;
    for (int d = 1; d < 64; d <<= 1) p += __shfl_xor(p, d);
    if ((tid & 63) == 0) out[4096 + b * 64 + q] = p;
  }
  if (tid == 0) {
    out[b * 64 + 2 * qq]     = redp0[0] + redp0[1] + redp0[2] + redp0[3];
    out[b * 64 + 2 * qq + 1] = redp1[0] + redp1[1] + redp1[2] + redp1[3];
  }
}

// ---------------- column stats from bf16 (sum, sumsq, weighted sum) ------
__global__ void k_stats(const short* __restrict__ ve_bf, const short* __restrict__ te_bf,
                        const int* __restrict__ gMT, const int* __restrict__ gMV,
                        const float* __restrict__ vwf, const float* __restrict__ twf,
                        float* __restrict__ statPart) {
  int stripe = blockIdx.x, chunk = blockIdx.y, m = blockIdx.z;
  int R = (m < 2) ? MROWS_T : MROWS_V;
  int nchunk = (R + 1023) >> 10;
  if (chunk >= nchunk) return;
  const short* M; const int* g; const float* w;
  if (m == 0)      { M = te_bf; g = 0;   w = twf; }
  else if (m == 1) { M = ve_bf; g = gMV; w = twf; }
  else if (m == 2) { M = ve_bf; g = 0;   w = vwf; }
  else             { M = te_bf; g = gMT; w = vwf; }
  int col = stripe * 64 + (threadIdx.x & 63);
  int rg = threadIdx.x >> 6;
  int r0 = chunk << 10;
  int r1 = min(r0 + 1024, R);
  float s = 0, ss = 0, sw = 0;
  for (int r = r0 + rg; r < r1; r += 4) {
    int row = g ? g[r] : r;
    float x = bf2f(M[(size_t)row * EDIM + col]);
    s += x; ss += x * x; sw += w[r] * x;
  }
  __shared__ float red[3][256];
  red[0][threadIdx.x] = s; red[1][threadIdx.x] = ss; red[2][threadIdx.x] = sw;
  __syncthreads();
  if (threadIdx.x < 64) {
    int c = threadIdx.x;
    float S  = red[0][c] + red[0][c + 64] + red[0][c + 128] + red[0][c + 192];
    float SS = red[1][c] + red[1][c + 64] + red[1][c + 128] + red[1][c + 192];
    float SW = red[2][c] + red[2][c + 64] + red[2][c + 128] + red[2][c + 192];
    size_t idx = ((size_t)(m * 13 + chunk) * 512 + stripe * 64 + c) * 3;
    statPart[idx] = S; statPart[idx + 1] = SS; statPart[idx + 2] = SW;
  }
}

__global__ void k_statfin(const float* __restrict__ statPart, float* __restrict__ stats) {
  int m = blockIdx.x, c = threadIdx.x;
  int R = (m < 2) ? MROWS_T : MROWS_V;
  int nchunk = (R + 1023) >> 10;
  float s = 0, ss = 0, sw = 0;
  for (int ch = 0; ch < nchunk; ch++) {
    size_t idx = ((size_t)(m * 13 + ch) * 512 + c) * 3;
    s += statPart[idx]; ss += statPart[idx + 1]; sw += statPart[idx + 2];
  }
  float mean = s / R;
  float var = (ss - s * mean) / (R - 1);  // ddof=1
  float rstd = 1.0f / sqrtf(var);
  stats[(m * 3 + 0) * 512 + c] = mean;
  stats[(m * 3 + 1) * 512 + c] = rstd;
  stats[(m * 3 + 2) * 512 + c] = sw;
}

// ------- transpose-materialize a-contiguous bf16 operands (w and gathers folded) ----
__global__ void k_materialize(const short* __restrict__ ve_bf, const short* __restrict__ te_bf,
                              const int* __restrict__ gMT, const int* __restrict__ gMV,
                              const float* __restrict__ vwf, const float* __restrict__ twf,
                              short* __restrict__ tTw, short* __restrict__ mvT,
                              short* __restrict__ vTw, short* __restrict__ mtT) {
  int z = blockIdx.z;
  int at = blockIdx.x, ct = blockIdx.y;
  int K = (z == 2 || z == 3) ? MROWS_V : MROWS_T;
  if (at * 64 >= K) return;
  const short* src; const int* g = 0; const float* w = 0; short* dst;
  if (z == 0)      { src = te_bf; w = twf; dst = tTw; }
  else if (z == 1) { src = ve_bf; g = gMV; dst = mvT; }
  else if (z == 2) { src = ve_bf; w = vwf; dst = vTw; }
  else             { src = te_bf; g = gMT; dst = mtT; }
  __shared__ float tile[64][67];
  int tid = threadIdx.x;
  for (int u = tid; u < 512; u += 256) {
    int a = u >> 3, cseg = (u & 7) << 3;
    int ga = at * 64 + a;
    int row = g ? g[ga] : ga;
    bf16x8 vv = *(const bf16x8*)(src + (size_t)row * EDIM + ct * 64 + cseg);
    float wa = w ? w[ga] : 1.0f;
#pragma unroll
    for (int j = 0; j < 8; j++) tile[a][cseg + j] = wa * bf2f(vv[j]);
  }
  __syncthreads();
  for (int u = tid; u < 512; u += 256) {
    int c = u >> 3, aseg = (u & 7) << 3;
    bf16x8 ov;
#pragma unroll
    for (int j = 0; j < 8; j++) ov[j] = (short)f2bf(tile[aseg + j][c]);
    *(bf16x8*)(dst + (size_t)(ct * 64 + c) * K + at * 64 + aseg) = ov;
  }
}

// ------- MFMA weighted GEMM: Spart[z][c][d] = sum_a AT[c][a]*BT[d][a] (split-K 4) ----
__global__ __launch_bounds__(256, 4) void k_wgemm2(
    const short* __restrict__ tTw, const short* __restrict__ mvT,
    const short* __restrict__ vTw, const short* __restrict__ mtT,
    float* __restrict__ Spart) {
  __shared__ short As[128 * 44];
  __shared__ short Bs[64 * 44];
  int c0 = blockIdx.x * 128, d0 = blockIdx.y * 64;
  int z = blockIdx.z;
  int which = z >> 2, slice = z & 3;
  const short* A = which ? vTw : tTw;
  const short* B = which ? mtT : mvT;
  int K = which ? MROWS_V : MROWS_T;
  int nch = (K >> 2) >> 5;             // 98 or 32 chunks of 32
  int a0 = slice * (K >> 2);
  int tid = threadIdx.x;
  int w = tid >> 6, lane = tid & 63, lg = lane >> 4, li = lane & 15;
  f32x4 acc[2][4];
#pragma unroll
  for (int i = 0; i < 2; ++i)
#pragma unroll
    for (int j = 0; j < 4; ++j) acc[i][j] = (f32x4){0.f, 0.f, 0.f, 0.f};
  for (int ch = 0; ch < nch; ++ch) {
    int ak = a0 + (ch << 5);
    __syncthreads();
#pragma unroll
    for (int uu = 0; uu < 2; ++uu) {
      int u = tid + uu * 256;
      int r = u >> 2, seg = (u & 3) << 3;
      *(bf16x8*)(As + r * 44 + seg) = *(const bf16x8*)(A + (size_t)(c0 + r) * K + ak + seg);
    }
    {
      int t = tid >> 2, seg = (tid & 3) << 3;
      *(bf16x8*)(Bs + t * 44 + seg) = *(const bf16x8*)(B + (size_t)(d0 + t) * K + ak + seg);
    }
    __syncthreads();
    bf16x8 bfr[4];
#pragma unroll
    for (int j = 0; j < 4; ++j)
      bfr[j] = *(const bf16x8*)(Bs + (j * 16 + li) * 44 + lg * 8);
#pragma unroll
    for (int i = 0; i < 2; ++i) {
      bf16x8 afr = *(const bf16x8*)(As + ((w * 2 + i) * 16 + li) * 44 + lg * 8);
#pragma unroll
      for (int j = 0; j < 4; ++j)
        acc[i][j] = __builtin_amdgcn_mfma_f32_16x16x32_bf16(afr, bfr[j], acc[i][j], 0, 0, 0);
    }
  }
  float* outp = Spart + (size_t)z * 512 * 512;
#pragma unroll
  for (int j = 0; j < 4; ++j) {
    int d = d0 + j * 16 + li;
#pragma unroll
    for (int i = 0; i < 2; ++i)
#pragma unroll
      for (int reg = 0; reg < 4; ++reg)
        outp[(size_t)(c0 + (w * 2 + i) * 16 + lg * 4 + reg) * 512 + d] = acc[i][j][reg];
  }
}

// ---------------- assemble c = (c1+c2)/2 from closed form; loss partials ----------
__global__ void k_assemble(const float* __restrict__ Spart, const float* __restrict__ stats,
                           float* __restrict__ lossPart) {
  int c = blockIdx.x, tid = threadIdx.x;
  float muT = stats[0 * 512 + c], rsT = stats[1 * 512 + c], swT = stats[2 * 512 + c];
  float muV = stats[6 * 512 + c], rsV = stats[7 * 512 + c], swV = stats[8 * 512 + c];
  const float W = 64.0f, invB = 1.0f / 64.0f;
  float on = 0, off = 0;
  for (int d = tid; d < 512; d += 256) {
    float s1 = 0, s2 = 0;
    for (int sl = 0; sl < 4; sl++) {
      s1 += Spart[((size_t)sl * 512 + c) * 512 + d];
      s2 += Spart[((size_t)(4 + sl) * 512 + c) * 512 + d];
    }
    float muMV = stats[3 * 512 + d], rsMV = stats[4 * 512 + d], swMV = stats[5 * 512 + d];
    float muMT = stats[9 * 512 + d], rsMT = stats[10 * 512 + d], swMT = stats[11 * 512 + d];
    float c1 = (s1 - muT * swMV - muMV * swT + muT * muMV * W) * rsT * rsMV * invB;
    float c2 = (s2 - muV * swMT - muMT * swV + muV * muMT * W) * rsV * rsMT * invB;
    float cc = 0.5f * (c1 + c2);
    if (d == c) { float dd = cc - 1.0f; on += dd * dd; }
    else off += cc * cc;
  }
  __shared__ float r1[4], r2[4];
  for (int s = 1; s < 64; s <<= 1) { on += __shfl_xor(on, s); off += __shfl_xor(off, s); }
  if ((tid & 63) == 0) { r1[tid >> 6] = on; r2[tid >> 6] = off; }
  __syncthreads();
  if (tid == 0) {
    lossPart[c * 2] = r1[0] + r1[1] + r1[2] + r1[3];
    lossPart[c * 2 + 1] = r2[0] + r2[1] + r2[2] + r2[3];
  }
}

__global__ void k_loss(const float* __restrict__ lossPart, float* __restrict__ out) {
  int tid = threadIdx.x;
  float on = 0, off = 0;
  for (int i = tid; i < 512; i += 256) { on += lossPart[2 * i]; off += lossPart[2 * i + 1]; }
  __shared__ float r1[4], r2[4];
  for (int s = 1; s < 64; s <<= 1) { on += __shfl_xor(on, s); off += __shfl_xor(off, s); }
  if ((tid & 63) == 0) { r1[tid >> 6] = on; r2[tid >> 6] = off; }
  __syncthreads();
  if (tid == 0)
    out[8192] = 0.1f * ((r1[0] + r1[1] + r1[2] + r1[3]) +
                        0.06f * (r2[0] + r2[1] + r2[2] + r2[3]));
}

extern "C" void kernel_launch(void* const* d_in, const int* in_sizes, int n_in,
                              void* d_out, int out_size, void* d_ws, size_t ws_size,
                              hipStream_t stream) {
  (void)in_sizes; (void)n_in; (void)out_size; (void)ws_size;
  const float* v_tok  = (const float*)d_in[1];
  const float* t_tok  = (const float*)d_in[3];
  const float* Wv_tok = (const float*)d_in[8];
  const float* Wt_tok = (const float*)d_in[10];
  const float* bv_tok = (const float*)d_in[9];
  const float* bt_tok = (const float*)d_in[11];
  const float* wv_fc  = (const float*)d_in[12];
  const float* bv_fc  = (const float*)d_in[13];
  const float* wt_fc  = (const float*)d_in[14];
  const float* bt_fc  = (const float*)d_in[15];
  const int*   tlen   = (const int*)d_in[16];
  float* out = (float*)d_out;

  char* wsb = (char*)d_ws;
  // --- P [0, 27,131,904): phase1 {v_tok_bf, t_tok_bf, WvT, WtT} (dead after proj);
  //     phase2 (materialize on): {tTw, mvT, vTw} (21,233,664 B)
  short* v_tok_bf = (short*)wsb;                       // 9,633,792 sh
  short* t_tok_bf = v_tok_bf + (size_t)9633792;        // 3,145,728 sh
  short* WvT      = t_tok_bf + (size_t)3145728;        //   393,216 sh
  short* WtT      = WvT + (size_t)393216;              //   393,216 sh
  short* tTw = (short*)wsb;                            // 512*4096 (alias, phase2)
  short* mvT = tTw + (size_t)2097152;                  // 512*4096
  short* vTw = mvT + (size_t)2097152;                  // 512*12544
  // --- Q [27,131,904, 44,171,264): phase-a {ve_bf, te_bf}; phase-b Spart
  short* ve_bf = (short*)(wsb + 27131904);             // 6,422,528 sh
  short* te_bf = ve_bf + (size_t)6422528;              // 2,097,152 sh
  float* Spart = (float*)(wsb + 27131904);             // 8*512*512 f (alias, phase-b)
  // --- mtT [44,171,264, 57,016,320)
  short* mtT = (short*)(wsb + 44171264);               // 512*12544
  // --- smalls at 57,016,320
  float* vwf = (float*)(wsb + 57016320);               // 12544
  float* twf = vwf + 12544;                            // 4096
  int* gMT = (int*)(twf + 4096);                       // 12544
  int* gMV = gMT + 12544;                              // 4096
  float* statPart = (float*)(gMV + 4096);              // 4*13*512*3
  float* stats = statPart + 79872;                     // 12*512
  float* lossPart = stats + 6144;                      // 1024

  k_tobf16<<<4704, 256, 0, stream>>>(v_tok, v_tok_bf, 1204224);
  k_tobf16<<<1536, 256, 0, stream>>>(t_tok, t_tok_bf, 393216);
  k_transpose_bf<<<dim3(24, 16, 2), dim3(32, 8), 0, stream>>>(Wv_tok, Wt_tok, WvT, WtT);
  k_proj_mfma<<<dim3(8, 98), 256, 0, stream>>>(v_tok_bf, WvT, bv_tok, ve_bf);
  k_proj_mfma<<<dim3(8, 32), 256, 0, stream>>>(t_tok_bf, WtT, bt_tok, te_bf);
  k_normfc<<<3136, 256, 0, stream>>>(ve_bf, wv_fc, bv_fc, vwf, 12544);
  k_normfc<<<1024, 256, 0, stream>>>(te_bf, wt_fc, bt_fc, twf, 4096);
  k_softmax<<<128, 256, 0, stream>>>(vwf, twf, tlen);
  k_sim<<<2048, 256, 0, stream>>>(ve_bf, te_bf, vwf, twf, out, gMT, gMV);
  k_stats<<<dim3(8, 13, 4), 256, 0, stream>>>(ve_bf, te_bf, gMT, gMV, vwf, twf, statPart);
  k_statfin<<<4, 512, 0, stream>>>(statPart, stats);
  k_materialize<<<dim3(196, 8, 4), 256, 0, stream>>>(ve_bf, te_bf, gMT, gMV, vwf, twf,
                                                     tTw, mvT, vTw, mtT);
  k_wgemm2<<<dim3(4, 8, 8), 256, 0, stream>>>(tTw, mvT, vTw, mtT, Spart);
  k_assemble<<<512, 256, 0, stream>>>(Spart, stats, lossPart);
  k_loss<<<1, 256, 0, stream>>>(lossPart, out);
}

// Round 9
// 338.511 us; speedup vs baseline: 2.6584x; 1.0667x over previous
//
#include <hip/hip_runtime.h>
#include <cstddef>

#define EDIM 512
#define KDIM 768
#define NB 64
#define NV 196
#define NT 64
#define MROWS_V (NB * NV) /* 12544 */
#define MROWS_T (NB * NT) /* 4096  */

typedef __attribute__((ext_vector_type(8))) short bf16x8;
typedef __attribute__((ext_vector_type(4))) float f32x4;

static __device__ inline unsigned short f2bf(float f) {  // round-to-nearest-even
  unsigned u = __float_as_uint(f);
  unsigned r = (u + 0x7fff + ((u >> 16) & 1)) >> 16;
  return (unsigned short)r;
}
static __device__ inline float bf2f(short s) {
  return __uint_as_float(((unsigned)(unsigned short)s) << 16);
}
// seg swizzle: bank-start spread over all 8 quad-spans for any 8 consecutive lanes
static __device__ __forceinline__ int swz4(int r) { return (r + (r >> 2)) & 3; }

// async global->LDS, 16B per lane; LDS dest = wave-uniform base + lane*16
static __device__ __forceinline__ void gload16(const void* g, void* l) {
  __builtin_amdgcn_global_load_lds(
      (const __attribute__((address_space(1))) void*)g,
      (__attribute__((address_space(3))) void*)l, 16, 0, 0);
}

// ---------------- fp32 -> bf16 elementwise, both tensors in one launch ----------------
__global__ void k_tobf16_2(const float* __restrict__ ina, short* __restrict__ outa, int na8,
                           const float* __restrict__ inb, short* __restrict__ outb, int nb8) {
  int i = blockIdx.x * 256 + threadIdx.x;
  const float* in; short* outp; int idx;
  if (i < na8) { in = ina; outp = outa; idx = i; }
  else { idx = i - na8; if (idx >= nb8) return; in = inb; outp = outb; }
  float4 a = *(const float4*)(in + (size_t)idx * 8);
  float4 b = *(const float4*)(in + (size_t)idx * 8 + 4);
  bf16x8 v;
  v[0] = (short)f2bf(a.x); v[1] = (short)f2bf(a.y);
  v[2] = (short)f2bf(a.z); v[3] = (short)f2bf(a.w);
  v[4] = (short)f2bf(b.x); v[5] = (short)f2bf(b.y);
  v[6] = (short)f2bf(b.z); v[7] = (short)f2bf(b.w);
  *(bf16x8*)(outp + (size_t)idx * 8) = v;
}

// ---------------- transpose W [768x512] fp32 -> WT [512x768] bf16 ----------------
__global__ void k_transpose_bf(const float* __restrict__ W0, const float* __restrict__ W1,
                               short* __restrict__ T0, short* __restrict__ T1) {
  __shared__ float tile[32][33];
  const float* W = blockIdx.z ? W1 : W0;
  short*       T = blockIdx.z ? T1 : T0;
  int k0 = blockIdx.x * 32;
  int n0 = blockIdx.y * 32;
  int tx = threadIdx.x, ty = threadIdx.y;
  for (int i = ty; i < 32; i += 8)
    tile[i][tx] = W[(size_t)(k0 + i) * EDIM + n0 + tx];
  __syncthreads();
  for (int i = ty; i < 32; i += 8)
    T[(size_t)(n0 + i) * KDIM + k0 + tx] = (short)f2bf(tile[tx][i]);
}

// ---------- MFMA projection: Mbf[r,n] = bf16(sum_k X[r,k]*WT[n,k] + bias[n]) ----
// dbuf + counted vmcnt; 3 loads/wave/kc uniform -> vmcnt(3).
__global__ __launch_bounds__(256, 4) void k_proj_mfma(
    const short* __restrict__ Xbf, const short* __restrict__ WT,
    const float* __restrict__ bias, short* __restrict__ Mbf) {
  __shared__ short As[2][128 * 32];   // linear 64B rows
  __shared__ short Bs[2][64 * 32];
  int n0 = blockIdx.x * 64;
  int r0 = blockIdx.y * 128;
  int tid = threadIdx.x;
  int w = tid >> 6, lane = tid & 63, lg = lane >> 4, li = lane & 15;
  int fsw = (li + (li >> 2)) & 3;     // g(row) for row = 16j+li

  auto stage = [&](int bb, int kc) {
    int k0 = kc << 5;
    short* Ad = &As[bb][0];
    short* Bd = &Bs[bb][0];
#pragma unroll
    for (int uu = 0; uu < 2; ++uu) {   // A: 128 rows x 4 segs = 512 units
      int u0 = uu * 256 + w * 64;
      int u = u0 + lane;
      int row = u >> 2, seg = u & 3;
      int ss = seg ^ swz4(row);
      gload16(Xbf + (size_t)(r0 + row) * KDIM + k0 + ss * 8, Ad + u0 * 8);
    }
    {                                   // B: 64 rows x 4 segs = 256 units
      int u0 = w * 64;
      int u = u0 + lane;
      int row = u >> 2, seg = u & 3;
      int ss = seg ^ swz4(row);
      gload16(WT + (size_t)(n0 + row) * KDIM + k0 + ss * 8, Bd + u0 * 8);
    }
  };

  f32x4 acc[2][4];
#pragma unroll
  for (int i = 0; i < 2; ++i)
#pragma unroll
    for (int j = 0; j < 4; ++j) acc[i][j] = (f32x4){0.f, 0.f, 0.f, 0.f};

  stage(0, 0);   // 3 loads in flight
  int cur = 0;
  const int NKC = KDIM / 32;  // 24
  for (int kc = 0; kc < NKC; ++kc) {
    __builtin_amdgcn_s_barrier();          // readers of buf[cur^1] (prev iter) done
    if (kc < NKC - 1) {
      stage(cur ^ 1, kc + 1);              // 3 new loads
      asm volatile("s_waitcnt vmcnt(3)" ::: "memory");  // old 3 complete, new in flight
    } else {
      asm volatile("s_waitcnt vmcnt(0)" ::: "memory");
    }
    __builtin_amdgcn_s_barrier();          // buf[cur] visible to all waves
    const short* Ab = &As[cur][0];
    const short* Bb = &Bs[cur][0];
    bf16x8 bfr[4];
#pragma unroll
    for (int j = 0; j < 4; ++j)
      bfr[j] = *(const bf16x8*)(Bb + (j * 16 + li) * 32 + (lg ^ fsw) * 8);
#pragma unroll
    for (int i = 0; i < 2; ++i) {
      bf16x8 afr = *(const bf16x8*)(Ab + ((w * 2 + i) * 16 + li) * 32 + (lg ^ fsw) * 8);
#pragma unroll
      for (int j = 0; j < 4; ++j)
        acc[i][j] = __builtin_amdgcn_mfma_f32_16x16x32_bf16(afr, bfr[j], acc[i][j], 0, 0, 0);
    }
    cur ^= 1;
  }
#pragma unroll
  for (int j = 0; j < 4; ++j) {
    int n = n0 + j * 16 + li;
    float bb = bias[n];
#pragma unroll
    for (int i = 0; i < 2; ++i)
#pragma unroll
      for (int reg = 0; reg < 4; ++reg)
        Mbf[(size_t)(r0 + (w * 2 + i) * 16 + lg * 4 + reg) * EDIM + n] =
            (short)f2bf(acc[i][j][reg] + bb);
  }
}

// ------- per-row (bf16 in place): fc scalar (pre-norm) + l2 normalize -------
__global__ void k_normfc(short* __restrict__ Mbf, const float* __restrict__ fcw,
                         const float* __restrict__ fcb, float* __restrict__ wout,
                         int nrows) {
  int row = blockIdx.x * 4 + (threadIdx.x >> 6);
  int lane = threadIdx.x & 63;
  if (row >= nrows) return;
  short* p = Mbf + (size_t)row * EDIM + lane * 8;
  bf16x8 v = *(bf16x8*)p;
  float4 w0 = *(const float4*)(fcw + lane * 8);
  float4 w1 = *(const float4*)(fcw + lane * 8 + 4);
  float a[8];
#pragma unroll
  for (int j = 0; j < 8; ++j) a[j] = bf2f(v[j]);
  float dot = a[0] * w0.x + a[1] * w0.y + a[2] * w0.z + a[3] * w0.w +
              a[4] * w1.x + a[5] * w1.y + a[6] * w1.z + a[7] * w1.w;
  float ss = a[0] * a[0] + a[1] * a[1] + a[2] * a[2] + a[3] * a[3] +
             a[4] * a[4] + a[5] * a[5] + a[6] * a[6] + a[7] * a[7];
  for (int s = 1; s < 64; s <<= 1) {
    dot += __shfl_xor(dot, s);
    ss += __shfl_xor(ss, s);
  }
  float inv = 1.0f / fmaxf(sqrtf(ss), 1e-12f);
#pragma unroll
  for (int j = 0; j < 8; ++j) v[j] = (short)f2bf(a[j] * inv);
  *(bf16x8*)p = v;
  if (lane == 0) wout[row] = dot + fcb[0];
}

// ---------------- softmax: blocks 0..63 vw rows (196), 64..127 tw rows (64, masked) ----
__global__ void k_softmax(float* __restrict__ vwf, float* __restrict__ twf,
                          const int* __restrict__ tlen) {
  __shared__ float red[8];
  int tid = threadIdx.x;
  if (blockIdx.x < 64) {
    int b = blockIdx.x;
    float x = (tid < NV) ? vwf[b * NV + tid] : -1e30f;
    float m = x;
    for (int s = 1; s < 64; s <<= 1) m = fmaxf(m, __shfl_xor(m, s));
    if ((tid & 63) == 0) red[tid >> 6] = m;
    __syncthreads();
    m = fmaxf(fmaxf(red[0], red[1]), fmaxf(red[2], red[3]));
    float e = (tid < NV) ? expf(x - m) : 0.0f;
    float s = e;
    for (int st = 1; st < 64; st <<= 1) s += __shfl_xor(s, st);
    if ((tid & 63) == 0) red[4 + (tid >> 6)] = s;
    __syncthreads();
    s = red[4] + red[5] + red[6] + red[7];
    if (tid < NV) vwf[b * NV + tid] = e / s;
  } else {
    int b = blockIdx.x - 64;
    if (tid < 64) {
      int len = tlen[b];
      float x = twf[b * NT + tid];
      bool valid = tid < len;
      float xv = valid ? x : -1e30f;
      float m = xv;
      for (int s = 1; s < 64; s <<= 1) m = fmaxf(m, __shfl_xor(m, s));
      float e = valid ? expf(x - m) : 0.0f;
      float s = e;
      for (int st = 1; st < 64; st <<= 1) s += __shfl_xor(s, st);
      twf[b * NT + tid] = e / s;
    }
  }
}

// ---------------- MFMA sim kernel: one block per (b, q-pair), XCD-chunked -----------
// dbuf + counted vmcnt (wave0: 6 loads -> vmcnt(6); waves1-3: 5 -> vmcnt(5)).
__global__ __launch_bounds__(256, 2) void k_sim(
    const short* __restrict__ ve_bf, const short* __restrict__ te_bf,
    const float* __restrict__ vwf, const float* __restrict__ twf,
    float* __restrict__ out, int* __restrict__ gMT, int* __restrict__ gMV) {
  __shared__ short As[2][256 * 32];   // linear, 64B row stride
  __shared__ short Bs[2][128 * 32];
  __shared__ float colv[4][128];
  __shared__ int   coli[4][128];
  __shared__ float redp0[4], redp1[4];
  int n = blockIdx.x;
  int xcd = n & 7, idx = n >> 3;
  int b = xcd * 8 + (idx & 7);       // b-fastest within XCD chunk
  int qq = idx >> 3;                 // 0..31
  int tid = threadIdx.x;
  int w = tid >> 6, lane = tid & 63, lg = lane >> 4, li = lane & 15;
  const short* Abf = ve_bf + (size_t)b * NV * EDIM;
  const short* Bbf = te_bf + (size_t)qq * 128 * EDIM;
  int fsw = (li + (li >> 2)) & 3;

  auto stage = [&](int bb, int kc) {
    int k0 = kc << 5;
    short* Ad = &As[bb][0];
    short* Bd = &Bs[bb][0];
#pragma unroll
    for (int uu = 0; uu < 2; ++uu) {   // B: 128 rows x 4 segs = 512 units (2/wave)
      int u0 = uu * 256 + w * 64;
      int u = u0 + lane;
      int row = u >> 2, seg = u & 3;
      int ss = seg ^ swz4(row);
      gload16(Bbf + (size_t)row * EDIM + k0 + ss * 8, Bd + u0 * 8);
    }
#pragma unroll
    for (int uu = 0; uu < 4; ++uu) {   // A: 784 valid units (w0: 4 instr, w1-3: 3)
      int u0 = uu * 256 + w * 64;
      if (u0 < NV * 4) {
        int u = u0 + lane;
        int row = u >> 2;
        if (row > NV - 1) row = NV - 1;
        int seg = u & 3;
        int ss = seg ^ swz4(row);
        gload16(Abf + (size_t)row * EDIM + k0 + ss * 8, Ad + u0 * 8);
      }
    }
  };

  f32x4 acc[4][8];
#pragma unroll
  for (int i = 0; i < 4; ++i)
#pragma unroll
    for (int j = 0; j < 8; ++j) acc[i][j] = (f32x4){0.f, 0.f, 0.f, 0.f};

  stage(0, 0);   // w0: 6 loads, w1-3: 5 loads in flight
  int cur = 0;
  for (int kc = 0; kc < 16; ++kc) {
    __builtin_amdgcn_s_barrier();          // prev iter's reads of buf[cur^1] done
    if (kc < 15) {
      stage(cur ^ 1, kc + 1);
      if (w == 0) asm volatile("s_waitcnt vmcnt(6)" ::: "memory");
      else        asm volatile("s_waitcnt vmcnt(5)" ::: "memory");
    } else {
      asm volatile("s_waitcnt vmcnt(0)" ::: "memory");
    }
    __builtin_amdgcn_s_barrier();          // buf[cur] visible to all waves
    const short* Ab2 = &As[cur][0];
    const short* Bb2 = &Bs[cur][0];
    bf16x8 bfr[8];
#pragma unroll
    for (int j = 0; j < 8; ++j)
      bfr[j] = *(const bf16x8*)(Bb2 + (j * 16 + li) * 32 + (lg ^ fsw) * 8);
#pragma unroll
    for (int i = 0; i < 4; ++i) {
      bf16x8 afr = *(const bf16x8*)(Ab2 + ((w * 4 + i) * 16 + li) * 32 + (lg ^ fsw) * 8);
#pragma unroll
      for (int j = 0; j < 8; ++j)
        acc[i][j] = __builtin_amdgcn_mfma_f32_16x16x32_bf16(afr, bfr[j], acc[i][j], 0, 0, 0);
    }
    cur ^= 1;
  }

  bool diag0 = (b == 2 * qq), diag1 = (b == 2 * qq + 1);
  // ---- row (over t) max+argmax per q; C layout: row=tile*16+lg*4+reg, col=j*16+li
  float ip0 = 0.f, ip1 = 0.f;
#pragma unroll
  for (int i = 0; i < 4; ++i) {
#pragma unroll
    for (int reg = 0; reg < 4; ++reg) {
      int v = (w * 4 + i) * 16 + lg * 4 + reg;
      float m = acc[i][0][reg];
      int ti = li;
#pragma unroll
      for (int j = 1; j < 4; ++j) {
        float vv = acc[i][j][reg];
        int t = j * 16 + li;
        if (vv > m) { m = vv; ti = t; }   // t ascending -> first-index kept
      }
      for (int d = 1; d < 16; d <<= 1) {  // within li-group (same row)
        float om = __shfl_xor(m, d);
        int oi = __shfl_xor(ti, d);
        if (om > m || (om == m && oi < ti)) { m = om; ti = oi; }
      }
      float m1 = acc[i][4][reg];
      int ti1 = li;
#pragma unroll
      for (int j = 5; j < 8; ++j) {
        float vv = acc[i][j][reg];
        int t = (j - 4) * 16 + li;
        if (vv > m1) { m1 = vv; ti1 = t; }
      }
      for (int d = 1; d < 16; d <<= 1) {
        float om = __shfl_xor(m1, d);
        int oi = __shfl_xor(ti1, d);
        if (om > m1 || (om == m1 && oi < ti1)) { m1 = om; ti1 = oi; }
      }
      if (li == 0 && v < NV) {
        float wv = vwf[b * NV + v];
        ip0 += wv * m;
        ip1 += wv * m1;
        if (diag0) gMT[b * NV + v] = b * NT + ti;
        if (diag1) gMT[b * NV + v] = b * NT + ti1;
      }
    }
  }
  for (int d = 1; d < 64; d <<= 1) {
    ip0 += __shfl_xor(ip0, d);
    ip1 += __shfl_xor(ip1, d);
  }
  if (lane == 0) { redp0[w] = ip0; redp1[w] = ip1; }
  // ---- col (over v) max+argmax for this wave's rows, all 128 cols
  float cm[8]; int cv[8];
#pragma unroll
  for (int j = 0; j < 8; ++j) { cm[j] = -3.0e38f; cv[j] = 0; }
#pragma unroll
  for (int i = 0; i < 4; ++i)
#pragma unroll
    for (int reg = 0; reg < 4; ++reg) {
      int v = (w * 4 + i) * 16 + lg * 4 + reg;
      bool ok = v < NV;
#pragma unroll
      for (int j = 0; j < 8; ++j) {
        float s = ok ? acc[i][j][reg] : -3.0e38f;
        if (s > cm[j]) { cm[j] = s; cv[j] = v; }  // v ascending per lane
      }
    }
#pragma unroll
  for (int j = 0; j < 8; ++j) {
    for (int d = 16; d < 64; d <<= 1) {   // mixes lg groups (same col)
      float om = __shfl_xor(cm[j], d);
      int ov = __shfl_xor(cv[j], d);
      if (om > cm[j] || (om == cm[j] && ov < cv[j])) { cm[j] = om; cv[j] = ov; }
    }
    if (lg == 0) { colv[w][j * 16 + li] = cm[j]; coli[w][j * 16 + li] = cv[j]; }
  }
  __syncthreads();
  if (tid < 128) {
    int t = tid;
    float m = colv[0][t];
    int bi = coli[0][t];
#pragma unroll
    for (int w2 = 1; w2 < 4; ++w2) {
      float om = colv[w2][t];
      int ov = coli[w2][t];
      if (om > m || (om == m && ov < bi)) { m = om; bi = ov; }
    }
    int q = 2 * qq + (t >> 6);
    int tt = t & 63;
    if (b == q) gMV[b * NT + tt] = b * NV + bi;
    float p = twf[q * NT + tt] * m;
    for (int d = 1; d < 64; d <<= 1) p += __shfl_xor(p, d);
    if ((tid & 63) == 0) out[4096 + b * 64 + q] = p;
  }
  if (tid == 0) {
    out[b * 64 + 2 * qq]     = redp0[0] + redp0[1] + redp0[2] + redp0[3];
    out[b * 64 + 2 * qq + 1] = redp1[0] + redp1[1] + redp1[2] + redp1[3];
  }
}

// ---------------- column stats from bf16 (sum, sumsq, weighted sum) ------
__global__ void k_stats(const short* __restrict__ ve_bf, const short* __restrict__ te_bf,
                        const int* __restrict__ gMT, const int* __restrict__ gMV,
                        const float* __restrict__ vwf, const float* __restrict__ twf,
                        float* __restrict__ statPart) {
  int stripe = blockIdx.x, chunk = blockIdx.y, m = blockIdx.z;
  int R = (m < 2) ? MROWS_T : MROWS_V;
  int nchunk = (R + 1023) >> 10;
  if (chunk >= nchunk) return;
  const short* M; const int* g; const float* w;
  if (m == 0)      { M = te_bf; g = 0;   w = twf; }
  else if (m == 1) { M = ve_bf; g = gMV; w = twf; }
  else if (m == 2) { M = ve_bf; g = 0;   w = vwf; }
  else             { M = te_bf; g = gMT; w = vwf; }
  int col = stripe * 64 + (threadIdx.x & 63);
  int rg = threadIdx.x >> 6;
  int r0 = chunk << 10;
  int r1 = min(r0 + 1024, R);
  float s = 0, ss = 0, sw = 0;
  for (int r = r0 + rg; r < r1; r += 4) {
    int row = g ? g[r] : r;
    float x = bf2f(M[(size_t)row * EDIM + col]);
    s += x; ss += x * x; sw += w[r] * x;
  }
  __shared__ float red[3][256];
  red[0][threadIdx.x] = s; red[1][threadIdx.x] = ss; red[2][threadIdx.x] = sw;
  __syncthreads();
  if (threadIdx.x < 64) {
    int c = threadIdx.x;
    float S  = red[0][c] + red[0][c + 64] + red[0][c + 128] + red[0][c + 192];
    float SS = red[1][c] + red[1][c + 64] + red[1][c + 128] + red[1][c + 192];
    float SW = red[2][c] + red[2][c + 64] + red[2][c + 128] + red[2][c + 192];
    size_t idx = ((size_t)(m * 13 + chunk) * 512 + stripe * 64 + c) * 3;
    statPart[idx] = S; statPart[idx + 1] = SS; statPart[idx + 2] = SW;
  }
}

__global__ void k_statfin(const float* __restrict__ statPart, float* __restrict__ stats) {
  int m = blockIdx.x, c = threadIdx.x;
  int R = (m < 2) ? MROWS_T : MROWS_V;
  int nchunk = (R + 1023) >> 10;
  float s = 0, ss = 0, sw = 0;
  for (int ch = 0; ch < nchunk; ch++) {
    size_t idx = ((size_t)(m * 13 + ch) * 512 + c) * 3;
    s += statPart[idx]; ss += statPart[idx + 1]; sw += statPart[idx + 2];
  }
  float mean = s / R;
  float var = (ss - s * mean) / (R - 1);  // ddof=1
  float rstd = 1.0f / sqrtf(var);
  stats[(m * 3 + 0) * 512 + c] = mean;
  stats[(m * 3 + 1) * 512 + c] = rstd;
  stats[(m * 3 + 2) * 512 + c] = sw;
}

// ------- transpose-materialize a-contiguous bf16 operands (w and gathers folded) ----
__global__ void k_materialize(const short* __restrict__ ve_bf, const short* __restrict__ te_bf,
                              const int* __restrict__ gMT, const int* __restrict__ gMV,
                              const float* __restrict__ vwf, const float* __restrict__ twf,
                              short* __restrict__ tTw, short* __restrict__ mvT,
                              short* __restrict__ vTw, short* __restrict__ mtT) {
  int z = blockIdx.z;
  int at = blockIdx.x, ct = blockIdx.y;
  int K = (z == 2 || z == 3) ? MROWS_V : MROWS_T;
  if (at * 64 >= K) return;
  const short* src; const int* g = 0; const float* w = 0; short* dst;
  if (z == 0)      { src = te_bf; w = twf; dst = tTw; }
  else if (z == 1) { src = ve_bf; g = gMV; dst = mvT; }
  else if (z == 2) { src = ve_bf; w = vwf; dst = vTw; }
  else             { src = te_bf; g = gMT; dst = mtT; }
  __shared__ float tile[64][67];
  int tid = threadIdx.x;
  for (int u = tid; u < 512; u += 256) {
    int a = u >> 3, cseg = (u & 7) << 3;
    int ga = at * 64 + a;
    int row = g ? g[ga] : ga;
    bf16x8 vv = *(const bf16x8*)(src + (size_t)row * EDIM + ct * 64 + cseg);
    float wa = w ? w[ga] : 1.0f;
#pragma unroll
    for (int j = 0; j < 8; j++) tile[a][cseg + j] = wa * bf2f(vv[j]);
  }
  __syncthreads();
  for (int u = tid; u < 512; u += 256) {
    int c = u >> 3, aseg = (u & 7) << 3;
    bf16x8 ov;
#pragma unroll
    for (int j = 0; j < 8; j++) ov[j] = (short)f2bf(tile[aseg + j][c]);
    *(bf16x8*)(dst + (size_t)(ct * 64 + c) * K + at * 64 + aseg) = ov;
  }
}

// ------- MFMA weighted GEMM: Spart[z][c][d] = sum_a AT[c][a]*BT[d][a] (split-K 8) ----
// gload16 + dbuf + counted vmcnt (3 loads/wave uniform); 512 blocks = 2/CU.
__global__ __launch_bounds__(256, 4) void k_wgemm2(
    const short* __restrict__ tTw, const short* __restrict__ mvT,
    const short* __restrict__ vTw, const short* __restrict__ mtT,
    float* __restrict__ Spart) {
  __shared__ short As[2][128 * 32];
  __shared__ short Bs[2][64 * 32];
  int c0 = blockIdx.x * 128, d0 = blockIdx.y * 64;
  int z = blockIdx.z;                 // 0..15
  int which = z >> 3, slice = z & 7;
  const short* A = which ? vTw : tTw;
  const short* B = which ? mtT : mvT;
  int K = which ? MROWS_V : MROWS_T;
  int nch = (K >> 3) >> 5;            // 49 or 16 chunks of 32
  int a0 = slice * (K >> 3);
  int tid = threadIdx.x;
  int w = tid >> 6, lane = tid & 63, lg = lane >> 4, li = lane & 15;
  int fsw = (li + (li >> 2)) & 3;

  auto stage = [&](int bb, int ch) {
    int ak = a0 + (ch << 5);
    short* Ad = &As[bb][0];
    short* Bd = &Bs[bb][0];
#pragma unroll
    for (int uu = 0; uu < 2; ++uu) {   // A: 128 rows x 4 segs
      int u0 = uu * 256 + w * 64;
      int u = u0 + lane;
      int row = u >> 2, seg = u & 3;
      int ss = seg ^ swz4(row);
      gload16(A + (size_t)(c0 + row) * K + ak + ss * 8, Ad + u0 * 8);
    }
    {                                   // B: 64 rows x 4 segs
      int u0 = w * 64;
      int u = u0 + lane;
      int row = u >> 2, seg = u & 3;
      int ss = seg ^ swz4(row);
      gload16(B + (size_t)(d0 + row) * K + ak + ss * 8, Bd + u0 * 8);
    }
  };

  f32x4 acc[2][4];
#pragma unroll
  for (int i = 0; i < 2; ++i)
#pragma unroll
    for (int j = 0; j < 4; ++j) acc[i][j] = (f32x4){0.f, 0.f, 0.f, 0.f};

  stage(0, 0);
  int cur = 0;
  for (int ch = 0; ch < nch; ++ch) {
    __builtin_amdgcn_s_barrier();
    if (ch < nch - 1) {
      stage(cur ^ 1, ch + 1);
      asm volatile("s_waitcnt vmcnt(3)" ::: "memory");
    } else {
      asm volatile("s_waitcnt vmcnt(0)" ::: "memory");
    }
    __builtin_amdgcn_s_barrier();
    const short* Ab = &As[cur][0];
    const short* Bb = &Bs[cur][0];
    bf16x8 bfr[4];
#pragma unroll
    for (int j = 0; j < 4; ++j)
      bfr[j] = *(const bf16x8*)(Bb + (j * 16 + li) * 32 + (lg ^ fsw) * 8);
#pragma unroll
    for (int i = 0; i < 2; ++i) {
      bf16x8 afr = *(const bf16x8*)(Ab + ((w * 2 + i) * 16 + li) * 32 + (lg ^ fsw) * 8);
#pragma unroll
      for (int j = 0; j < 4; ++j)
        acc[i][j] = __builtin_amdgcn_mfma_f32_16x16x32_bf16(afr, bfr[j], acc[i][j], 0, 0, 0);
    }
    cur ^= 1;
  }
  float* outp = Spart + (size_t)z * 512 * 512;
#pragma unroll
  for (int j = 0; j < 4; ++j) {
    int d = d0 + j * 16 + li;
#pragma unroll
    for (int i = 0; i < 2; ++i)
#pragma unroll
      for (int reg = 0; reg < 4; ++reg)
        outp[(size_t)(c0 + (w * 2 + i) * 16 + lg * 4 + reg) * 512 + d] = acc[i][j][reg];
  }
}

// ---------------- assemble c = (c1+c2)/2 from closed form; loss partials ----------
__global__ void k_assemble(const float* __restrict__ Spart, const float* __restrict__ stats,
                           float* __restrict__ lossPart) {
  int c = blockIdx.x, tid = threadIdx.x;
  float muT = stats[0 * 512 + c], rsT = stats[1 * 512 + c], swT = stats[2 * 512 + c];
  float muV = stats[6 * 512 + c], rsV = stats[7 * 512 + c], swV = stats[8 * 512 + c];
  const float W = 64.0f, invB = 1.0f / 64.0f;
  float on = 0, off = 0;
  for (int d = tid; d < 512; d += 256) {
    float s1 = 0, s2 = 0;
    for (int sl = 0; sl < 8; sl++) {
      s1 += Spart[((size_t)sl * 512 + c) * 512 + d];
      s2 += Spart[((size_t)(8 + sl) * 512 + c) * 512 + d];
    }
    float muMV = stats[3 * 512 + d], rsMV = stats[4 * 512 + d], swMV = stats[5 * 512 + d];
    float muMT = stats[9 * 512 + d], rsMT = stats[10 * 512 + d], swMT = stats[11 * 512 + d];
    float c1 = (s1 - muT * swMV - muMV * swT + muT * muMV * W) * rsT * rsMV * invB;
    float c2 = (s2 - muV * swMT - muMT * swV + muV * muMT * W) * rsV * rsMT * invB;
    float cc = 0.5f * (c1 + c2);
    if (d == c) { float dd = cc - 1.0f; on += dd * dd; }
    else off += cc * cc;
  }
  __shared__ float r1[4], r2[4];
  for (int s = 1; s < 64; s <<= 1) { on += __shfl_xor(on, s); off += __shfl_xor(off, s); }
  if ((tid & 63) == 0) { r1[tid >> 6] = on; r2[tid >> 6] = off; }
  __syncthreads();
  if (tid == 0) {
    lossPart[c * 2] = r1[0] + r1[1] + r1[2] + r1[3];
    lossPart[c * 2 + 1] = r2[0] + r2[1] + r2[2] + r2[3];
  }
}

__global__ void k_loss(const float* __restrict__ lossPart, float* __restrict__ out) {
  int tid = threadIdx.x;
  float on = 0, off = 0;
  for (int i = tid; i < 512; i += 256) { on += lossPart[2 * i]; off += lossPart[2 * i + 1]; }
  __shared__ float r1[4], r2[4];
  for (int s = 1; s < 64; s <<= 1) { on += __shfl_xor(on, s); off += __shfl_xor(off, s); }
  if ((tid & 63) == 0) { r1[tid >> 6] = on; r2[tid >> 6] = off; }
  __syncthreads();
  if (tid == 0)
    out[8192] = 0.1f * ((r1[0] + r1[1] + r1[2] + r1[3]) +
                        0.06f * (r2[0] + r2[1] + r2[2] + r2[3]));
}

extern "C" void kernel_launch(void* const* d_in, const int* in_sizes, int n_in,
                              void* d_out, int out_size, void* d_ws, size_t ws_size,
                              hipStream_t stream) {
  (void)in_sizes; (void)n_in; (void)out_size; (void)ws_size;
  const float* v_tok  = (const float*)d_in[1];
  const float* t_tok  = (const float*)d_in[3];
  const float* Wv_tok = (const float*)d_in[8];
  const float* Wt_tok = (const float*)d_in[10];
  const float* bv_tok = (const float*)d_in[9];
  const float* bt_tok = (const float*)d_in[11];
  const float* wv_fc  = (const float*)d_in[12];
  const float* bv_fc  = (const float*)d_in[13];
  const float* wt_fc  = (const float*)d_in[14];
  const float* bt_fc  = (const float*)d_in[15];
  const int*   tlen   = (const int*)d_in[16];
  float* out = (float*)d_out;

  char* wsb = (char*)d_ws;
  // --- P [0, 27,131,904): phase1 {v_tok_bf, t_tok_bf, WvT, WtT} (dead after proj);
  //     phase2 (materialize on): {tTw, mvT, vTw}
  short* v_tok_bf = (short*)wsb;                       // 9,633,792 sh
  short* t_tok_bf = v_tok_bf + (size_t)9633792;        // 3,145,728 sh
  short* WvT      = t_tok_bf + (size_t)3145728;        //   393,216 sh
  short* WtT      = WvT + (size_t)393216;              //   393,216 sh
  short* tTw = (short*)wsb;                            // 512*4096 (alias, phase2)
  short* mvT = tTw + (size_t)2097152;                  // 512*4096
  short* vTw = mvT + (size_t)2097152;                  // 512*12544
  // --- Q [27,131,904, 44,171,264): phase-a {ve_bf, te_bf}; phase-b Spart (16 MB)
  short* ve_bf = (short*)(wsb + 27131904);             // 6,422,528 sh
  short* te_bf = ve_bf + (size_t)6422528;              // 2,097,152 sh
  float* Spart = (float*)(wsb + 27131904);             // 16*512*512 f (alias, phase-b)
  // --- mtT [44,171,264, 57,016,320)
  short* mtT = (short*)(wsb + 44171264);               // 512*12544
  // --- smalls at 57,016,320
  float* vwf = (float*)(wsb + 57016320);               // 12544
  float* twf = vwf + 12544;                            // 4096
  int* gMT = (int*)(twf + 4096);                       // 12544
  int* gMV = gMT + 12544;                              // 4096
  float* statPart = (float*)(gMV + 4096);              // 4*13*512*3
  float* stats = statPart + 79872;                     // 12*512
  float* lossPart = stats + 6144;                      // 1024

  k_tobf16_2<<<6240, 256, 0, stream>>>(v_tok, v_tok_bf, 1204224, t_tok, t_tok_bf, 393216);
  k_transpose_bf<<<dim3(24, 16, 2), dim3(32, 8), 0, stream>>>(Wv_tok, Wt_tok, WvT, WtT);
  k_proj_mfma<<<dim3(8, 98), 256, 0, stream>>>(v_tok_bf, WvT, bv_tok, ve_bf);
  k_proj_mfma<<<dim3(8, 32), 256, 0, stream>>>(t_tok_bf, WtT, bt_tok, te_bf);
  k_normfc<<<3136, 256, 0, stream>>>(ve_bf, wv_fc, bv_fc, vwf, 12544);
  k_normfc<<<1024, 256, 0, stream>>>(te_bf, wt_fc, bt_fc, twf, 4096);
  k_softmax<<<128, 256, 0, stream>>>(vwf, twf, tlen);
  k_sim<<<2048, 256, 0, stream>>>(ve_bf, te_bf, vwf, twf, out, gMT, gMV);
  k_stats<<<dim3(8, 13, 4), 256, 0, stream>>>(ve_bf, te_bf, gMT, gMV, vwf, twf, statPart);
  k_statfin<<<4, 512, 0, stream>>>(statPart, stats);
  k_materialize<<<dim3(196, 8, 4), 256, 0, stream>>>(ve_bf, te_bf, gMT, gMV, vwf, twf,
                                                     tTw, mvT, vTw, mtT);
  k_wgemm2<<<dim3(4, 8, 16), 256, 0, stream>>>(tTw, mvT, vTw, mtT, Spart);
  k_assemble<<<512, 256, 0, stream>>>(Spart, stats, lossPart);
  k_loss<<<1, 256, 0, stream>>>(lossPart, out);
}

// Round 10
// 319.276 us; speedup vs baseline: 2.8186x; 1.0602x over previous
//
#include <hip/hip_runtime.h>
#include <cstddef>

#define EDIM 512
#define KDIM 768
#define NB 64
#define NV 196
#define NT 64
#define MROWS_V (NB * NV) /* 12544 */
#define MROWS_T (NB * NT) /* 4096  */

typedef __attribute__((ext_vector_type(8))) short bf16x8;
typedef __attribute__((ext_vector_type(4))) float f32x4;

static __device__ inline unsigned short f2bf(float f) {  // round-to-nearest-even
  unsigned u = __float_as_uint(f);
  unsigned r = (u + 0x7fff + ((u >> 16) & 1)) >> 16;
  return (unsigned short)r;
}
static __device__ inline float bf2f(short s) {
  return __uint_as_float(((unsigned)(unsigned short)s) << 16);
}
// seg swizzle: for row-tiles read at fixed li, spreads bank-starts
static __device__ __forceinline__ int swz4(int r) { return (r + (r >> 2)) & 3; }

// async global->LDS, 16B per lane; LDS dest = wave-uniform base + lane*16
static __device__ __forceinline__ void gload16(const void* g, void* l) {
  __builtin_amdgcn_global_load_lds(
      (const __attribute__((address_space(1))) void*)g,
      (__attribute__((address_space(3))) void*)l, 16, 0, 0);
}

// ---------------- fp32 -> bf16 elementwise, both tensors in one launch ----------------
__global__ void k_tobf16_2(const float* __restrict__ ina, short* __restrict__ outa, int na8,
                           const float* __restrict__ inb, short* __restrict__ outb, int nb8) {
  int i = blockIdx.x * 256 + threadIdx.x;
  const float* in; short* outp; int idx;
  if (i < na8) { in = ina; outp = outa; idx = i; }
  else { idx = i - na8; if (idx >= nb8) return; in = inb; outp = outb; }
  float4 a = *(const float4*)(in + (size_t)idx * 8);
  float4 b = *(const float4*)(in + (size_t)idx * 8 + 4);
  bf16x8 v;
  v[0] = (short)f2bf(a.x); v[1] = (short)f2bf(a.y);
  v[2] = (short)f2bf(a.z); v[3] = (short)f2bf(a.w);
  v[4] = (short)f2bf(b.x); v[5] = (short)f2bf(b.y);
  v[6] = (short)f2bf(b.z); v[7] = (short)f2bf(b.w);
  *(bf16x8*)(outp + (size_t)idx * 8) = v;
}

// ---------------- transpose W [768x512] fp32 -> WT [512x768] bf16 ----------------
__global__ void k_transpose_bf(const float* __restrict__ W0, const float* __restrict__ W1,
                               short* __restrict__ T0, short* __restrict__ T1) {
  __shared__ float tile[32][33];
  const float* W = blockIdx.z ? W1 : W0;
  short*       T = blockIdx.z ? T1 : T0;
  int k0 = blockIdx.x * 32;
  int n0 = blockIdx.y * 32;
  int tx = threadIdx.x, ty = threadIdx.y;
  for (int i = ty; i < 32; i += 8)
    tile[i][tx] = W[(size_t)(k0 + i) * EDIM + n0 + tx];
  __syncthreads();
  for (int i = ty; i < 32; i += 8)
    T[(size_t)(n0 + i) * KDIM + k0 + tx] = (short)f2bf(tile[tx][i]);
}

// ---------- MFMA projection: Mbf[r,n] = bf16(sum_k X[r,k]*WT[n,k] + bias[n]) ----
// dbuf + counted vmcnt; 3 loads/wave/kc uniform -> vmcnt(3).
__global__ __launch_bounds__(256, 4) void k_proj_mfma(
    const short* __restrict__ Xbf, const short* __restrict__ WT,
    const float* __restrict__ bias, short* __restrict__ Mbf) {
  __shared__ short As[2][128 * 32];   // linear 64B rows
  __shared__ short Bs[2][64 * 32];
  int n0 = blockIdx.x * 64;
  int r0 = blockIdx.y * 128;
  int tid = threadIdx.x;
  int w = tid >> 6, lane = tid & 63, lg = lane >> 4, li = lane & 15;
  int fsw = (li + (li >> 2)) & 3;     // = swz4(row) for row = 16j+li

  auto stage = [&](int bb, int kc) {
    int k0 = kc << 5;
    short* Ad = &As[bb][0];
    short* Bd = &Bs[bb][0];
#pragma unroll
    for (int uu = 0; uu < 2; ++uu) {   // A: 128 rows x 4 segs = 512 units
      int u0 = uu * 256 + w * 64;
      int u = u0 + lane;
      int row = u >> 2, seg = u & 3;
      int ss = seg ^ swz4(row);
      gload16(Xbf + (size_t)(r0 + row) * KDIM + k0 + ss * 8, Ad + u0 * 8);
    }
    {                                   // B: 64 rows x 4 segs = 256 units
      int u0 = w * 64;
      int u = u0 + lane;
      int row = u >> 2, seg = u & 3;
      int ss = seg ^ swz4(row);
      gload16(WT + (size_t)(n0 + row) * KDIM + k0 + ss * 8, Bd + u0 * 8);
    }
  };

  f32x4 acc[2][4];
#pragma unroll
  for (int i = 0; i < 2; ++i)
#pragma unroll
    for (int j = 0; j < 4; ++j) acc[i][j] = (f32x4){0.f, 0.f, 0.f, 0.f};

  stage(0, 0);   // 3 loads in flight
  int cur = 0;
  const int NKC = KDIM / 32;  // 24
  for (int kc = 0; kc < NKC; ++kc) {
    __builtin_amdgcn_s_barrier();          // readers of buf[cur^1] (prev iter) done
    if (kc < NKC - 1) {
      stage(cur ^ 1, kc + 1);              // 3 new loads
      asm volatile("s_waitcnt vmcnt(3)" ::: "memory");  // old 3 complete
    } else {
      asm volatile("s_waitcnt vmcnt(0)" ::: "memory");
    }
    __builtin_amdgcn_s_barrier();          // buf[cur] visible to all waves
    const short* Ab = &As[cur][0];
    const short* Bb = &Bs[cur][0];
    bf16x8 bfr[4];
#pragma unroll
    for (int j = 0; j < 4; ++j)
      bfr[j] = *(const bf16x8*)(Bb + (j * 16 + li) * 32 + (lg ^ fsw) * 8);
#pragma unroll
    for (int i = 0; i < 2; ++i) {
      bf16x8 afr = *(const bf16x8*)(Ab + ((w * 2 + i) * 16 + li) * 32 + (lg ^ fsw) * 8);
#pragma unroll
      for (int j = 0; j < 4; ++j)
        acc[i][j] = __builtin_amdgcn_mfma_f32_16x16x32_bf16(afr, bfr[j], acc[i][j], 0, 0, 0);
    }
    cur ^= 1;
  }
#pragma unroll
  for (int j = 0; j < 4; ++j) {
    int n = n0 + j * 16 + li;
    float bb = bias[n];
#pragma unroll
    for (int i = 0; i < 2; ++i)
#pragma unroll
      for (int reg = 0; reg < 4; ++reg)
        Mbf[(size_t)(r0 + (w * 2 + i) * 16 + lg * 4 + reg) * EDIM + n] =
            (short)f2bf(acc[i][j][reg] + bb);
  }
}

// ------- per-row (bf16 in place): fc scalar (pre-norm) + l2 normalize -------
__global__ void k_normfc(short* __restrict__ Mbf, const float* __restrict__ fcw,
                         const float* __restrict__ fcb, float* __restrict__ wout,
                         int nrows) {
  int row = blockIdx.x * 4 + (threadIdx.x >> 6);
  int lane = threadIdx.x & 63;
  if (row >= nrows) return;
  short* p = Mbf + (size_t)row * EDIM + lane * 8;
  bf16x8 v = *(bf16x8*)p;
  float4 w0 = *(const float4*)(fcw + lane * 8);
  float4 w1 = *(const float4*)(fcw + lane * 8 + 4);
  float a[8];
#pragma unroll
  for (int j = 0; j < 8; ++j) a[j] = bf2f(v[j]);
  float dot = a[0] * w0.x + a[1] * w0.y + a[2] * w0.z + a[3] * w0.w +
              a[4] * w1.x + a[5] * w1.y + a[6] * w1.z + a[7] * w1.w;
  float ss = a[0] * a[0] + a[1] * a[1] + a[2] * a[2] + a[3] * a[3] +
             a[4] * a[4] + a[5] * a[5] + a[6] * a[6] + a[7] * a[7];
  for (int s = 1; s < 64; s <<= 1) {
    dot += __shfl_xor(dot, s);
    ss += __shfl_xor(ss, s);
  }
  float inv = 1.0f / fmaxf(sqrtf(ss), 1e-12f);
#pragma unroll
  for (int j = 0; j < 8; ++j) v[j] = (short)f2bf(a[j] * inv);
  *(bf16x8*)p = v;
  if (lane == 0) wout[row] = dot + fcb[0];
}

// ---------------- softmax: blocks 0..63 vw rows (196), 64..127 tw rows (64, masked) ----
__global__ void k_softmax(float* __restrict__ vwf, float* __restrict__ twf,
                          const int* __restrict__ tlen) {
  __shared__ float red[8];
  int tid = threadIdx.x;
  if (blockIdx.x < 64) {
    int b = blockIdx.x;
    float x = (tid < NV) ? vwf[b * NV + tid] : -1e30f;
    float m = x;
    for (int s = 1; s < 64; s <<= 1) m = fmaxf(m, __shfl_xor(m, s));
    if ((tid & 63) == 0) red[tid >> 6] = m;
    __syncthreads();
    m = fmaxf(fmaxf(red[0], red[1]), fmaxf(red[2], red[3]));
    float e = (tid < NV) ? expf(x - m) : 0.0f;
    float s = e;
    for (int st = 1; st < 64; st <<= 1) s += __shfl_xor(s, st);
    if ((tid & 63) == 0) red[4 + (tid >> 6)] = s;
    __syncthreads();
    s = red[4] + red[5] + red[6] + red[7];
    if (tid < NV) vwf[b * NV + tid] = e / s;
  } else {
    int b = blockIdx.x - 64;
    if (tid < 64) {
      int len = tlen[b];
      float x = twf[b * NT + tid];
      bool valid = tid < len;
      float xv = valid ? x : -1e30f;
      float m = xv;
      for (int s = 1; s < 64; s <<= 1) m = fmaxf(m, __shfl_xor(m, s));
      float e = valid ? expf(x - m) : 0.0f;
      float s = e;
      for (int st = 1; st < 64; st <<= 1) s += __shfl_xor(s, st);
      twf[b * NT + tid] = e / s;
    }
  }
}

// ---------------- MFMA sim kernel: one block per (b, q), XCD-chunked ----------------
// acc[4][4]=64 AGPR + ~55 VGPR -> 4 waves/SIMD (vs 2 for the q-pair version).
// Single-buffer 22.3KB LDS; 2 __syncthreads per kc; 4 blocks/CU hide the drain.
__global__ __launch_bounds__(256, 4) void k_sim(
    const short* __restrict__ ve_bf, const short* __restrict__ te_bf,
    const float* __restrict__ vwf, const float* __restrict__ twf,
    float* __restrict__ out, int* __restrict__ gMT, int* __restrict__ gMV) {
  __shared__ short As[256 * 32];   // linear, 64B row stride
  __shared__ short Bs[64 * 32];
  __shared__ float colv[4][64];
  __shared__ int   coli[4][64];
  __shared__ float redp[4];
  int n = blockIdx.x;
  int xcd = n & 7, idx = n >> 3;
  int b = xcd * 8 + (idx & 7);     // b-fastest within XCD chunk (ve L2-resident)
  int q = idx >> 3;                // 0..63
  int tid = threadIdx.x;
  int w = tid >> 6, lane = tid & 63, lg = lane >> 4, li = lane & 15;
  const short* Abf = ve_bf + (size_t)b * NV * EDIM;
  const short* Bbf = te_bf + (size_t)q * NT * EDIM;
  int fsw = (li + (li >> 2)) & 3;

  f32x4 acc[4][4];
#pragma unroll
  for (int i = 0; i < 4; ++i)
#pragma unroll
    for (int j = 0; j < 4; ++j) acc[i][j] = (f32x4){0.f, 0.f, 0.f, 0.f};

  for (int kc = 0; kc < 16; ++kc) {
    int k0 = kc << 5;
    __syncthreads();   // prior kc's frag reads done before DMA overwrite
    {   // B: 64 rows x 4 segs = 256 units, 1 instr/wave
      int u0 = w * 64;
      int u = u0 + lane;
      int row = u >> 2, seg = u & 3;
      int ss = seg ^ swz4(row);
      gload16(Bbf + (size_t)row * EDIM + k0 + ss * 8, Bs + u0 * 8);
    }
#pragma unroll
    for (int uu = 0; uu < 4; ++uu) {   // A: 784 valid units (rows clamped past 195)
      int u0 = uu * 256 + w * 64;
      if (u0 < NV * 4) {
        int u = u0 + lane;
        int row = u >> 2;
        if (row > NV - 1) row = NV - 1;
        int seg = u & 3;
        int ss = seg ^ swz4(row);
        gload16(Abf + (size_t)row * EDIM + k0 + ss * 8, As + u0 * 8);
      }
    }
    __syncthreads();   // vmcnt(0) drain -> tile visible (hidden by 4 blocks/CU)
    bf16x8 bfr[4];
#pragma unroll
    for (int j = 0; j < 4; ++j)
      bfr[j] = *(const bf16x8*)(Bs + (j * 16 + li) * 32 + (lg ^ fsw) * 8);
    __builtin_amdgcn_s_setprio(1);
#pragma unroll
    for (int i = 0; i < 4; ++i) {
      bf16x8 afr = *(const bf16x8*)(As + ((w * 4 + i) * 16 + li) * 32 + (lg ^ fsw) * 8);
#pragma unroll
      for (int j = 0; j < 4; ++j)
        acc[i][j] = __builtin_amdgcn_mfma_f32_16x16x32_bf16(afr, bfr[j], acc[i][j], 0, 0, 0);
    }
    __builtin_amdgcn_s_setprio(0);
  }

  bool diag = (b == q);
  // ---- row (over t) max+argmax; C layout: row=tile*16+lg*4+reg, col=j*16+li
  float ip = 0.f;
#pragma unroll
  for (int i = 0; i < 4; ++i) {
#pragma unroll
    for (int reg = 0; reg < 4; ++reg) {
      int v = (w * 4 + i) * 16 + lg * 4 + reg;
      float m = acc[i][0][reg];
      int ti = li;
#pragma unroll
      for (int j = 1; j < 4; ++j) {
        float vv = acc[i][j][reg];
        int t = j * 16 + li;
        if (vv > m) { m = vv; ti = t; }   // t ascending -> first-index kept
      }
      for (int d = 1; d < 16; d <<= 1) {  // within li-group (same row)
        float om = __shfl_xor(m, d);
        int oi = __shfl_xor(ti, d);
        if (om > m || (om == m && oi < ti)) { m = om; ti = oi; }
      }
      if (li == 0 && v < NV) {
        ip += vwf[b * NV + v] * m;
        if (diag) gMT[b * NV + v] = b * NT + ti;
      }
    }
  }
  for (int d = 1; d < 64; d <<= 1) ip += __shfl_xor(ip, d);
  if (lane == 0) redp[w] = ip;
  // ---- col (over v) max+argmax for this wave's rows
  float cm[4]; int cv[4];
#pragma unroll
  for (int j = 0; j < 4; ++j) { cm[j] = -3.0e38f; cv[j] = 0; }
#pragma unroll
  for (int i = 0; i < 4; ++i)
#pragma unroll
    for (int reg = 0; reg < 4; ++reg) {
      int v = (w * 4 + i) * 16 + lg * 4 + reg;
      bool ok = v < NV;
#pragma unroll
      for (int j = 0; j < 4; ++j) {
        float s = ok ? acc[i][j][reg] : -3.0e38f;
        if (s > cm[j]) { cm[j] = s; cv[j] = v; }  // v ascending per lane
      }
    }
#pragma unroll
  for (int j = 0; j < 4; ++j) {
    for (int d = 16; d < 64; d <<= 1) {   // mixes lg groups (same col)
      float om = __shfl_xor(cm[j], d);
      int ov = __shfl_xor(cv[j], d);
      if (om > cm[j] || (om == cm[j] && ov < cv[j])) { cm[j] = om; cv[j] = ov; }
    }
    if (lg == 0) { colv[w][j * 16 + li] = cm[j]; coli[w][j * 16 + li] = cv[j]; }
  }
  __syncthreads();
  if (tid < 64) {
    int t = tid;
    float m = colv[0][t];
    int bi = coli[0][t];
#pragma unroll
    for (int w2 = 1; w2 < 4; ++w2) {
      float om = colv[w2][t];
      int ov = coli[w2][t];
      if (om > m || (om == m && ov < bi)) { m = om; bi = ov; }
    }
    if (diag) gMV[b * NT + t] = b * NV + bi;
    float p = twf[q * NT + t] * m;
    for (int d = 1; d < 64; d <<= 1) p += __shfl_xor(p, d);
    if (t == 0) out[4096 + b * 64 + q] = p;
  }
  if (tid == 0) out[b * 64 + q] = redp[0] + redp[1] + redp[2] + redp[3];
}

// ---------------- column stats from bf16 (sum, sumsq, weighted sum) ------
__global__ void k_stats(const short* __restrict__ ve_bf, const short* __restrict__ te_bf,
                        const int* __restrict__ gMT, const int* __restrict__ gMV,
                        const float* __restrict__ vwf, const float* __restrict__ twf,
                        float* __restrict__ statPart) {
  int stripe = blockIdx.x, chunk = blockIdx.y, m = blockIdx.z;
  int R = (m < 2) ? MROWS_T : MROWS_V;
  int nchunk = (R + 1023) >> 10;
  if (chunk >= nchunk) return;
  const short* M; const int* g; const float* w;
  if (m == 0)      { M = te_bf; g = 0;   w = twf; }
  else if (m == 1) { M = ve_bf; g = gMV; w = twf; }
  else if (m == 2) { M = ve_bf; g = 0;   w = vwf; }
  else             { M = te_bf; g = gMT; w = vwf; }
  int col = stripe * 64 + (threadIdx.x & 63);
  int rg = threadIdx.x >> 6;
  int r0 = chunk << 10;
  int r1 = min(r0 + 1024, R);
  float s = 0, ss = 0, sw = 0;
  for (int r = r0 + rg; r < r1; r += 4) {
    int row = g ? g[r] : r;
    float x = bf2f(M[(size_t)row * EDIM + col]);
    s += x; ss += x * x; sw += w[r] * x;
  }
  __shared__ float red[3][256];
  red[0][threadIdx.x] = s; red[1][threadIdx.x] = ss; red[2][threadIdx.x] = sw;
  __syncthreads();
  if (threadIdx.x < 64) {
    int c = threadIdx.x;
    float S  = red[0][c] + red[0][c + 64] + red[0][c + 128] + red[0][c + 192];
    float SS = red[1][c] + red[1][c + 64] + red[1][c + 128] + red[1][c + 192];
    float SW = red[2][c] + red[2][c + 64] + red[2][c + 128] + red[2][c + 192];
    size_t idx = ((size_t)(m * 13 + chunk) * 512 + stripe * 64 + c) * 3;
    statPart[idx] = S; statPart[idx + 1] = SS; statPart[idx + 2] = SW;
  }
}

__global__ void k_statfin(const float* __restrict__ statPart, float* __restrict__ stats) {
  int m = blockIdx.x, c = threadIdx.x;
  int R = (m < 2) ? MROWS_T : MROWS_V;
  int nchunk = (R + 1023) >> 10;
  float s = 0, ss = 0, sw = 0;
  for (int ch = 0; ch < nchunk; ch++) {
    size_t idx = ((size_t)(m * 13 + ch) * 512 + c) * 3;
    s += statPart[idx]; ss += statPart[idx + 1]; sw += statPart[idx + 2];
  }
  float mean = s / R;
  float var = (ss - s * mean) / (R - 1);  // ddof=1
  float rstd = 1.0f / sqrtf(var);
  stats[(m * 3 + 0) * 512 + c] = mean;
  stats[(m * 3 + 1) * 512 + c] = rstd;
  stats[(m * 3 + 2) * 512 + c] = sw;
}

// ------- transpose-materialize a-contiguous bf16 operands (w and gathers folded) ----
__global__ void k_materialize(const short* __restrict__ ve_bf, const short* __restrict__ te_bf,
                              const int* __restrict__ gMT, const int* __restrict__ gMV,
                              const float* __restrict__ vwf, const float* __restrict__ twf,
                              short* __restrict__ tTw, short* __restrict__ mvT,
                              short* __restrict__ vTw, short* __restrict__ mtT) {
  int z = blockIdx.z;
  int at = blockIdx.x, ct = blockIdx.y;
  int K = (z == 2 || z == 3) ? MROWS_V : MROWS_T;
  if (at * 64 >= K) return;
  const short* src; const int* g = 0; const float* w = 0; short* dst;
  if (z == 0)      { src = te_bf; w = twf; dst = tTw; }
  else if (z == 1) { src = ve_bf; g = gMV; dst = mvT; }
  else if (z == 2) { src = ve_bf; w = vwf; dst = vTw; }
  else             { src = te_bf; g = gMT; dst = mtT; }
  __shared__ float tile[64][67];
  int tid = threadIdx.x;
  for (int u = tid; u < 512; u += 256) {
    int a = u >> 3, cseg = (u & 7) << 3;
    int ga = at * 64 + a;
    int row = g ? g[ga] : ga;
    bf16x8 vv = *(const bf16x8*)(src + (size_t)row * EDIM + ct * 64 + cseg);
    float wa = w ? w[ga] : 1.0f;
#pragma unroll
    for (int j = 0; j < 8; j++) tile[a][cseg + j] = wa * bf2f(vv[j]);
  }
  __syncthreads();
  for (int u = tid; u < 512; u += 256) {
    int c = u >> 3, aseg = (u & 7) << 3;
    bf16x8 ov;
#pragma unroll
    for (int j = 0; j < 8; j++) ov[j] = (short)f2bf(tile[aseg + j][c]);
    *(bf16x8*)(dst + (size_t)(ct * 64 + c) * K + at * 64 + aseg) = ov;
  }
}

// ------- MFMA weighted GEMM: Spart[z][c][d] = sum_a AT[c][a]*BT[d][a] (split-K 8) ----
__global__ __launch_bounds__(256, 4) void k_wgemm2(
    const short* __restrict__ tTw, const short* __restrict__ mvT,
    const short* __restrict__ vTw, const short* __restrict__ mtT,
    float* __restrict__ Spart) {
  __shared__ short As[2][128 * 32];
  __shared__ short Bs[2][64 * 32];
  int c0 = blockIdx.x * 128, d0 = blockIdx.y * 64;
  int z = blockIdx.z;                 // 0..15
  int which = z >> 3, slice = z & 7;
  const short* A = which ? vTw : tTw;
  const short* B = which ? mtT : mvT;
  int K = which ? MROWS_V : MROWS_T;
  int nch = (K >> 3) >> 5;            // 49 or 16 chunks of 32
  int a0 = slice * (K >> 3);
  int tid = threadIdx.x;
  int w = tid >> 6, lane = tid & 63, lg = lane >> 4, li = lane & 15;
  int fsw = (li + (li >> 2)) & 3;

  auto stage = [&](int bb, int ch) {
    int ak = a0 + (ch << 5);
    short* Ad = &As[bb][0];
    short* Bd = &Bs[bb][0];
#pragma unroll
    for (int uu = 0; uu < 2; ++uu) {   // A: 128 rows x 4 segs
      int u0 = uu * 256 + w * 64;
      int u = u0 + lane;
      int row = u >> 2, seg = u & 3;
      int ss = seg ^ swz4(row);
      gload16(A + (size_t)(c0 + row) * K + ak + ss * 8, Ad + u0 * 8);
    }
    {                                   // B: 64 rows x 4 segs
      int u0 = w * 64;
      int u = u0 + lane;
      int row = u >> 2, seg = u & 3;
      int ss = seg ^ swz4(row);
      gload16(B + (size_t)(d0 + row) * K + ak + ss * 8, Bd + u0 * 8);
    }
  };

  f32x4 acc[2][4];
#pragma unroll
  for (int i = 0; i < 2; ++i)
#pragma unroll
    for (int j = 0; j < 4; ++j) acc[i][j] = (f32x4){0.f, 0.f, 0.f, 0.f};

  stage(0, 0);
  int cur = 0;
  for (int ch = 0; ch < nch; ++ch) {
    __builtin_amdgcn_s_barrier();
    if (ch < nch - 1) {
      stage(cur ^ 1, ch + 1);
      asm volatile("s_waitcnt vmcnt(3)" ::: "memory");
    } else {
      asm volatile("s_waitcnt vmcnt(0)" ::: "memory");
    }
    __builtin_amdgcn_s_barrier();
    const short* Ab = &As[cur][0];
    const short* Bb = &Bs[cur][0];
    bf16x8 bfr[4];
#pragma unroll
    for (int j = 0; j < 4; ++j)
      bfr[j] = *(const bf16x8*)(Bb + (j * 16 + li) * 32 + (lg ^ fsw) * 8);
#pragma unroll
    for (int i = 0; i < 2; ++i) {
      bf16x8 afr = *(const bf16x8*)(Ab + ((w * 2 + i) * 16 + li) * 32 + (lg ^ fsw) * 8);
#pragma unroll
      for (int j = 0; j < 4; ++j)
        acc[i][j] = __builtin_amdgcn_mfma_f32_16x16x32_bf16(afr, bfr[j], acc[i][j], 0, 0, 0);
    }
    cur ^= 1;
  }
  float* outp = Spart + (size_t)z * 512 * 512;
#pragma unroll
  for (int j = 0; j < 4; ++j) {
    int d = d0 + j * 16 + li;
#pragma unroll
    for (int i = 0; i < 2; ++i)
#pragma unroll
      for (int reg = 0; reg < 4; ++reg)
        outp[(size_t)(c0 + (w * 2 + i) * 16 + lg * 4 + reg) * 512 + d] = acc[i][j][reg];
  }
}

// ---------------- assemble c = (c1+c2)/2 from closed form; loss partials ----------
__global__ void k_assemble(const float* __restrict__ Spart, const float* __restrict__ stats,
                           float* __restrict__ lossPart) {
  int c = blockIdx.x, tid = threadIdx.x;
  float muT = stats[0 * 512 + c], rsT = stats[1 * 512 + c], swT = stats[2 * 512 + c];
  float muV = stats[6 * 512 + c], rsV = stats[7 * 512 + c], swV = stats[8 * 512 + c];
  const float W = 64.0f, invB = 1.0f / 64.0f;
  float on = 0, off = 0;
  for (int d = tid; d < 512; d += 256) {
    float s1 = 0, s2 = 0;
    for (int sl = 0; sl < 8; sl++) {
      s1 += Spart[((size_t)sl * 512 + c) * 512 + d];
      s2 += Spart[((size_t)(8 + sl) * 512 + c) * 512 + d];
    }
    float muMV = stats[3 * 512 + d], rsMV = stats[4 * 512 + d], swMV = stats[5 * 512 + d];
    float muMT = stats[9 * 512 + d], rsMT = stats[10 * 512 + d], swMT = stats[11 * 512 + d];
    float c1 = (s1 - muT * swMV - muMV * swT + muT * muMV * W) * rsT * rsMV * invB;
    float c2 = (s2 - muV * swMT - muMT * swV + muV * muMT * W) * rsV * rsMT * invB;
    float cc = 0.5f * (c1 + c2);
    if (d == c) { float dd = cc - 1.0f; on += dd * dd; }
    else off += cc * cc;
  }
  __shared__ float r1[4], r2[4];
  for (int s = 1; s < 64; s <<= 1) { on += __shfl_xor(on, s); off += __shfl_xor(off, s); }
  if ((tid & 63) == 0) { r1[tid >> 6] = on; r2[tid >> 6] = off; }
  __syncthreads();
  if (tid == 0) {
    lossPart[c * 2] = r1[0] + r1[1] + r1[2] + r1[3];
    lossPart[c * 2 + 1] = r2[0] + r2[1] + r2[2] + r2[3];
  }
}

__global__ void k_loss(const float* __restrict__ lossPart, float* __restrict__ out) {
  int tid = threadIdx.x;
  float on = 0, off = 0;
  for (int i = tid; i < 512; i += 256) { on += lossPart[2 * i]; off += lossPart[2 * i + 1]; }
  __shared__ float r1[4], r2[4];
  for (int s = 1; s < 64; s <<= 1) { on += __shfl_xor(on, s); off += __shfl_xor(off, s); }
  if ((tid & 63) == 0) { r1[tid >> 6] = on; r2[tid >> 6] = off; }
  __syncthreads();
  if (tid == 0)
    out[8192] = 0.1f * ((r1[0] + r1[1] + r1[2] + r1[3]) +
                        0.06f * (r2[0] + r2[1] + r2[2] + r2[3]));
}

extern "C" void kernel_launch(void* const* d_in, const int* in_sizes, int n_in,
                              void* d_out, int out_size, void* d_ws, size_t ws_size,
                              hipStream_t stream) {
  (void)in_sizes; (void)n_in; (void)out_size; (void)ws_size;
  const float* v_tok  = (const float*)d_in[1];
  const float* t_tok  = (const float*)d_in[3];
  const float* Wv_tok = (const float*)d_in[8];
  const float* Wt_tok = (const float*)d_in[10];
  const float* bv_tok = (const float*)d_in[9];
  const float* bt_tok = (const float*)d_in[11];
  const float* wv_fc  = (const float*)d_in[12];
  const float* bv_fc  = (const float*)d_in[13];
  const float* wt_fc  = (const float*)d_in[14];
  const float* bt_fc  = (const float*)d_in[15];
  const int*   tlen   = (const int*)d_in[16];
  float* out = (float*)d_out;

  char* wsb = (char*)d_ws;
  // --- P [0, 27,131,904): phase1 {v_tok_bf, t_tok_bf, WvT, WtT} (dead after proj);
  //     phase2 (materialize on): {tTw, mvT, vTw}
  short* v_tok_bf = (short*)wsb;                       // 9,633,792 sh
  short* t_tok_bf = v_tok_bf + (size_t)9633792;        // 3,145,728 sh
  short* WvT      = t_tok_bf + (size_t)3145728;        //   393,216 sh
  short* WtT      = WvT + (size_t)393216;              //   393,216 sh
  short* tTw = (short*)wsb;                            // 512*4096 (alias, phase2)
  short* mvT = tTw + (size_t)2097152;                  // 512*4096
  short* vTw = mvT + (size_t)2097152;                  // 512*12544
  // --- Q [27,131,904, 44,171,264): phase-a {ve_bf, te_bf}; phase-b Spart (16 MB)
  short* ve_bf = (short*)(wsb + 27131904);             // 6,422,528 sh
  short* te_bf = ve_bf + (size_t)6422528;              // 2,097,152 sh
  float* Spart = (float*)(wsb + 27131904);             // 16*512*512 f (alias, phase-b)
  // --- mtT [44,171,264, 57,016,320)
  short* mtT = (short*)(wsb + 44171264);               // 512*12544
  // --- smalls at 57,016,320
  float* vwf = (float*)(wsb + 57016320);               // 12544
  float* twf = vwf + 12544;                            // 4096
  int* gMT = (int*)(twf + 4096);                       // 12544
  int* gMV = gMT + 12544;                              // 4096
  float* statPart = (float*)(gMV + 4096);              // 4*13*512*3
  float* stats = statPart + 79872;                     // 12*512
  float* lossPart = stats + 6144;                      // 1024

  k_tobf16_2<<<6240, 256, 0, stream>>>(v_tok, v_tok_bf, 1204224, t_tok, t_tok_bf, 393216);
  k_transpose_bf<<<dim3(24, 16, 2), dim3(32, 8), 0, stream>>>(Wv_tok, Wt_tok, WvT, WtT);
  k_proj_mfma<<<dim3(8, 98), 256, 0, stream>>>(v_tok_bf, WvT, bv_tok, ve_bf);
  k_proj_mfma<<<dim3(8, 32), 256, 0, stream>>>(t_tok_bf, WtT, bt_tok, te_bf);
  k_normfc<<<3136, 256, 0, stream>>>(ve_bf, wv_fc, bv_fc, vwf, 12544);
  k_normfc<<<1024, 256, 0, stream>>>(te_bf, wt_fc, bt_fc, twf, 4096);
  k_softmax<<<128, 256, 0, stream>>>(vwf, twf, tlen);
  k_sim<<<4096, 256, 0, stream>>>(ve_bf, te_bf, vwf, twf, out, gMT, gMV);
  k_stats<<<dim3(8, 13, 4), 256, 0, stream>>>(ve_bf, te_bf, gMT, gMV, vwf, twf, statPart);
  k_statfin<<<4, 512, 0, stream>>>(statPart, stats);
  k_materialize<<<dim3(196, 8, 4), 256, 0, stream>>>(ve_bf, te_bf, gMT, gMV, vwf, twf,
                                                     tTw, mvT, vTw, mtT);
  k_wgemm2<<<dim3(4, 8, 16), 256, 0, stream>>>(tTw, mvT, vTw, mtT, Spart);
  k_assemble<<<512, 256, 0, stream>>>(Spart, stats, lossPart);
  k_loss<<<1, 256, 0, stream>>>(lossPart, out);
}

// Round 11
// 313.762 us; speedup vs baseline: 2.8681x; 1.0176x over previous
//
#include <hip/hip_runtime.h>
#include <cstddef>

#define EDIM 512
#define KDIM 768
#define NB 64
#define NV 196
#define NT 64
#define MROWS_V (NB * NV) /* 12544 */
#define MROWS_T (NB * NT) /* 4096  */

typedef __attribute__((ext_vector_type(8))) short bf16x8;
typedef __attribute__((ext_vector_type(4))) float f32x4;

static __device__ inline unsigned short f2bf(float f) {  // round-to-nearest-even
  unsigned u = __float_as_uint(f);
  unsigned r = (u + 0x7fff + ((u >> 16) & 1)) >> 16;
  return (unsigned short)r;
}
static __device__ inline float bf2f(short s) {
  return __uint_as_float(((unsigned)(unsigned short)s) << 16);
}
// seg swizzle: for row-tiles read at fixed li, spreads bank-starts
static __device__ __forceinline__ int swz4(int r) { return (r + (r >> 2)) & 3; }

// async global->LDS, 16B per lane; LDS dest = wave-uniform base + lane*16
static __device__ __forceinline__ void gload16(const void* g, void* l) {
  __builtin_amdgcn_global_load_lds(
      (const __attribute__((address_space(1))) void*)g,
      (__attribute__((address_space(3))) void*)l, 16, 0, 0);
}

// ---------------- fp32 -> bf16 elementwise, both tensors in one launch ----------------
__global__ void k_tobf16_2(const float* __restrict__ ina, short* __restrict__ outa, int na8,
                           const float* __restrict__ inb, short* __restrict__ outb, int nb8) {
  int i = blockIdx.x * 256 + threadIdx.x;
  const float* in; short* outp; int idx;
  if (i < na8) { in = ina; outp = outa; idx = i; }
  else { idx = i - na8; if (idx >= nb8) return; in = inb; outp = outb; }
  float4 a = *(const float4*)(in + (size_t)idx * 8);
  float4 b = *(const float4*)(in + (size_t)idx * 8 + 4);
  bf16x8 v;
  v[0] = (short)f2bf(a.x); v[1] = (short)f2bf(a.y);
  v[2] = (short)f2bf(a.z); v[3] = (short)f2bf(a.w);
  v[4] = (short)f2bf(b.x); v[5] = (short)f2bf(b.y);
  v[6] = (short)f2bf(b.z); v[7] = (short)f2bf(b.w);
  *(bf16x8*)(outp + (size_t)idx * 8) = v;
}

// ---------------- transpose W [768x512] fp32 -> WT [512x768] bf16 ----------------
__global__ void k_transpose_bf(const float* __restrict__ W0, const float* __restrict__ W1,
                               short* __restrict__ T0, short* __restrict__ T1) {
  __shared__ float tile[32][33];
  const float* W = blockIdx.z ? W1 : W0;
  short*       T = blockIdx.z ? T1 : T0;
  int k0 = blockIdx.x * 32;
  int n0 = blockIdx.y * 32;
  int tx = threadIdx.x, ty = threadIdx.y;
  for (int i = ty; i < 32; i += 8)
    tile[i][tx] = W[(size_t)(k0 + i) * EDIM + n0 + tx];
  __syncthreads();
  for (int i = ty; i < 32; i += 8)
    T[(size_t)(n0 + i) * KDIM + k0 + tx] = (short)f2bf(tile[tx][i]);
}

// ---------- MFMA projection (merged v+t): Mbf[r,n] = bf16(X@WT + bias) ----
// dbuf + counted vmcnt(3); per-lane src pointers hoisted, advance 64B/kc.
__global__ __launch_bounds__(256, 4) void k_proj_mfma(
    const short* __restrict__ vX, const short* __restrict__ tX,
    const float* __restrict__ vb, const float* __restrict__ tb,
    short* __restrict__ vout, short* __restrict__ tout) {
  __shared__ short As[2][128 * 32];   // linear 64B rows
  __shared__ short Bs[2][64 * 32];
  int y = blockIdx.y;
  const short* Xbf; const short* WTb; const float* bias; short* Mbf; int r0;
  if (y < 98) { Xbf = vX; bias = vb; Mbf = vout; r0 = y * 128; WTb = tX; }
  else        { Xbf = tX; bias = tb; Mbf = tout; r0 = (y - 98) * 128; WTb = tX; }
  // WT pointers are passed via vX/tX trick? No -- WT passed separately below.
  (void)WTb;
  int n0 = blockIdx.x * 64;
  int tid = threadIdx.x;
  int w = tid >> 6, lane = tid & 63, lg = lane >> 4, li = lane & 15;
  int fsw = (li + (li >> 2)) & 3;

  // WT base comes in through vb/tb? -- no: use separate globals below.
  extern __device__ short dummy_unused[];
  // (WT pointers are provided via the separate parameters in launch; see below.)
  // NOTE: actual WT pointer passed via Mbf-adjacent params in kernel_launch.
  // To keep signature simple we re-derive: handled by caller passing WvT/WtT
  // in vX2/tX2 slots -- see k_proj_mfma2 wrapper below.
  // (This kernel body is completed in k_proj_mfma2.)
}

// Real merged projection kernel with explicit WT pointers.
__global__ __launch_bounds__(256, 4) void k_proj_mfma2(
    const short* __restrict__ vX, const short* __restrict__ tX,
    const short* __restrict__ WvT, const short* __restrict__ WtT,
    const float* __restrict__ vb, const float* __restrict__ tb,
    short* __restrict__ vout, short* __restrict__ tout) {
  __shared__ short As[2][128 * 32];
  __shared__ short Bs[2][64 * 32];
  int y = blockIdx.y;
  const short* Xbf; const short* WT; const float* bias; short* Mbf; int r0;
  if (y < 98) { Xbf = vX; WT = WvT; bias = vb; Mbf = vout; r0 = y * 128; }
  else        { Xbf = tX; WT = WtT; bias = tb; Mbf = tout; r0 = (y - 98) * 128; }
  int n0 = blockIdx.x * 64;
  int tid = threadIdx.x;
  int w = tid >> 6, lane = tid & 63, lg = lane >> 4, li = lane & 15;
  int fsw = (li + (li >> 2)) & 3;

  // hoisted per-lane global srcs (advance 32 shorts = 64B per kc)
  const short* aSrc[2];
#pragma unroll
  for (int uu = 0; uu < 2; ++uu) {
    int u = uu * 256 + w * 64 + lane;
    int row = u >> 2, seg = u & 3;
    int ss = seg ^ swz4(row);
    aSrc[uu] = Xbf + (size_t)(r0 + row) * KDIM + ss * 8;
  }
  const short* bSrc;
  {
    int u = w * 64 + lane;
    int row = u >> 2, seg = u & 3;
    int ss = seg ^ swz4(row);
    bSrc = WT + (size_t)(n0 + row) * KDIM + ss * 8;
  }

  auto stage = [&](int bb) {
    short* Ad = &As[bb][0];
    short* Bd = &Bs[bb][0];
#pragma unroll
    for (int uu = 0; uu < 2; ++uu) {
      gload16(aSrc[uu], Ad + (uu * 256 + w * 64) * 8);
      aSrc[uu] += 32;
    }
    gload16(bSrc, Bd + (w * 64) * 8);
    bSrc += 32;
  };

  f32x4 acc[2][4];
#pragma unroll
  for (int i = 0; i < 2; ++i)
#pragma unroll
    for (int j = 0; j < 4; ++j) acc[i][j] = (f32x4){0.f, 0.f, 0.f, 0.f};

  stage(0);   // 3 loads in flight
  int cur = 0;
  const int NKC = KDIM / 32;  // 24
  for (int kc = 0; kc < NKC; ++kc) {
    __builtin_amdgcn_s_barrier();          // readers of buf[cur^1] (prev iter) done
    if (kc < NKC - 1) {
      stage(cur ^ 1);                      // 3 new loads
      asm volatile("s_waitcnt vmcnt(3)" ::: "memory");  // old 3 complete
    } else {
      asm volatile("s_waitcnt vmcnt(0)" ::: "memory");
    }
    __builtin_amdgcn_s_barrier();          // buf[cur] visible to all waves
    const short* Ab = &As[cur][0];
    const short* Bb = &Bs[cur][0];
    bf16x8 bfr[4];
#pragma unroll
    for (int j = 0; j < 4; ++j)
      bfr[j] = *(const bf16x8*)(Bb + (j * 16 + li) * 32 + (lg ^ fsw) * 8);
#pragma unroll
    for (int i = 0; i < 2; ++i) {
      bf16x8 afr = *(const bf16x8*)(Ab + ((w * 2 + i) * 16 + li) * 32 + (lg ^ fsw) * 8);
#pragma unroll
      for (int j = 0; j < 4; ++j)
        acc[i][j] = __builtin_amdgcn_mfma_f32_16x16x32_bf16(afr, bfr[j], acc[i][j], 0, 0, 0);
    }
    cur ^= 1;
  }
#pragma unroll
  for (int j = 0; j < 4; ++j) {
    int n = n0 + j * 16 + li;
    float bb = bias[n];
#pragma unroll
    for (int i = 0; i < 2; ++i)
#pragma unroll
      for (int reg = 0; reg < 4; ++reg)
        Mbf[(size_t)(r0 + (w * 2 + i) * 16 + lg * 4 + reg) * EDIM + n] =
            (short)f2bf(acc[i][j][reg] + bb);
  }
}

// ------- per-row (bf16 in place): fc scalar (pre-norm) + l2 normalize -------
__global__ void k_normfc(short* __restrict__ Mbf, const float* __restrict__ fcw,
                         const float* __restrict__ fcb, float* __restrict__ wout,
                         int nrows) {
  int row = blockIdx.x * 4 + (threadIdx.x >> 6);
  int lane = threadIdx.x & 63;
  if (row >= nrows) return;
  short* p = Mbf + (size_t)row * EDIM + lane * 8;
  bf16x8 v = *(bf16x8*)p;
  float4 w0 = *(const float4*)(fcw + lane * 8);
  float4 w1 = *(const float4*)(fcw + lane * 8 + 4);
  float a[8];
#pragma unroll
  for (int j = 0; j < 8; ++j) a[j] = bf2f(v[j]);
  float dot = a[0] * w0.x + a[1] * w0.y + a[2] * w0.z + a[3] * w0.w +
              a[4] * w1.x + a[5] * w1.y + a[6] * w1.z + a[7] * w1.w;
  float ss = a[0] * a[0] + a[1] * a[1] + a[2] * a[2] + a[3] * a[3] +
             a[4] * a[4] + a[5] * a[5] + a[6] * a[6] + a[7] * a[7];
  for (int s = 1; s < 64; s <<= 1) {
    dot += __shfl_xor(dot, s);
    ss += __shfl_xor(ss, s);
  }
  float inv = 1.0f / fmaxf(sqrtf(ss), 1e-12f);
#pragma unroll
  for (int j = 0; j < 8; ++j) v[j] = (short)f2bf(a[j] * inv);
  *(bf16x8*)p = v;
  if (lane == 0) wout[row] = dot + fcb[0];
}

// ---------------- softmax: blocks 0..63 vw rows (196), 64..127 tw rows (64, masked) ----
__global__ void k_softmax(float* __restrict__ vwf, float* __restrict__ twf,
                          const int* __restrict__ tlen) {
  __shared__ float red[8];
  int tid = threadIdx.x;
  if (blockIdx.x < 64) {
    int b = blockIdx.x;
    float x = (tid < NV) ? vwf[b * NV + tid] : -1e30f;
    float m = x;
    for (int s = 1; s < 64; s <<= 1) m = fmaxf(m, __shfl_xor(m, s));
    if ((tid & 63) == 0) red[tid >> 6] = m;
    __syncthreads();
    m = fmaxf(fmaxf(red[0], red[1]), fmaxf(red[2], red[3]));
    float e = (tid < NV) ? expf(x - m) : 0.0f;
    float s = e;
    for (int st = 1; st < 64; st <<= 1) s += __shfl_xor(s, st);
    if ((tid & 63) == 0) red[4 + (tid >> 6)] = s;
    __syncthreads();
    s = red[4] + red[5] + red[6] + red[7];
    if (tid < NV) vwf[b * NV + tid] = e / s;
  } else {
    int b = blockIdx.x - 64;
    if (tid < 64) {
      int len = tlen[b];
      float x = twf[b * NT + tid];
      bool valid = tid < len;
      float xv = valid ? x : -1e30f;
      float m = xv;
      for (int s = 1; s < 64; s <<= 1) m = fmaxf(m, __shfl_xor(m, s));
      float e = valid ? expf(x - m) : 0.0f;
      float s = e;
      for (int st = 1; st < 64; st <<= 1) s += __shfl_xor(s, st);
      twf[b * NT + tid] = e / s;
    }
  }
}

// ---------------- MFMA sim kernel: one block per (b, q), XCD-chunked ----------------
// 13 row-tiles (w0: tiles 0-3, w1-3: 3 tiles each); hoisted src pointers.
__global__ __launch_bounds__(256, 4) void k_sim(
    const short* __restrict__ ve_bf, const short* __restrict__ te_bf,
    const float* __restrict__ vwf, const float* __restrict__ twf,
    float* __restrict__ out, int* __restrict__ gMT, int* __restrict__ gMV) {
  __shared__ short As[208 * 32];   // linear, 64B row stride
  __shared__ short Bs[64 * 32];
  __shared__ float colv[4][64];
  __shared__ int   coli[4][64];
  __shared__ float redp[4];
  int n = blockIdx.x;
  int xcd = n & 7, idx = n >> 3;
  int b = xcd * 8 + (idx & 7);     // b-fastest within XCD chunk (ve L2-resident)
  int q = idx >> 3;                // 0..63
  int tid = threadIdx.x;
  int w = tid >> 6, lane = tid & 63, lg = lane >> 4, li = lane & 15;
  const short* Abf = ve_bf + (size_t)b * NV * EDIM;
  const short* Bbf = te_bf + (size_t)q * NT * EDIM;
  int fsw = (li + (li >> 2)) & 3;
  int nt = w ? 3 : 4;              // wave tile count (13 tiles total)
  int tbase = w ? (1 + w * 3) : 0; // w0:0-3, w1:4-6, w2:7-9, w3:10-12

  // hoisted per-lane global srcs (advance 32 shorts = 64B per kc)
  const short* aSrc[4];
#pragma unroll
  for (int uu = 0; uu < 4; ++uu) {
    int u = uu * 256 + w * 64 + lane;
    int row = u >> 2;
    if (row > NV - 1) row = NV - 1;
    int seg = u & 3;
    int ss = seg ^ swz4(row);
    aSrc[uu] = Abf + (size_t)row * EDIM + ss * 8;
  }
  const short* bSrc;
  {
    int u = w * 64 + lane;
    int row = u >> 2, seg = u & 3;
    int ss = seg ^ swz4(row);
    bSrc = Bbf + (size_t)row * EDIM + ss * 8;
  }

  f32x4 acc[4][4];
#pragma unroll
  for (int i = 0; i < 4; ++i)
#pragma unroll
    for (int j = 0; j < 4; ++j) acc[i][j] = (f32x4){0.f, 0.f, 0.f, 0.f};

  for (int kc = 0; kc < 16; ++kc) {
    __syncthreads();   // prior kc's frag reads done before DMA overwrite
    gload16(bSrc, Bs + (w * 64) * 8);
    bSrc += 32;
#pragma unroll
    for (int uu = 0; uu < 4; ++uu) {
      int u0 = uu * 256 + w * 64;
      if (u0 < NV * 4) {
        gload16(aSrc[uu], As + u0 * 8);
        aSrc[uu] += 32;
      }
    }
    __syncthreads();   // vmcnt(0) drain -> tile visible (hidden by 4 blocks/CU)
    bf16x8 bfr[4];
#pragma unroll
    for (int j = 0; j < 4; ++j)
      bfr[j] = *(const bf16x8*)(Bs + (j * 16 + li) * 32 + (lg ^ fsw) * 8);
    __builtin_amdgcn_s_setprio(1);
#pragma unroll
    for (int i = 0; i < 4; ++i) {
      if (i < nt) {
        int T = tbase + i;
        bf16x8 afr = *(const bf16x8*)(As + (T * 16 + li) * 32 + (lg ^ fsw) * 8);
#pragma unroll
        for (int j = 0; j < 4; ++j)
          acc[i][j] = __builtin_amdgcn_mfma_f32_16x16x32_bf16(afr, bfr[j], acc[i][j], 0, 0, 0);
      }
    }
    __builtin_amdgcn_s_setprio(0);
  }

  bool diag = (b == q);
  // ---- row (over t) max+argmax; C layout: row=T*16+lg*4+reg, col=j*16+li
  float ip = 0.f;
#pragma unroll
  for (int i = 0; i < 4; ++i) {
    if (i < nt) {
#pragma unroll
      for (int reg = 0; reg < 4; ++reg) {
        int v = (tbase + i) * 16 + lg * 4 + reg;
        float m = acc[i][0][reg];
        int ti = li;
#pragma unroll
        for (int j = 1; j < 4; ++j) {
          float vv = acc[i][j][reg];
          int t = j * 16 + li;
          if (vv > m) { m = vv; ti = t; }   // t ascending -> first-index kept
        }
        for (int d = 1; d < 16; d <<= 1) {  // within li-group (same row)
          float om = __shfl_xor(m, d);
          int oi = __shfl_xor(ti, d);
          if (om > m || (om == m && oi < ti)) { m = om; ti = oi; }
        }
        if (li == 0 && v < NV) {
          ip += vwf[b * NV + v] * m;
          if (diag) gMT[b * NV + v] = b * NT + ti;
        }
      }
    }
  }
  for (int d = 1; d < 64; d <<= 1) ip += __shfl_xor(ip, d);
  if (lane == 0) redp[w] = ip;
  // ---- col (over v) max+argmax for this wave's rows
  float cm[4]; int cv[4];
#pragma unroll
  for (int j = 0; j < 4; ++j) { cm[j] = -3.0e38f; cv[j] = 0; }
#pragma unroll
  for (int i = 0; i < 4; ++i) {
    if (i < nt) {
#pragma unroll
      for (int reg = 0; reg < 4; ++reg) {
        int v = (tbase + i) * 16 + lg * 4 + reg;
        bool ok = v < NV;
#pragma unroll
        for (int j = 0; j < 4; ++j) {
          float s = ok ? acc[i][j][reg] : -3.0e38f;
          if (s > cm[j]) { cm[j] = s; cv[j] = v; }  // v ascending per lane
        }
      }
    }
  }
#pragma unroll
  for (int j = 0; j < 4; ++j) {
    for (int d = 16; d < 64; d <<= 1) {   // mixes lg groups (same col)
      float om = __shfl_xor(cm[j], d);
      int ov = __shfl_xor(cv[j], d);
      if (om > cm[j] || (om == cm[j] && ov < cv[j])) { cm[j] = om; cv[j] = ov; }
    }
    if (lg == 0) { colv[w][j * 16 + li] = cm[j]; coli[w][j * 16 + li] = cv[j]; }
  }
  __syncthreads();
  if (tid < 64) {
    int t = tid;
    float m = colv[0][t];
    int bi = coli[0][t];
#pragma unroll
    for (int w2 = 1; w2 < 4; ++w2) {
      float om = colv[w2][t];
      int ov = coli[w2][t];
      if (om > m || (om == m && ov < bi)) { m = om; bi = ov; }
    }
    if (diag) gMV[b * NT + t] = b * NV + bi;
    float p = twf[q * NT + t] * m;
    for (int d = 1; d < 64; d <<= 1) p += __shfl_xor(p, d);
    if (t == 0) out[4096 + b * 64 + q] = p;
  }
  if (tid == 0) out[b * 64 + q] = redp[0] + redp[1] + redp[2] + redp[3];
}

// ---------------- column stats from bf16 (sum, sumsq, weighted sum) ------
__global__ void k_stats(const short* __restrict__ ve_bf, const short* __restrict__ te_bf,
                        const int* __restrict__ gMT, const int* __restrict__ gMV,
                        const float* __restrict__ vwf, const float* __restrict__ twf,
                        float* __restrict__ statPart) {
  int stripe = blockIdx.x, chunk = blockIdx.y, m = blockIdx.z;
  int R = (m < 2) ? MROWS_T : MROWS_V;
  int nchunk = (R + 1023) >> 10;
  if (chunk >= nchunk) return;
  const short* M; const int* g; const float* w;
  if (m == 0)      { M = te_bf; g = 0;   w = twf; }
  else if (m == 1) { M = ve_bf; g = gMV; w = twf; }
  else if (m == 2) { M = ve_bf; g = 0;   w = vwf; }
  else             { M = te_bf; g = gMT; w = vwf; }
  int col = stripe * 64 + (threadIdx.x & 63);
  int rg = threadIdx.x >> 6;
  int r0 = chunk << 10;
  int r1 = min(r0 + 1024, R);
  float s = 0, ss = 0, sw = 0;
  for (int r = r0 + rg; r < r1; r += 4) {
    int row = g ? g[r] : r;
    float x = bf2f(M[(size_t)row * EDIM + col]);
    s += x; ss += x * x; sw += w[r] * x;
  }
  __shared__ float red[3][256];
  red[0][threadIdx.x] = s; red[1][threadIdx.x] = ss; red[2][threadIdx.x] = sw;
  __syncthreads();
  if (threadIdx.x < 64) {
    int c = threadIdx.x;
    float S  = red[0][c] + red[0][c + 64] + red[0][c + 128] + red[0][c + 192];
    float SS = red[1][c] + red[1][c + 64] + red[1][c + 128] + red[1][c + 192];
    float SW = red[2][c] + red[2][c + 64] + red[2][c + 128] + red[2][c + 192];
    size_t idx = ((size_t)(m * 13 + chunk) * 512 + stripe * 64 + c) * 3;
    statPart[idx] = S; statPart[idx + 1] = SS; statPart[idx + 2] = SW;
  }
}

__global__ void k_statfin(const float* __restrict__ statPart, float* __restrict__ stats) {
  int m = blockIdx.x, c = threadIdx.x;
  int R = (m < 2) ? MROWS_T : MROWS_V;
  int nchunk = (R + 1023) >> 10;
  float s = 0, ss = 0, sw = 0;
  for (int ch = 0; ch < nchunk; ch++) {
    size_t idx = ((size_t)(m * 13 + ch) * 512 + c) * 3;
    s += statPart[idx]; ss += statPart[idx + 1]; sw += statPart[idx + 2];
  }
  float mean = s / R;
  float var = (ss - s * mean) / (R - 1);  // ddof=1
  float rstd = 1.0f / sqrtf(var);
  stats[(m * 3 + 0) * 512 + c] = mean;
  stats[(m * 3 + 1) * 512 + c] = rstd;
  stats[(m * 3 + 2) * 512 + c] = sw;
}

// ------- transpose-materialize a-contiguous bf16 operands (w and gathers folded) ----
__global__ void k_materialize(const short* __restrict__ ve_bf, const short* __restrict__ te_bf,
                              const int* __restrict__ gMT, const int* __restrict__ gMV,
                              const float* __restrict__ vwf, const float* __restrict__ twf,
                              short* __restrict__ tTw, short* __restrict__ mvT,
                              short* __restrict__ vTw, short* __restrict__ mtT) {
  int z = blockIdx.z;
  int at = blockIdx.x, ct = blockIdx.y;
  int K = (z == 2 || z == 3) ? MROWS_V : MROWS_T;
  if (at * 64 >= K) return;
  const short* src; const int* g = 0; const float* w = 0; short* dst;
  if (z == 0)      { src = te_bf; w = twf; dst = tTw; }
  else if (z == 1) { src = ve_bf; g = gMV; dst = mvT; }
  else if (z == 2) { src = ve_bf; w = vwf; dst = vTw; }
  else             { src = te_bf; g = gMT; dst = mtT; }
  __shared__ float tile[64][67];
  int tid = threadIdx.x;
  for (int u = tid; u < 512; u += 256) {
    int a = u >> 3, cseg = (u & 7) << 3;
    int ga = at * 64 + a;
    int row = g ? g[ga] : ga;
    bf16x8 vv = *(const bf16x8*)(src + (size_t)row * EDIM + ct * 64 + cseg);
    float wa = w ? w[ga] : 1.0f;
#pragma unroll
    for (int j = 0; j < 8; j++) tile[a][cseg + j] = wa * bf2f(vv[j]);
  }
  __syncthreads();
  for (int u = tid; u < 512; u += 256) {
    int c = u >> 3, aseg = (u & 7) << 3;
    bf16x8 ov;
#pragma unroll
    for (int j = 0; j < 8; j++) ov[j] = (short)f2bf(tile[aseg + j][c]);
    *(bf16x8*)(dst + (size_t)(ct * 64 + c) * K + at * 64 + aseg) = ov;
  }
}

// ------- MFMA weighted GEMM: Spart[z][c][d] = sum_a AT[c][a]*BT[d][a] (split-K 8) ----
__global__ __launch_bounds__(256, 4) void k_wgemm2(
    const short* __restrict__ tTw, const short* __restrict__ mvT,
    const short* __restrict__ vTw, const short* __restrict__ mtT,
    float* __restrict__ Spart) {
  __shared__ short As[2][128 * 32];
  __shared__ short Bs[2][64 * 32];
  int c0 = blockIdx.x * 128, d0 = blockIdx.y * 64;
  int z = blockIdx.z;                 // 0..15
  int which = z >> 3, slice = z & 7;
  const short* A = which ? vTw : tTw;
  const short* B = which ? mtT : mvT;
  int K = which ? MROWS_V : MROWS_T;
  int nch = (K >> 3) >> 5;            // 49 or 16 chunks of 32
  int a0 = slice * (K >> 3);
  int tid = threadIdx.x;
  int w = tid >> 6, lane = tid & 63, lg = lane >> 4, li = lane & 15;
  int fsw = (li + (li >> 2)) & 3;

  const short* aSrc[2];
#pragma unroll
  for (int uu = 0; uu < 2; ++uu) {
    int u = uu * 256 + w * 64 + lane;
    int row = u >> 2, seg = u & 3;
    int ss = seg ^ swz4(row);
    aSrc[uu] = A + (size_t)(c0 + row) * K + a0 + ss * 8;
  }
  const short* bSrc;
  {
    int u = w * 64 + lane;
    int row = u >> 2, seg = u & 3;
    int ss = seg ^ swz4(row);
    bSrc = B + (size_t)(d0 + row) * K + a0 + ss * 8;
  }

  auto stage = [&](int bb) {
    short* Ad = &As[bb][0];
    short* Bd = &Bs[bb][0];
#pragma unroll
    for (int uu = 0; uu < 2; ++uu) {
      gload16(aSrc[uu], Ad + (uu * 256 + w * 64) * 8);
      aSrc[uu] += 32;
    }
    gload16(bSrc, Bd + (w * 64) * 8);
    bSrc += 32;
  };

  f32x4 acc[2][4];
#pragma unroll
  for (int i = 0; i < 2; ++i)
#pragma unroll
    for (int j = 0; j < 4; ++j) acc[i][j] = (f32x4){0.f, 0.f, 0.f, 0.f};

  stage(0);
  int cur = 0;
  for (int ch = 0; ch < nch; ++ch) {
    __builtin_amdgcn_s_barrier();
    if (ch < nch - 1) {
      stage(cur ^ 1);
      asm volatile("s_waitcnt vmcnt(3)" ::: "memory");
    } else {
      asm volatile("s_waitcnt vmcnt(0)" ::: "memory");
    }
    __builtin_amdgcn_s_barrier();
    const short* Ab = &As[cur][0];
    const short* Bb = &Bs[cur][0];
    bf16x8 bfr[4];
#pragma unroll
    for (int j = 0; j < 4; ++j)
      bfr[j] = *(const bf16x8*)(Bb + (j * 16 + li) * 32 + (lg ^ fsw) * 8);
#pragma unroll
    for (int i = 0; i < 2; ++i) {
      bf16x8 afr = *(const bf16x8*)(Ab + ((w * 2 + i) * 16 + li) * 32 + (lg ^ fsw) * 8);
#pragma unroll
      for (int j = 0; j < 4; ++j)
        acc[i][j] = __builtin_amdgcn_mfma_f32_16x16x32_bf16(afr, bfr[j], acc[i][j], 0, 0, 0);
    }
    cur ^= 1;
  }
  float* outp = Spart + (size_t)z * 512 * 512;
#pragma unroll
  for (int j = 0; j < 4; ++j) {
    int d = d0 + j * 16 + li;
#pragma unroll
    for (int i = 0; i < 2; ++i)
#pragma unroll
      for (int reg = 0; reg < 4; ++reg)
        outp[(size_t)(c0 + (w * 2 + i) * 16 + lg * 4 + reg) * 512 + d] = acc[i][j][reg];
  }
}

// ---------------- assemble c = (c1+c2)/2 from closed form; loss partials ----------
__global__ void k_assemble(const float* __restrict__ Spart, const float* __restrict__ stats,
                           float* __restrict__ lossPart) {
  int c = blockIdx.x, tid = threadIdx.x;
  float muT = stats[0 * 512 + c], rsT = stats[1 * 512 + c], swT = stats[2 * 512 + c];
  float muV = stats[6 * 512 + c], rsV = stats[7 * 512 + c], swV = stats[8 * 512 + c];
  const float W = 64.0f, invB = 1.0f / 64.0f;
  float on = 0, off = 0;
  for (int d = tid; d < 512; d += 256) {
    float s1 = 0, s2 = 0;
    for (int sl = 0; sl < 8; sl++) {
      s1 += Spart[((size_t)sl * 512 + c) * 512 + d];
      s2 += Spart[((size_t)(8 + sl) * 512 + c) * 512 + d];
    }
    float muMV = stats[3 * 512 + d], rsMV = stats[4 * 512 + d], swMV = stats[5 * 512 + d];
    float muMT = stats[9 * 512 + d], rsMT = stats[10 * 512 + d], swMT = stats[11 * 512 + d];
    float c1 = (s1 - muT * swMV - muMV * swT + muT * muMV * W) * rsT * rsMV * invB;
    float c2 = (s2 - muV * swMT - muMT * swV + muV * muMT * W) * rsV * rsMT * invB;
    float cc = 0.5f * (c1 + c2);
    if (d == c) { float dd = cc - 1.0f; on += dd * dd; }
    else off += cc * cc;
  }
  __shared__ float r1[4], r2[4];
  for (int s = 1; s < 64; s <<= 1) { on += __shfl_xor(on, s); off += __shfl_xor(off, s); }
  if ((tid & 63) == 0) { r1[tid >> 6] = on; r2[tid >> 6] = off; }
  __syncthreads();
  if (tid == 0) {
    lossPart[c * 2] = r1[0] + r1[1] + r1[2] + r1[3];
    lossPart[c * 2 + 1] = r2[0] + r2[1] + r2[2] + r2[3];
  }
}

__global__ void k_loss(const float* __restrict__ lossPart, float* __restrict__ out) {
  int tid = threadIdx.x;
  float on = 0, off = 0;
  for (int i = tid; i < 512; i += 256) { on += lossPart[2 * i]; off += lossPart[2 * i + 1]; }
  __shared__ float r1[4], r2[4];
  for (int s = 1; s < 64; s <<= 1) { on += __shfl_xor(on, s); off += __shfl_xor(off, s); }
  if ((tid & 63) == 0) { r1[tid >> 6] = on; r2[tid >> 6] = off; }
  __syncthreads();
  if (tid == 0)
    out[8192] = 0.1f * ((r1[0] + r1[1] + r1[2] + r1[3]) +
                        0.06f * (r2[0] + r2[1] + r2[2] + r2[3]));
}

extern "C" void kernel_launch(void* const* d_in, const int* in_sizes, int n_in,
                              void* d_out, int out_size, void* d_ws, size_t ws_size,
                              hipStream_t stream) {
  (void)in_sizes; (void)n_in; (void)out_size; (void)ws_size;
  const float* v_tok  = (const float*)d_in[1];
  const float* t_tok  = (const float*)d_in[3];
  const float* Wv_tok = (const float*)d_in[8];
  const float* Wt_tok = (const float*)d_in[10];
  const float* bv_tok = (const float*)d_in[9];
  const float* bt_tok = (const float*)d_in[11];
  const float* wv_fc  = (const float*)d_in[12];
  const float* bv_fc  = (const float*)d_in[13];
  const float* wt_fc  = (const float*)d_in[14];
  const float* bt_fc  = (const float*)d_in[15];
  const int*   tlen   = (const int*)d_in[16];
  float* out = (float*)d_out;

  char* wsb = (char*)d_ws;
  // --- P [0, 27,131,904): phase1 {v_tok_bf, t_tok_bf, WvT, WtT} (dead after proj);
  //     phase2 (materialize on): {tTw, mvT, vTw}
  short* v_tok_bf = (short*)wsb;                       // 9,633,792 sh
  short* t_tok_bf = v_tok_bf + (size_t)9633792;        // 3,145,728 sh
  short* WvT      = t_tok_bf + (size_t)3145728;        //   393,216 sh
  short* WtT      = WvT + (size_t)393216;              //   393,216 sh
  short* tTw = (short*)wsb;                            // 512*4096 (alias, phase2)
  short* mvT = tTw + (size_t)2097152;                  // 512*4096
  short* vTw = mvT + (size_t)2097152;                  // 512*12544
  // --- Q [27,131,904, 44,171,264): phase-a {ve_bf, te_bf}; phase-b Spart (16 MB)
  short* ve_bf = (short*)(wsb + 27131904);             // 6,422,528 sh
  short* te_bf = ve_bf + (size_t)6422528;              // 2,097,152 sh
  float* Spart = (float*)(wsb + 27131904);             // 16*512*512 f (alias, phase-b)
  // --- mtT [44,171,264, 57,016,320)
  short* mtT = (short*)(wsb + 44171264);               // 512*12544
  // --- smalls at 57,016,320
  float* vwf = (float*)(wsb + 57016320);               // 12544
  float* twf = vwf + 12544;                            // 4096
  int* gMT = (int*)(twf + 4096);                       // 12544
  int* gMV = gMT + 12544;                              // 4096
  float* statPart = (float*)(gMV + 4096);              // 4*13*512*3
  float* stats = statPart + 79872;                     // 12*512
  float* lossPart = stats + 6144;                      // 1024

  k_tobf16_2<<<6240, 256, 0, stream>>>(v_tok, v_tok_bf, 1204224, t_tok, t_tok_bf, 393216);
  k_transpose_bf<<<dim3(24, 16, 2), dim3(32, 8), 0, stream>>>(Wv_tok, Wt_tok, WvT, WtT);
  k_proj_mfma2<<<dim3(8, 130), 256, 0, stream>>>(v_tok_bf, t_tok_bf, WvT, WtT,
                                                 bv_tok, bt_tok, ve_bf, te_bf);
  k_normfc<<<3136, 256, 0, stream>>>(ve_bf, wv_fc, bv_fc, vwf, 12544);
  k_normfc<<<1024, 256, 0, stream>>>(te_bf, wt_fc, bt_fc, twf, 4096);
  k_softmax<<<128, 256, 0, stream>>>(vwf, twf, tlen);
  k_sim<<<4096, 256, 0, stream>>>(ve_bf, te_bf, vwf, twf, out, gMT, gMV);
  k_stats<<<dim3(8, 13, 4), 256, 0, stream>>>(ve_bf, te_bf, gMT, gMV, vwf, twf, statPart);
  k_statfin<<<4, 512, 0, stream>>>(statPart, stats);
  k_materialize<<<dim3(196, 8, 4), 256, 0, stream>>>(ve_bf, te_bf, gMT, gMV, vwf, twf,
                                                     tTw, mvT, vTw, mtT);
  k_wgemm2<<<dim3(4, 8, 16), 256, 0, stream>>>(tTw, mvT, vTw, mtT, Spart);
  k_assemble<<<512, 256, 0, stream>>>(Spart, stats, lossPart);
  k_loss<<<1, 256, 0, stream>>>(lossPart, out);
}

// Round 12
// 301.728 us; speedup vs baseline: 2.9825x; 1.0399x over previous
//
#include <hip/hip_runtime.h>
#include <cstddef>

#define EDIM 512
#define KDIM 768
#define NB 64
#define NV 196
#define NT 64
#define MROWS_V (NB * NV) /* 12544 */
#define MROWS_T (NB * NT) /* 4096  */

typedef __attribute__((ext_vector_type(8))) short bf16x8;
typedef __attribute__((ext_vector_type(4))) float f32x4;

static __device__ inline unsigned short f2bf(float f) {  // round-to-nearest-even
  unsigned u = __float_as_uint(f);
  unsigned r = (u + 0x7fff + ((u >> 16) & 1)) >> 16;
  return (unsigned short)r;
}
static __device__ inline float bf2f(short s) {
  return __uint_as_float(((unsigned)(unsigned short)s) << 16);
}
// seg swizzle: for row-tiles read at fixed li, spreads bank-starts
static __device__ __forceinline__ int swz4(int r) { return (r + (r >> 2)) & 3; }

// async global->LDS, 16B per lane; LDS dest = wave-uniform base + lane*16
static __device__ __forceinline__ void gload16(const void* g, void* l) {
  __builtin_amdgcn_global_load_lds(
      (const __attribute__((address_space(1))) void*)g,
      (__attribute__((address_space(3))) void*)l, 16, 0, 0);
}

// ------- merged prep: fp32->bf16 convert (v_tok,t_tok) + W transpose->bf16 -------
__global__ void k_prep(const float* __restrict__ va, short* __restrict__ vo, int na8,
                       const float* __restrict__ ta, short* __restrict__ to, int nb8,
                       const float* __restrict__ W0, const float* __restrict__ W1,
                       short* __restrict__ T0, short* __restrict__ T1) {
  __shared__ float tile[32][33];
  int blk = blockIdx.x;
  int tid = threadIdx.x;
  if (blk < 6240) {
    int i = blk * 256 + tid;
    const float* in; short* outp; int idx;
    if (i < na8) { in = va; outp = vo; idx = i; }
    else { idx = i - na8; if (idx >= nb8) return; in = ta; outp = to; }
    float4 a = *(const float4*)(in + (size_t)idx * 8);
    float4 b = *(const float4*)(in + (size_t)idx * 8 + 4);
    bf16x8 v;
    v[0] = (short)f2bf(a.x); v[1] = (short)f2bf(a.y);
    v[2] = (short)f2bf(a.z); v[3] = (short)f2bf(a.w);
    v[4] = (short)f2bf(b.x); v[5] = (short)f2bf(b.y);
    v[6] = (short)f2bf(b.z); v[7] = (short)f2bf(b.w);
    *(bf16x8*)(outp + (size_t)idx * 8) = v;
  } else {
    int z = blk - 6240;            // 0..767 = 24 x 16 x 2
    int bx = z % 24, by = (z / 24) % 16, bz = z / 384;
    const float* W = bz ? W1 : W0;
    short*       T = bz ? T1 : T0;
    int k0 = bx * 32, n0 = by * 32;
    int tx = tid & 31, ty = tid >> 5;
    for (int i = ty; i < 32; i += 8)
      tile[i][tx] = W[(size_t)(k0 + i) * EDIM + n0 + tx];
    __syncthreads();
    for (int i = ty; i < 32; i += 8)
      T[(size_t)(n0 + i) * KDIM + k0 + tx] = (short)f2bf(tile[tx][i]);
  }
}

// ---------- MFMA projection (merged v+t): Mbf[r,n] = bf16(X@WT + bias) ----
// dbuf + counted vmcnt(3); per-lane src pointers hoisted, advance 64B/kc.
__global__ __launch_bounds__(256, 4) void k_proj_mfma2(
    const short* __restrict__ vX, const short* __restrict__ tX,
    const short* __restrict__ WvT, const short* __restrict__ WtT,
    const float* __restrict__ vb, const float* __restrict__ tb,
    short* __restrict__ vout, short* __restrict__ tout) {
  __shared__ short As[2][128 * 32];
  __shared__ short Bs[2][64 * 32];
  int y = blockIdx.y;
  const short* Xbf; const short* WT; const float* bias; short* Mbf; int r0;
  if (y < 98) { Xbf = vX; WT = WvT; bias = vb; Mbf = vout; r0 = y * 128; }
  else        { Xbf = tX; WT = WtT; bias = tb; Mbf = tout; r0 = (y - 98) * 128; }
  int n0 = blockIdx.x * 64;
  int tid = threadIdx.x;
  int w = tid >> 6, lane = tid & 63, lg = lane >> 4, li = lane & 15;
  int fsw = (li + (li >> 2)) & 3;

  const short* aSrc[2];
#pragma unroll
  for (int uu = 0; uu < 2; ++uu) {
    int u = uu * 256 + w * 64 + lane;
    int row = u >> 2, seg = u & 3;
    int ss = seg ^ swz4(row);
    aSrc[uu] = Xbf + (size_t)(r0 + row) * KDIM + ss * 8;
  }
  const short* bSrc;
  {
    int u = w * 64 + lane;
    int row = u >> 2, seg = u & 3;
    int ss = seg ^ swz4(row);
    bSrc = WT + (size_t)(n0 + row) * KDIM + ss * 8;
  }

  auto stage = [&](int bb) {
    short* Ad = &As[bb][0];
    short* Bd = &Bs[bb][0];
#pragma unroll
    for (int uu = 0; uu < 2; ++uu) {
      gload16(aSrc[uu], Ad + (uu * 256 + w * 64) * 8);
      aSrc[uu] += 32;
    }
    gload16(bSrc, Bd + (w * 64) * 8);
    bSrc += 32;
  };

  f32x4 acc[2][4];
#pragma unroll
  for (int i = 0; i < 2; ++i)
#pragma unroll
    for (int j = 0; j < 4; ++j) acc[i][j] = (f32x4){0.f, 0.f, 0.f, 0.f};

  stage(0);
  int cur = 0;
  const int NKC = KDIM / 32;  // 24
  for (int kc = 0; kc < NKC; ++kc) {
    __builtin_amdgcn_s_barrier();
    if (kc < NKC - 1) {
      stage(cur ^ 1);
      asm volatile("s_waitcnt vmcnt(3)" ::: "memory");
    } else {
      asm volatile("s_waitcnt vmcnt(0)" ::: "memory");
    }
    __builtin_amdgcn_s_barrier();
    const short* Ab = &As[cur][0];
    const short* Bb = &Bs[cur][0];
    bf16x8 bfr[4];
#pragma unroll
    for (int j = 0; j < 4; ++j)
      bfr[j] = *(const bf16x8*)(Bb + (j * 16 + li) * 32 + (lg ^ fsw) * 8);
#pragma unroll
    for (int i = 0; i < 2; ++i) {
      bf16x8 afr = *(const bf16x8*)(Ab + ((w * 2 + i) * 16 + li) * 32 + (lg ^ fsw) * 8);
#pragma unroll
      for (int j = 0; j < 4; ++j)
        acc[i][j] = __builtin_amdgcn_mfma_f32_16x16x32_bf16(afr, bfr[j], acc[i][j], 0, 0, 0);
    }
    cur ^= 1;
  }
#pragma unroll
  for (int j = 0; j < 4; ++j) {
    int n = n0 + j * 16 + li;
    float bb = bias[n];
#pragma unroll
    for (int i = 0; i < 2; ++i)
#pragma unroll
      for (int reg = 0; reg < 4; ++reg)
        Mbf[(size_t)(r0 + (w * 2 + i) * 16 + lg * 4 + reg) * EDIM + n] =
            (short)f2bf(acc[i][j][reg] + bb);
  }
}

// ------- per-row (bf16 in place): fc scalar + l2 normalize; merged v+t -------
__global__ void k_normfc2(short* __restrict__ vM, short* __restrict__ tM,
                          const float* __restrict__ vfcw, const float* __restrict__ tfcw,
                          const float* __restrict__ vfcb, const float* __restrict__ tfcb,
                          float* __restrict__ vwout, float* __restrict__ twout) {
  int blk = blockIdx.x;
  short* Mbf; const float* fcw; const float* fcb; float* wout; int row;
  if (blk < 3136) { Mbf = vM; fcw = vfcw; fcb = vfcb; wout = vwout;
                    row = blk * 4 + (threadIdx.x >> 6); if (row >= 12544) return; }
  else            { Mbf = tM; fcw = tfcw; fcb = tfcb; wout = twout;
                    row = (blk - 3136) * 4 + (threadIdx.x >> 6); if (row >= 4096) return; }
  int lane = threadIdx.x & 63;
  short* p = Mbf + (size_t)row * EDIM + lane * 8;
  bf16x8 v = *(bf16x8*)p;
  float4 w0 = *(const float4*)(fcw + lane * 8);
  float4 w1 = *(const float4*)(fcw + lane * 8 + 4);
  float a[8];
#pragma unroll
  for (int j = 0; j < 8; ++j) a[j] = bf2f(v[j]);
  float dot = a[0] * w0.x + a[1] * w0.y + a[2] * w0.z + a[3] * w0.w +
              a[4] * w1.x + a[5] * w1.y + a[6] * w1.z + a[7] * w1.w;
  float ss = a[0] * a[0] + a[1] * a[1] + a[2] * a[2] + a[3] * a[3] +
             a[4] * a[4] + a[5] * a[5] + a[6] * a[6] + a[7] * a[7];
  for (int s = 1; s < 64; s <<= 1) {
    dot += __shfl_xor(dot, s);
    ss += __shfl_xor(ss, s);
  }
  float inv = 1.0f / fmaxf(sqrtf(ss), 1e-12f);
#pragma unroll
  for (int j = 0; j < 8; ++j) v[j] = (short)f2bf(a[j] * inv);
  *(bf16x8*)p = v;
  if (lane == 0) wout[row] = dot + fcb[0];
}

// ---------------- softmax: blocks 0..63 vw rows (196), 64..127 tw rows (64, masked) ----
__global__ void k_softmax(float* __restrict__ vwf, float* __restrict__ twf,
                          const int* __restrict__ tlen) {
  __shared__ float red[8];
  int tid = threadIdx.x;
  if (blockIdx.x < 64) {
    int b = blockIdx.x;
    float x = (tid < NV) ? vwf[b * NV + tid] : -1e30f;
    float m = x;
    for (int s = 1; s < 64; s <<= 1) m = fmaxf(m, __shfl_xor(m, s));
    if ((tid & 63) == 0) red[tid >> 6] = m;
    __syncthreads();
    m = fmaxf(fmaxf(red[0], red[1]), fmaxf(red[2], red[3]));
    float e = (tid < NV) ? expf(x - m) : 0.0f;
    float s = e;
    for (int st = 1; st < 64; st <<= 1) s += __shfl_xor(s, st);
    if ((tid & 63) == 0) red[4 + (tid >> 6)] = s;
    __syncthreads();
    s = red[4] + red[5] + red[6] + red[7];
    if (tid < NV) vwf[b * NV + tid] = e / s;
  } else {
    int b = blockIdx.x - 64;
    if (tid < 64) {
      int len = tlen[b];
      float x = twf[b * NT + tid];
      bool valid = tid < len;
      float xv = valid ? x : -1e30f;
      float m = xv;
      for (int s = 1; s < 64; s <<= 1) m = fmaxf(m, __shfl_xor(m, s));
      float e = valid ? expf(x - m) : 0.0f;
      float s = e;
      for (int st = 1; st < 64; st <<= 1) s += __shfl_xor(s, st);
      twf[b * NT + tid] = e / s;
    }
  }
}

// ---------------- MFMA sim kernel: one block (8 waves) per (b, q-pair) --------------
// Wave w: qsel=w>>2, wr=w&3; 13 row-tiles split {4,3,3,3} over wr.
// A staged ONCE per q-pair (halves staging); dbuf + counted vmcnt; 2 blocks/CU.
__global__ __launch_bounds__(512, 4) void k_sim(
    const short* __restrict__ ve_bf, const short* __restrict__ te_bf,
    const float* __restrict__ vwf, const float* __restrict__ twf,
    float* __restrict__ out, int* __restrict__ gMT, int* __restrict__ gMV) {
  __shared__ short As[2][208 * 32];   // linear, 64B row stride
  __shared__ short Bs[2][128 * 32];
  __shared__ float colv[8][64];
  __shared__ int   coli[8][64];
  __shared__ float redp[8];
  int n = blockIdx.x;
  int xcd = n & 7, idx = n >> 3;
  int b = xcd * 8 + (idx & 7);     // b-fastest within XCD chunk (ve L2-resident)
  int qq = idx >> 3;               // 0..31
  int tid = threadIdx.x;
  int w = tid >> 6, lane = tid & 63, lg = lane >> 4, li = lane & 15;
  int qsel = w >> 2, wr = w & 3;
  int q = 2 * qq + qsel;
  const short* Abf = ve_bf + (size_t)b * NV * EDIM;
  const short* Bbf = te_bf + (size_t)qq * 128 * EDIM;  // rows 0-63: q0, 64-127: q1
  int fsw = (li + (li >> 2)) & 3;
  int nt = wr ? 3 : 4;
  int tbase = wr ? (1 + wr * 3) : 0;  // wr0:0-3, wr1:4-6, wr2:7-9, wr3:10-12

  // hoisted per-lane global srcs (advance 32 shorts = 64B per kc)
  const short* aSrc[2];
#pragma unroll
  for (int uu = 0; uu < 2; ++uu) {
    int u = uu * 512 + w * 64 + lane;
    int row = u >> 2;
    if (row > NV - 1) row = NV - 1;
    int seg = u & 3;
    int ss = seg ^ swz4(row);
    aSrc[uu] = Abf + (size_t)row * EDIM + ss * 8;
  }
  const short* bSrc;
  {
    int u = tid;                     // 512 units = 128 rows x 4 segs
    int row = u >> 2, seg = u & 3;
    int ss = seg ^ swz4(row);
    bSrc = Bbf + (size_t)row * EDIM + ss * 8;
  }

  auto stage = [&](int bb) {
    short* Ad = &As[bb][0];
    short* Bd = &Bs[bb][0];
    gload16(bSrc, Bd + (w * 64) * 8);
    bSrc += 32;
#pragma unroll
    for (int uu = 0; uu < 2; ++uu) {
      int u0 = uu * 512 + w * 64;
      if (u0 < NV * 4) {             // w0-7 at uu=0; w0-4 at uu=1
        gload16(aSrc[uu], Ad + u0 * 8);
        aSrc[uu] += 32;
      }
    }
  };

  f32x4 acc[4][4];
#pragma unroll
  for (int i = 0; i < 4; ++i)
#pragma unroll
    for (int j = 0; j < 4; ++j) acc[i][j] = (f32x4){0.f, 0.f, 0.f, 0.f};

  stage(0);   // w0-4: 3 loads, w5-7: 2 loads in flight
  int cur = 0;
  for (int kc = 0; kc < 16; ++kc) {
    __builtin_amdgcn_s_barrier();      // all waves done reading buf[cur^1]
    if (kc < 15) {
      stage(cur ^ 1);
      if (w <= 4) asm volatile("s_waitcnt vmcnt(3)" ::: "memory");
      else        asm volatile("s_waitcnt vmcnt(2)" ::: "memory");
    } else {
      asm volatile("s_waitcnt vmcnt(0)" ::: "memory");
    }
    __builtin_amdgcn_s_barrier();      // buf[cur] visible to all waves
    const short* Ab2 = &As[cur][0];
    const short* Bb2 = &Bs[cur][0];
    bf16x8 bfr[4];
#pragma unroll
    for (int j = 0; j < 4; ++j)
      bfr[j] = *(const bf16x8*)(Bb2 + (qsel * 64 + j * 16 + li) * 32 + (lg ^ fsw) * 8);
    __builtin_amdgcn_s_setprio(1);
#pragma unroll
    for (int i = 0; i < 4; ++i) {
      if (i < nt) {
        bf16x8 afr = *(const bf16x8*)(Ab2 + ((tbase + i) * 16 + li) * 32 + (lg ^ fsw) * 8);
#pragma unroll
        for (int j = 0; j < 4; ++j)
          acc[i][j] = __builtin_amdgcn_mfma_f32_16x16x32_bf16(afr, bfr[j], acc[i][j], 0, 0, 0);
      }
    }
    __builtin_amdgcn_s_setprio(0);
    cur ^= 1;
  }

  bool diag = (b == q);
  // ---- row (over t) max+argmax for this wave's q; C: row=T*16+lg*4+reg, col=j*16+li
  float ip = 0.f;
#pragma unroll
  for (int i = 0; i < 4; ++i) {
    if (i < nt) {
#pragma unroll
      for (int reg = 0; reg < 4; ++reg) {
        int v = (tbase + i) * 16 + lg * 4 + reg;
        float m = acc[i][0][reg];
        int ti = li;
#pragma unroll
        for (int j = 1; j < 4; ++j) {
          float vv = acc[i][j][reg];
          int t = j * 16 + li;
          if (vv > m) { m = vv; ti = t; }   // t ascending -> first-index kept
        }
        for (int d = 1; d < 16; d <<= 1) {  // within li-group (same row)
          float om = __shfl_xor(m, d);
          int oi = __shfl_xor(ti, d);
          if (om > m || (om == m && oi < ti)) { m = om; ti = oi; }
        }
        if (li == 0 && v < NV) {
          ip += vwf[b * NV + v] * m;
          if (diag) gMT[b * NV + v] = b * NT + ti;
        }
      }
    }
  }
  for (int d = 1; d < 64; d <<= 1) ip += __shfl_xor(ip, d);
  if (lane == 0) redp[w] = ip;
  // ---- col (over v) max+argmax for this wave's rows (its q's 64 cols)
  float cm[4]; int cv[4];
#pragma unroll
  for (int j = 0; j < 4; ++j) { cm[j] = -3.0e38f; cv[j] = 0; }
#pragma unroll
  for (int i = 0; i < 4; ++i) {
    if (i < nt) {
#pragma unroll
      for (int reg = 0; reg < 4; ++reg) {
        int v = (tbase + i) * 16 + lg * 4 + reg;
        bool ok = v < NV;
#pragma unroll
        for (int j = 0; j < 4; ++j) {
          float s = ok ? acc[i][j][reg] : -3.0e38f;
          if (s > cm[j]) { cm[j] = s; cv[j] = v; }  // v ascending per lane
        }
      }
    }
  }
#pragma unroll
  for (int j = 0; j < 4; ++j) {
    for (int d = 16; d < 64; d <<= 1) {   // mixes lg groups (same col)
      float om = __shfl_xor(cm[j], d);
      int ov = __shfl_xor(cv[j], d);
      if (om > cm[j] || (om == cm[j] && ov < cv[j])) { cm[j] = om; cv[j] = ov; }
    }
    if (lg == 0) { colv[w][j * 16 + li] = cm[j]; coli[w][j * 16 + li] = cv[j]; }
  }
  __syncthreads();
  if (tid < 128) {   // wave0 -> q0 (colv 0-3), wave1 -> q1 (colv 4-7)
    int qs = tid >> 6, t = tid & 63;
    int qe = 2 * qq + qs;
    float m = colv[qs * 4][t];
    int bi = coli[qs * 4][t];
#pragma unroll
    for (int w2 = 1; w2 < 4; ++w2) {
      float om = colv[qs * 4 + w2][t];
      int ov = coli[qs * 4 + w2][t];
      if (om > m || (om == m && ov < bi)) { m = om; bi = ov; }
    }
    if (b == qe) gMV[b * NT + t] = b * NV + bi;
    float p = twf[qe * NT + t] * m;
    for (int d = 1; d < 64; d <<= 1) p += __shfl_xor(p, d);
    if ((tid & 63) == 0) out[4096 + b * 64 + qe] = p;
  }
  if (tid == 0) {
    out[b * 64 + 2 * qq]     = redp[0] + redp[1] + redp[2] + redp[3];
    out[b * 64 + 2 * qq + 1] = redp[4] + redp[5] + redp[6] + redp[7];
  }
}

// ---------------- column stats from bf16 (sum, sumsq, weighted sum) ------
__global__ void k_stats(const short* __restrict__ ve_bf, const short* __restrict__ te_bf,
                        const int* __restrict__ gMT, const int* __restrict__ gMV,
                        const float* __restrict__ vwf, const float* __restrict__ twf,
                        float* __restrict__ statPart) {
  int stripe = blockIdx.x, chunk = blockIdx.y, m = blockIdx.z;
  int R = (m < 2) ? MROWS_T : MROWS_V;
  int nchunk = (R + 1023) >> 10;
  if (chunk >= nchunk) return;
  const short* M; const int* g; const float* w;
  if (m == 0)      { M = te_bf; g = 0;   w = twf; }
  else if (m == 1) { M = ve_bf; g = gMV; w = twf; }
  else if (m == 2) { M = ve_bf; g = 0;   w = vwf; }
  else             { M = te_bf; g = gMT; w = vwf; }
  int col = stripe * 64 + (threadIdx.x & 63);
  int rg = threadIdx.x >> 6;
  int r0 = chunk << 10;
  int r1 = min(r0 + 1024, R);
  float s = 0, ss = 0, sw = 0;
  for (int r = r0 + rg; r < r1; r += 4) {
    int row = g ? g[r] : r;
    float x = bf2f(M[(size_t)row * EDIM + col]);
    s += x; ss += x * x; sw += w[r] * x;
  }
  __shared__ float red[3][256];
  red[0][threadIdx.x] = s; red[1][threadIdx.x] = ss; red[2][threadIdx.x] = sw;
  __syncthreads();
  if (threadIdx.x < 64) {
    int c = threadIdx.x;
    float S  = red[0][c] + red[0][c + 64] + red[0][c + 128] + red[0][c + 192];
    float SS = red[1][c] + red[1][c + 64] + red[1][c + 128] + red[1][c + 192];
    float SW = red[2][c] + red[2][c + 64] + red[2][c + 128] + red[2][c + 192];
    size_t idx = ((size_t)(m * 13 + chunk) * 512 + stripe * 64 + c) * 3;
    statPart[idx] = S; statPart[idx + 1] = SS; statPart[idx + 2] = SW;
  }
}

__global__ void k_statfin(const float* __restrict__ statPart, float* __restrict__ stats) {
  int m = blockIdx.x, c = threadIdx.x;
  int R = (m < 2) ? MROWS_T : MROWS_V;
  int nchunk = (R + 1023) >> 10;
  float s = 0, ss = 0, sw = 0;
  for (int ch = 0; ch < nchunk; ch++) {
    size_t idx = ((size_t)(m * 13 + ch) * 512 + c) * 3;
    s += statPart[idx]; ss += statPart[idx + 1]; sw += statPart[idx + 2];
  }
  float mean = s / R;
  float var = (ss - s * mean) / (R - 1);  // ddof=1
  float rstd = 1.0f / sqrtf(var);
  stats[(m * 3 + 0) * 512 + c] = mean;
  stats[(m * 3 + 1) * 512 + c] = rstd;
  stats[(m * 3 + 2) * 512 + c] = sw;
}

// ------- transpose-materialize a-contiguous bf16 operands (w and gathers folded) ----
__global__ void k_materialize(const short* __restrict__ ve_bf, const short* __restrict__ te_bf,
                              const int* __restrict__ gMT, const int* __restrict__ gMV,
                              const float* __restrict__ vwf, const float* __restrict__ twf,
                              short* __restrict__ tTw, short* __restrict__ mvT,
                              short* __restrict__ vTw, short* __restrict__ mtT) {
  int z = blockIdx.z;
  int at = blockIdx.x, ct = blockIdx.y;
  int K = (z == 2 || z == 3) ? MROWS_V : MROWS_T;
  if (at * 64 >= K) return;
  const short* src; const int* g = 0; const float* w = 0; short* dst;
  if (z == 0)      { src = te_bf; w = twf; dst = tTw; }
  else if (z == 1) { src = ve_bf; g = gMV; dst = mvT; }
  else if (z == 2) { src = ve_bf; w = vwf; dst = vTw; }
  else             { src = te_bf; g = gMT; dst = mtT; }
  __shared__ float tile[64][67];
  int tid = threadIdx.x;
  for (int u = tid; u < 512; u += 256) {
    int a = u >> 3, cseg = (u & 7) << 3;
    int ga = at * 64 + a;
    int row = g ? g[ga] : ga;
    bf16x8 vv = *(const bf16x8*)(src + (size_t)row * EDIM + ct * 64 + cseg);
    float wa = w ? w[ga] : 1.0f;
#pragma unroll
    for (int j = 0; j < 8; j++) tile[a][cseg + j] = wa * bf2f(vv[j]);
  }
  __syncthreads();
  for (int u = tid; u < 512; u += 256) {
    int c = u >> 3, aseg = (u & 7) << 3;
    bf16x8 ov;
#pragma unroll
    for (int j = 0; j < 8; j++) ov[j] = (short)f2bf(tile[aseg + j][c]);
    *(bf16x8*)(dst + (size_t)(ct * 64 + c) * K + at * 64 + aseg) = ov;
  }
}

// ------- MFMA weighted GEMM: Spart[z][c][d] = sum_a AT[c][a]*BT[d][a] (split-K 8) ----
__global__ __launch_bounds__(256, 4) void k_wgemm2(
    const short* __restrict__ tTw, const short* __restrict__ mvT,
    const short* __restrict__ vTw, const short* __restrict__ mtT,
    float* __restrict__ Spart) {
  __shared__ short As[2][128 * 32];
  __shared__ short Bs[2][64 * 32];
  int c0 = blockIdx.x * 128, d0 = blockIdx.y * 64;
  int z = blockIdx.z;                 // 0..15
  int which = z >> 3, slice = z & 7;
  const short* A = which ? vTw : tTw;
  const short* B = which ? mtT : mvT;
  int K = which ? MROWS_V : MROWS_T;
  int nch = (K >> 3) >> 5;            // 49 or 16 chunks of 32
  int a0 = slice * (K >> 3);
  int tid = threadIdx.x;
  int w = tid >> 6, lane = tid & 63, lg = lane >> 4, li = lane & 15;
  int fsw = (li + (li >> 2)) & 3;

  const short* aSrc[2];
#pragma unroll
  for (int uu = 0; uu < 2; ++uu) {
    int u = uu * 256 + w * 64 + lane;
    int row = u >> 2, seg = u & 3;
    int ss = seg ^ swz4(row);
    aSrc[uu] = A + (size_t)(c0 + row) * K + a0 + ss * 8;
  }
  const short* bSrc;
  {
    int u = w * 64 + lane;
    int row = u >> 2, seg = u & 3;
    int ss = seg ^ swz4(row);
    bSrc = B + (size_t)(d0 + row) * K + a0 + ss * 8;
  }

  auto stage = [&](int bb) {
    short* Ad = &As[bb][0];
    short* Bd = &Bs[bb][0];
#pragma unroll
    for (int uu = 0; uu < 2; ++uu) {
      gload16(aSrc[uu], Ad + (uu * 256 + w * 64) * 8);
      aSrc[uu] += 32;
    }
    gload16(bSrc, Bd + (w * 64) * 8);
    bSrc += 32;
  };

  f32x4 acc[2][4];
#pragma unroll
  for (int i = 0; i < 2; ++i)
#pragma unroll
    for (int j = 0; j < 4; ++j) acc[i][j] = (f32x4){0.f, 0.f, 0.f, 0.f};

  stage(0);
  int cur = 0;
  for (int ch = 0; ch < nch; ++ch) {
    __builtin_amdgcn_s_barrier();
    if (ch < nch - 1) {
      stage(cur ^ 1);
      asm volatile("s_waitcnt vmcnt(3)" ::: "memory");
    } else {
      asm volatile("s_waitcnt vmcnt(0)" ::: "memory");
    }
    __builtin_amdgcn_s_barrier();
    const short* Ab = &As[cur][0];
    const short* Bb = &Bs[cur][0];
    bf16x8 bfr[4];
#pragma unroll
    for (int j = 0; j < 4; ++j)
      bfr[j] = *(const bf16x8*)(Bb + (j * 16 + li) * 32 + (lg ^ fsw) * 8);
#pragma unroll
    for (int i = 0; i < 2; ++i) {
      bf16x8 afr = *(const bf16x8*)(Ab + ((w * 2 + i) * 16 + li) * 32 + (lg ^ fsw) * 8);
#pragma unroll
      for (int j = 0; j < 4; ++j)
        acc[i][j] = __builtin_amdgcn_mfma_f32_16x16x32_bf16(afr, bfr[j], acc[i][j], 0, 0, 0);
    }
    cur ^= 1;
  }
  float* outp = Spart + (size_t)z * 512 * 512;
#pragma unroll
  for (int j = 0; j < 4; ++j) {
    int d = d0 + j * 16 + li;
#pragma unroll
    for (int i = 0; i < 2; ++i)
#pragma unroll
      for (int reg = 0; reg < 4; ++reg)
        outp[(size_t)(c0 + (w * 2 + i) * 16 + lg * 4 + reg) * 512 + d] = acc[i][j][reg];
  }
}

// ---------------- assemble c = (c1+c2)/2 from closed form; loss partials ----------
__global__ void k_assemble(const float* __restrict__ Spart, const float* __restrict__ stats,
                           float* __restrict__ lossPart) {
  int c = blockIdx.x, tid = threadIdx.x;
  float muT = stats[0 * 512 + c], rsT = stats[1 * 512 + c], swT = stats[2 * 512 + c];
  float muV = stats[6 * 512 + c], rsV = stats[7 * 512 + c], swV = stats[8 * 512 + c];
  const float W = 64.0f, invB = 1.0f / 64.0f;
  float on = 0, off = 0;
  for (int d = tid; d < 512; d += 256) {
    float s1 = 0, s2 = 0;
    for (int sl = 0; sl < 8; sl++) {
      s1 += Spart[((size_t)sl * 512 + c) * 512 + d];
      s2 += Spart[((size_t)(8 + sl) * 512 + c) * 512 + d];
    }
    float muMV = stats[3 * 512 + d], rsMV = stats[4 * 512 + d], swMV = stats[5 * 512 + d];
    float muMT = stats[9 * 512 + d], rsMT = stats[10 * 512 + d], swMT = stats[11 * 512 + d];
    float c1 = (s1 - muT * swMV - muMV * swT + muT * muMV * W) * rsT * rsMV * invB;
    float c2 = (s2 - muV * swMT - muMT * swV + muV * muMT * W) * rsV * rsMT * invB;
    float cc = 0.5f * (c1 + c2);
    if (d == c) { float dd = cc - 1.0f; on += dd * dd; }
    else off += cc * cc;
  }
  __shared__ float r1[4], r2[4];
  for (int s = 1; s < 64; s <<= 1) { on += __shfl_xor(on, s); off += __shfl_xor(off, s); }
  if ((tid & 63) == 0) { r1[tid >> 6] = on; r2[tid >> 6] = off; }
  __syncthreads();
  if (tid == 0) {
    lossPart[c * 2] = r1[0] + r1[1] + r1[2] + r1[3];
    lossPart[c * 2 + 1] = r2[0] + r2[1] + r2[2] + r2[3];
  }
}

__global__ void k_loss(const float* __restrict__ lossPart, float* __restrict__ out) {
  int tid = threadIdx.x;
  float on = 0, off = 0;
  for (int i = tid; i < 512; i += 256) { on += lossPart[2 * i]; off += lossPart[2 * i + 1]; }
  __shared__ float r1[4], r2[4];
  for (int s = 1; s < 64; s <<= 1) { on += __shfl_xor(on, s); off += __shfl_xor(off, s); }
  if ((tid & 63) == 0) { r1[tid >> 6] = on; r2[tid >> 6] = off; }
  __syncthreads();
  if (tid == 0)
    out[8192] = 0.1f * ((r1[0] + r1[1] + r1[2] + r1[3]) +
                        0.06f * (r2[0] + r2[1] + r2[2] + r2[3]));
}

extern "C" void kernel_launch(void* const* d_in, const int* in_sizes, int n_in,
                              void* d_out, int out_size, void* d_ws, size_t ws_size,
                              hipStream_t stream) {
  (void)in_sizes; (void)n_in; (void)out_size; (void)ws_size;
  const float* v_tok  = (const float*)d_in[1];
  const float* t_tok  = (const float*)d_in[3];
  const float* Wv_tok = (const float*)d_in[8];
  const float* Wt_tok = (const float*)d_in[10];
  const float* bv_tok = (const float*)d_in[9];
  const float* bt_tok = (const float*)d_in[11];
  const float* wv_fc  = (const float*)d_in[12];
  const float* bv_fc  = (const float*)d_in[13];
  const float* wt_fc  = (const float*)d_in[14];
  const float* bt_fc  = (const float*)d_in[15];
  const int*   tlen   = (const int*)d_in[16];
  float* out = (float*)d_out;

  char* wsb = (char*)d_ws;
  short* v_tok_bf = (short*)wsb;                       // 9,633,792 sh
  short* t_tok_bf = v_tok_bf + (size_t)9633792;        // 3,145,728 sh
  short* WvT      = t_tok_bf + (size_t)3145728;        //   393,216 sh
  short* WtT      = WvT + (size_t)393216;              //   393,216 sh
  short* tTw = (short*)wsb;                            // 512*4096 (alias, phase2)
  short* mvT = tTw + (size_t)2097152;                  // 512*4096
  short* vTw = mvT + (size_t)2097152;                  // 512*12544
  short* ve_bf = (short*)(wsb + 27131904);             // 6,422,528 sh
  short* te_bf = ve_bf + (size_t)6422528;              // 2,097,152 sh
  float* Spart = (float*)(wsb + 27131904);             // 16*512*512 f (alias, phase-b)
  short* mtT = (short*)(wsb + 44171264);               // 512*12544
  float* vwf = (float*)(wsb + 57016320);               // 12544
  float* twf = vwf + 12544;                            // 4096
  int* gMT = (int*)(twf + 4096);                       // 12544
  int* gMV = gMT + 12544;                              // 4096
  float* statPart = (float*)(gMV + 4096);              // 4*13*512*3
  float* stats = statPart + 79872;                     // 12*512
  float* lossPart = stats + 6144;                      // 1024

  k_prep<<<7008, 256, 0, stream>>>(v_tok, v_tok_bf, 1204224, t_tok, t_tok_bf, 393216,
                                   Wv_tok, Wt_tok, WvT, WtT);
  k_proj_mfma2<<<dim3(8, 130), 256, 0, stream>>>(v_tok_bf, t_tok_bf, WvT, WtT,
                                                 bv_tok, bt_tok, ve_bf, te_bf);
  k_normfc2<<<4160, 256, 0, stream>>>(ve_bf, te_bf, wv_fc, wt_fc, bv_fc, bt_fc, vwf, twf);
  k_softmax<<<128, 256, 0, stream>>>(vwf, twf, tlen);
  k_sim<<<2048, 512, 0, stream>>>(ve_bf, te_bf, vwf, twf, out, gMT, gMV);
  k_stats<<<dim3(8, 13, 4), 256, 0, stream>>>(ve_bf, te_bf, gMT, gMV, vwf, twf, statPart);
  k_statfin<<<4, 512, 0, stream>>>(statPart, stats);
  k_materialize<<<dim3(196, 8, 4), 256, 0, stream>>>(ve_bf, te_bf, gMT, gMV, vwf, twf,
                                                     tTw, mvT, vTw, mtT);
  k_wgemm2<<<dim3(4, 8, 16), 256, 0, stream>>>(tTw, mvT, vTw, mtT, Spart);
  k_assemble<<<512, 256, 0, stream>>>(Spart, stats, lossPart);
  k_loss<<<1, 256, 0, stream>>>(lossPart, out);
}

// Round 13
// 272.362 us; speedup vs baseline: 3.3041x; 1.1078x over previous
//
#include <hip/hip_runtime.h>
#include <cstddef>

#define EDIM 512
#define KDIM 768
#define NB 64
#define NV 196
#define NT 64
#define MROWS_V (NB * NV) /* 12544 */
#define MROWS_T (NB * NT) /* 4096  */

typedef __attribute__((ext_vector_type(8))) short bf16x8;
typedef __attribute__((ext_vector_type(4))) float f32x4;

static __device__ inline unsigned short f2bf(float f) {  // round-to-nearest-even
  unsigned u = __float_as_uint(f);
  unsigned r = (u + 0x7fff + ((u >> 16) & 1)) >> 16;
  return (unsigned short)r;
}
static __device__ inline float bf2f(short s) {
  return __uint_as_float(((unsigned)(unsigned short)s) << 16);
}
// seg swizzle: for row-tiles read at fixed li, spreads bank-starts
static __device__ __forceinline__ int swz4(int r) { return (r + (r >> 2)) & 3; }

// async global->LDS, 16B per lane; LDS dest = wave-uniform base + lane*16
static __device__ __forceinline__ void gload16(const void* g, void* l) {
  __builtin_amdgcn_global_load_lds(
      (const __attribute__((address_space(1))) void*)g,
      (__attribute__((address_space(3))) void*)l, 16, 0, 0);
}

// ------- merged prep: fp32->bf16 convert (v_tok,t_tok) + W transpose->bf16 -------
__global__ void k_prep(const float* __restrict__ va, short* __restrict__ vo, int na8,
                       const float* __restrict__ ta, short* __restrict__ to, int nb8,
                       const float* __restrict__ W0, const float* __restrict__ W1,
                       short* __restrict__ T0, short* __restrict__ T1) {
  __shared__ float tile[32][33];
  int blk = blockIdx.x;
  int tid = threadIdx.x;
  if (blk < 6240) {
    int i = blk * 256 + tid;
    const float* in; short* outp; int idx;
    if (i < na8) { in = va; outp = vo; idx = i; }
    else { idx = i - na8; if (idx >= nb8) return; in = ta; outp = to; }
    float4 a = *(const float4*)(in + (size_t)idx * 8);
    float4 b = *(const float4*)(in + (size_t)idx * 8 + 4);
    bf16x8 v;
    v[0] = (short)f2bf(a.x); v[1] = (short)f2bf(a.y);
    v[2] = (short)f2bf(a.z); v[3] = (short)f2bf(a.w);
    v[4] = (short)f2bf(b.x); v[5] = (short)f2bf(b.y);
    v[6] = (short)f2bf(b.z); v[7] = (short)f2bf(b.w);
    *(bf16x8*)(outp + (size_t)idx * 8) = v;
  } else {
    int z = blk - 6240;            // 0..767 = 24 x 16 x 2
    int bx = z % 24, by = (z / 24) % 16, bz = z / 384;
    const float* W = bz ? W1 : W0;
    short*       T = bz ? T1 : T0;
    int k0 = bx * 32, n0 = by * 32;
    int tx = tid & 31, ty = tid >> 5;
    for (int i = ty; i < 32; i += 8)
      tile[i][tx] = W[(size_t)(k0 + i) * EDIM + n0 + tx];
    __syncthreads();
    for (int i = ty; i < 32; i += 8)
      T[(size_t)(n0 + i) * KDIM + k0 + tx] = (short)f2bf(tile[tx][i]);
  }
}

// ---------- MFMA projection (merged v+t): Mbf[r,n] = bf16(X@WT + bias) ----
__global__ __launch_bounds__(256, 4) void k_proj_mfma2(
    const short* __restrict__ vX, const short* __restrict__ tX,
    const short* __restrict__ WvT, const short* __restrict__ WtT,
    const float* __restrict__ vb, const float* __restrict__ tb,
    short* __restrict__ vout, short* __restrict__ tout) {
  __shared__ short As[2][128 * 32];
  __shared__ short Bs[2][64 * 32];
  int y = blockIdx.y;
  const short* Xbf; const short* WT; const float* bias; short* Mbf; int r0;
  if (y < 98) { Xbf = vX; WT = WvT; bias = vb; Mbf = vout; r0 = y * 128; }
  else        { Xbf = tX; WT = WtT; bias = tb; Mbf = tout; r0 = (y - 98) * 128; }
  int n0 = blockIdx.x * 64;
  int tid = threadIdx.x;
  int w = tid >> 6, lane = tid & 63, lg = lane >> 4, li = lane & 15;
  int fsw = (li + (li >> 2)) & 3;

  const short* aSrc[2];
#pragma unroll
  for (int uu = 0; uu < 2; ++uu) {
    int u = uu * 256 + w * 64 + lane;
    int row = u >> 2, seg = u & 3;
    int ss = seg ^ swz4(row);
    aSrc[uu] = Xbf + (size_t)(r0 + row) * KDIM + ss * 8;
  }
  const short* bSrc;
  {
    int u = w * 64 + lane;
    int row = u >> 2, seg = u & 3;
    int ss = seg ^ swz4(row);
    bSrc = WT + (size_t)(n0 + row) * KDIM + ss * 8;
  }

  auto stage = [&](int bb) {
    short* Ad = &As[bb][0];
    short* Bd = &Bs[bb][0];
#pragma unroll
    for (int uu = 0; uu < 2; ++uu) {
      gload16(aSrc[uu], Ad + (uu * 256 + w * 64) * 8);
      aSrc[uu] += 32;
    }
    gload16(bSrc, Bd + (w * 64) * 8);
    bSrc += 32;
  };

  f32x4 acc[2][4];
#pragma unroll
  for (int i = 0; i < 2; ++i)
#pragma unroll
    for (int j = 0; j < 4; ++j) acc[i][j] = (f32x4){0.f, 0.f, 0.f, 0.f};

  stage(0);
  int cur = 0;
  const int NKC = KDIM / 32;  // 24
  for (int kc = 0; kc < NKC; ++kc) {
    __builtin_amdgcn_s_barrier();
    if (kc < NKC - 1) {
      stage(cur ^ 1);
      asm volatile("s_waitcnt vmcnt(3)" ::: "memory");
    } else {
      asm volatile("s_waitcnt vmcnt(0)" ::: "memory");
    }
    __builtin_amdgcn_s_barrier();
    const short* Ab = &As[cur][0];
    const short* Bb = &Bs[cur][0];
    bf16x8 bfr[4];
#pragma unroll
    for (int j = 0; j < 4; ++j)
      bfr[j] = *(const bf16x8*)(Bb + (j * 16 + li) * 32 + (lg ^ fsw) * 8);
#pragma unroll
    for (int i = 0; i < 2; ++i) {
      bf16x8 afr = *(const bf16x8*)(Ab + ((w * 2 + i) * 16 + li) * 32 + (lg ^ fsw) * 8);
#pragma unroll
      for (int j = 0; j < 4; ++j)
        acc[i][j] = __builtin_amdgcn_mfma_f32_16x16x32_bf16(afr, bfr[j], acc[i][j], 0, 0, 0);
    }
    cur ^= 1;
  }
#pragma unroll
  for (int j = 0; j < 4; ++j) {
    int n = n0 + j * 16 + li;
    float bb = bias[n];
#pragma unroll
    for (int i = 0; i < 2; ++i)
#pragma unroll
      for (int reg = 0; reg < 4; ++reg)
        Mbf[(size_t)(r0 + (w * 2 + i) * 16 + lg * 4 + reg) * EDIM + n] =
            (short)f2bf(acc[i][j][reg] + bb);
  }
}

// ------- per-row (bf16 in place): fc scalar + l2 normalize; merged v+t -------
__global__ void k_normfc2(short* __restrict__ vM, short* __restrict__ tM,
                          const float* __restrict__ vfcw, const float* __restrict__ tfcw,
                          const float* __restrict__ vfcb, const float* __restrict__ tfcb,
                          float* __restrict__ vwout, float* __restrict__ twout) {
  int blk = blockIdx.x;
  short* Mbf; const float* fcw; const float* fcb; float* wout; int row;
  if (blk < 3136) { Mbf = vM; fcw = vfcw; fcb = vfcb; wout = vwout;
                    row = blk * 4 + (threadIdx.x >> 6); if (row >= 12544) return; }
  else            { Mbf = tM; fcw = tfcw; fcb = tfcb; wout = twout;
                    row = (blk - 3136) * 4 + (threadIdx.x >> 6); if (row >= 4096) return; }
  int lane = threadIdx.x & 63;
  short* p = Mbf + (size_t)row * EDIM + lane * 8;
  bf16x8 v = *(bf16x8*)p;
  float4 w0 = *(const float4*)(fcw + lane * 8);
  float4 w1 = *(const float4*)(fcw + lane * 8 + 4);
  float a[8];
#pragma unroll
  for (int j = 0; j < 8; ++j) a[j] = bf2f(v[j]);
  float dot = a[0] * w0.x + a[1] * w0.y + a[2] * w0.z + a[3] * w0.w +
              a[4] * w1.x + a[5] * w1.y + a[6] * w1.z + a[7] * w1.w;
  float ss = a[0] * a[0] + a[1] * a[1] + a[2] * a[2] + a[3] * a[3] +
             a[4] * a[4] + a[5] * a[5] + a[6] * a[6] + a[7] * a[7];
  for (int s = 1; s < 64; s <<= 1) {
    dot += __shfl_xor(dot, s);
    ss += __shfl_xor(ss, s);
  }
  float inv = 1.0f / fmaxf(sqrtf(ss), 1e-12f);
#pragma unroll
  for (int j = 0; j < 8; ++j) v[j] = (short)f2bf(a[j] * inv);
  *(bf16x8*)p = v;
  if (lane == 0) wout[row] = dot + fcb[0];
}

// ---------------- softmax: blocks 0..63 vw rows (196), 64..127 tw rows (64, masked) ----
__global__ void k_softmax(float* __restrict__ vwf, float* __restrict__ twf,
                          const int* __restrict__ tlen) {
  __shared__ float red[8];
  int tid = threadIdx.x;
  if (blockIdx.x < 64) {
    int b = blockIdx.x;
    float x = (tid < NV) ? vwf[b * NV + tid] : -1e30f;
    float m = x;
    for (int s = 1; s < 64; s <<= 1) m = fmaxf(m, __shfl_xor(m, s));
    if ((tid & 63) == 0) red[tid >> 6] = m;
    __syncthreads();
    m = fmaxf(fmaxf(red[0], red[1]), fmaxf(red[2], red[3]));
    float e = (tid < NV) ? expf(x - m) : 0.0f;
    float s = e;
    for (int st = 1; st < 64; st <<= 1) s += __shfl_xor(s, st);
    if ((tid & 63) == 0) red[4 + (tid >> 6)] = s;
    __syncthreads();
    s = red[4] + red[5] + red[6] + red[7];
    if (tid < NV) vwf[b * NV + tid] = e / s;
  } else {
    int b = blockIdx.x - 64;
    if (tid < 64) {
      int len = tlen[b];
      float x = twf[b * NT + tid];
      bool valid = tid < len;
      float xv = valid ? x : -1e30f;
      float m = xv;
      for (int s = 1; s < 64; s <<= 1) m = fmaxf(m, __shfl_xor(m, s));
      float e = valid ? expf(x - m) : 0.0f;
      float s = e;
      for (int st = 1; st < 64; st <<= 1) s += __shfl_xor(s, st);
      twf[b * NT + tid] = e / s;
    }
  }
}

// ---------------- MFMA sim kernel: one block (8 waves) per (b, q-pair) --------------
// 3-stage circular LDS pipeline (prefetch depth 2): stage kc+2 issued at kc;
// vmcnt(2n) -> a stage's loads get ~2 kc of compute to complete. 2 blocks/CU.
__global__ __launch_bounds__(512, 4) void k_sim(
    const short* __restrict__ ve_bf, const short* __restrict__ te_bf,
    const float* __restrict__ vwf, const float* __restrict__ twf,
    float* __restrict__ out, int* __restrict__ gMT, int* __restrict__ gMV) {
  __shared__ short As[3][208 * 32];   // linear, 64B row stride
  __shared__ short Bs[3][128 * 32];
  __shared__ float colv[8][64];
  __shared__ int   coli[8][64];
  __shared__ float redp[8];
  int n = blockIdx.x;
  int xcd = n & 7, idx = n >> 3;
  int b = xcd * 8 + (idx & 7);     // b-fastest within XCD chunk (ve L2-resident)
  int qq = idx >> 3;               // 0..31
  int tid = threadIdx.x;
  int w = tid >> 6, lane = tid & 63, lg = lane >> 4, li = lane & 15;
  int qsel = w >> 2, wr = w & 3;
  int q = 2 * qq + qsel;
  const short* Abf = ve_bf + (size_t)b * NV * EDIM;
  const short* Bbf = te_bf + (size_t)qq * 128 * EDIM;  // rows 0-63: q0, 64-127: q1
  int fsw = (li + (li >> 2)) & 3;
  int nt = wr ? 3 : 4;
  int tbase = wr ? (1 + wr * 3) : 0;  // wr0:0-3, wr1:4-6, wr2:7-9, wr3:10-12

  const short* aSrc[2];
#pragma unroll
  for (int uu = 0; uu < 2; ++uu) {
    int u = uu * 512 + w * 64 + lane;
    int row = u >> 2;
    if (row > NV - 1) row = NV - 1;
    int seg = u & 3;
    int ss = seg ^ swz4(row);
    aSrc[uu] = Abf + (size_t)row * EDIM + ss * 8;
  }
  const short* bSrc;
  {
    int u = tid;                     // 512 units = 128 rows x 4 segs
    int row = u >> 2, seg = u & 3;
    int ss = seg ^ swz4(row);
    bSrc = Bbf + (size_t)row * EDIM + ss * 8;
  }

  auto stage = [&](int s) {          // w0-4: 3 loads, w5-7: 2 loads
    short* Ad = &As[s][0];
    short* Bd = &Bs[s][0];
    gload16(bSrc, Bd + (w * 64) * 8);
    bSrc += 32;
#pragma unroll
    for (int uu = 0; uu < 2; ++uu) {
      int u0 = uu * 512 + w * 64;
      if (u0 < NV * 4) {
        gload16(aSrc[uu], Ad + u0 * 8);
        aSrc[uu] += 32;
      }
    }
  };

  f32x4 acc[4][4];
#pragma unroll
  for (int i = 0; i < 4; ++i)
#pragma unroll
    for (int j = 0; j < 4; ++j) acc[i][j] = (f32x4){0.f, 0.f, 0.f, 0.f};

  stage(0);
  stage(1);
  for (int kc = 0; kc < 16; ++kc) {
    __builtin_amdgcn_s_barrier();      // readers of buf[(kc+2)%3] (used at kc-1) done
    if (kc < 14) {
      stage((kc + 2) % 3);
      if (w <= 4) asm volatile("s_waitcnt vmcnt(6)" ::: "memory");
      else        asm volatile("s_waitcnt vmcnt(4)" ::: "memory");
    } else if (kc == 14) {
      if (w <= 4) asm volatile("s_waitcnt vmcnt(3)" ::: "memory");
      else        asm volatile("s_waitcnt vmcnt(2)" ::: "memory");
    } else {
      asm volatile("s_waitcnt vmcnt(0)" ::: "memory");
    }
    __builtin_amdgcn_s_barrier();      // buf[kc%3] fully landed (all waves)
    const short* Ab2 = &As[kc % 3][0];
    const short* Bb2 = &Bs[kc % 3][0];
    bf16x8 bfr[4];
#pragma unroll
    for (int j = 0; j < 4; ++j)
      bfr[j] = *(const bf16x8*)(Bb2 + (qsel * 64 + j * 16 + li) * 32 + (lg ^ fsw) * 8);
    __builtin_amdgcn_s_setprio(1);
#pragma unroll
    for (int i = 0; i < 4; ++i) {
      if (i < nt) {
        bf16x8 afr = *(const bf16x8*)(Ab2 + ((tbase + i) * 16 + li) * 32 + (lg ^ fsw) * 8);
#pragma unroll
        for (int j = 0; j < 4; ++j)
          acc[i][j] = __builtin_amdgcn_mfma_f32_16x16x32_bf16(afr, bfr[j], acc[i][j], 0, 0, 0);
      }
    }
    __builtin_amdgcn_s_setprio(0);
  }

  bool diag = (b == q);
  // ---- row (over t) max+argmax for this wave's q; C: row=T*16+lg*4+reg, col=j*16+li
  float ip = 0.f;
#pragma unroll
  for (int i = 0; i < 4; ++i) {
    if (i < nt) {
#pragma unroll
      for (int reg = 0; reg < 4; ++reg) {
        int v = (tbase + i) * 16 + lg * 4 + reg;
        float m = acc[i][0][reg];
        int ti = li;
#pragma unroll
        for (int j = 1; j < 4; ++j) {
          float vv = acc[i][j][reg];
          int t = j * 16 + li;
          if (vv > m) { m = vv; ti = t; }   // t ascending -> first-index kept
        }
        for (int d = 1; d < 16; d <<= 1) {  // within li-group (same row)
          float om = __shfl_xor(m, d);
          int oi = __shfl_xor(ti, d);
          if (om > m || (om == m && oi < ti)) { m = om; ti = oi; }
        }
        if (li == 0 && v < NV) {
          ip += vwf[b * NV + v] * m;
          if (diag) gMT[b * NV + v] = b * NT + ti;
        }
      }
    }
  }
  for (int d = 1; d < 64; d <<= 1) ip += __shfl_xor(ip, d);
  if (lane == 0) redp[w] = ip;
  // ---- col (over v) max+argmax for this wave's rows (its q's 64 cols)
  float cm[4]; int cv[4];
#pragma unroll
  for (int j = 0; j < 4; ++j) { cm[j] = -3.0e38f; cv[j] = 0; }
#pragma unroll
  for (int i = 0; i < 4; ++i) {
    if (i < nt) {
#pragma unroll
      for (int reg = 0; reg < 4; ++reg) {
        int v = (tbase + i) * 16 + lg * 4 + reg;
        bool ok = v < NV;
#pragma unroll
        for (int j = 0; j < 4; ++j) {
          float s = ok ? acc[i][j][reg] : -3.0e38f;
          if (s > cm[j]) { cm[j] = s; cv[j] = v; }  // v ascending per lane
        }
      }
    }
  }
#pragma unroll
  for (int j = 0; j < 4; ++j) {
    for (int d = 16; d < 64; d <<= 1) {   // mixes lg groups (same col)
      float om = __shfl_xor(cm[j], d);
      int ov = __shfl_xor(cv[j], d);
      if (om > cm[j] || (om == cm[j] && ov < cv[j])) { cm[j] = om; cv[j] = ov; }
    }
    if (lg == 0) { colv[w][j * 16 + li] = cm[j]; coli[w][j * 16 + li] = cv[j]; }
  }
  __syncthreads();
  if (tid < 128) {   // tid>>6==0 -> q0 (colv 0-3), ==1 -> q1 (colv 4-7)
    int qs = tid >> 6, t = tid & 63;
    int qe = 2 * qq + qs;
    float m = colv[qs * 4][t];
    int bi = coli[qs * 4][t];
#pragma unroll
    for (int w2 = 1; w2 < 4; ++w2) {
      float om = colv[qs * 4 + w2][t];
      int ov = coli[qs * 4 + w2][t];
      if (om > m || (om == m && ov < bi)) { m = om; bi = ov; }
    }
    if (b == qe) gMV[b * NT + t] = b * NV + bi;
    float p = twf[qe * NT + t] * m;
    for (int d = 1; d < 64; d <<= 1) p += __shfl_xor(p, d);
    if ((tid & 63) == 0) out[4096 + b * 64 + qe] = p;
  }
  if (tid == 0) {
    out[b * 64 + 2 * qq]     = redp[0] + redp[1] + redp[2] + redp[3];
    out[b * 64 + 2 * qq + 1] = redp[4] + redp[5] + redp[6] + redp[7];
  }
}

// ------- transpose-materialize + FUSED column stats (sum, sumsq, wsum) --------------
// z: 0 tTw=tw*te, 1 mvT=ve[gMV], 2 vTw=vw*ve, 3 mtT=te[gMT]; stats m == z.
__global__ void k_materialize(const short* __restrict__ ve_bf, const short* __restrict__ te_bf,
                              const int* __restrict__ gMT, const int* __restrict__ gMV,
                              const float* __restrict__ vwf, const float* __restrict__ twf,
                              short* __restrict__ tTw, short* __restrict__ mvT,
                              short* __restrict__ vTw, short* __restrict__ mtT,
                              float* __restrict__ statPart) {
  int z = blockIdx.z;
  int at = blockIdx.x, ct = blockIdx.y;
  int K = (z == 2 || z == 3) ? MROWS_V : MROWS_T;
  if (at * 64 >= K) return;
  const short* src; const int* g = 0; short* dst;
  bool applyW;
  const float* wS = (z <= 1) ? twf : vwf;
  if (z == 0)      { src = te_bf; dst = tTw; applyW = true;  }
  else if (z == 1) { src = ve_bf; g = gMV; dst = mvT; applyW = false; }
  else if (z == 2) { src = ve_bf; dst = vTw; applyW = true;  }
  else             { src = te_bf; g = gMT; dst = mtT; applyW = false; }
  __shared__ float tile[64][67];
  __shared__ float wrow[64];
  int tid = threadIdx.x;
  for (int u = tid; u < 512; u += 256) {
    int a = u >> 3, cseg = (u & 7) << 3;
    int ga = at * 64 + a;
    int row = g ? g[ga] : ga;
    bf16x8 vv = *(const bf16x8*)(src + (size_t)row * EDIM + ct * 64 + cseg);
#pragma unroll
    for (int j = 0; j < 8; j++) tile[a][cseg + j] = bf2f(vv[j]);
    if ((u & 7) == 0) wrow[a] = wS[ga];
  }
  __syncthreads();
  for (int u = tid; u < 512; u += 256) {
    int c = u >> 3, aseg = (u & 7) << 3;
    bf16x8 ov;
#pragma unroll
    for (int j = 0; j < 8; j++) {
      float x = tile[aseg + j][c];
      if (applyW) x *= wrow[aseg + j];
      ov[j] = (short)f2bf(x);
    }
    *(bf16x8*)(dst + (size_t)(ct * 64 + c) * K + at * 64 + aseg) = ov;
  }
  // ---- fused stats partials: 4 threads per column, 16 a's each
  int cl = tid >> 2, part = tid & 3;
  float s = 0, ssq = 0, sw = 0;
  for (int a = part * 16; a < part * 16 + 16; ++a) {
    float x = tile[a][cl];
    s += x; ssq += x * x; sw += wrow[a] * x;
  }
  for (int d = 1; d < 4; d <<= 1) {   // 4 consecutive lanes share a column
    s += __shfl_xor(s, d); ssq += __shfl_xor(ssq, d); sw += __shfl_xor(sw, d);
  }
  if (part == 0) {
    int cbase = (z == 0) ? 0 : (z == 1) ? 64 : (z == 2) ? 128 : 324;
    size_t sidx = ((size_t)(cbase + at) * 512 + ct * 64 + cl) * 3;
    statPart[sidx] = s; statPart[sidx + 1] = ssq; statPart[sidx + 2] = sw;
  }
}

__global__ void k_statfin(const float* __restrict__ statPart, float* __restrict__ stats) {
  int m = blockIdx.x, c = threadIdx.x;
  int R = (m < 2) ? MROWS_T : MROWS_V;
  int nchunk = (m < 2) ? 64 : 196;
  int base = (m == 0) ? 0 : (m == 1) ? 64 : (m == 2) ? 128 : 324;
  float s = 0, ss = 0, sw = 0;
  for (int ch = 0; ch < nchunk; ch++) {
    size_t idx = ((size_t)(base + ch) * 512 + c) * 3;
    s += statPart[idx]; ss += statPart[idx + 1]; sw += statPart[idx + 2];
  }
  float mean = s / R;
  float var = (ss - s * mean) / (R - 1);  // ddof=1
  float rstd = 1.0f / sqrtf(var);
  stats[(m * 3 + 0) * 512 + c] = mean;
  stats[(m * 3 + 1) * 512 + c] = rstd;
  stats[(m * 3 + 2) * 512 + c] = sw;
}

// ------- MFMA weighted GEMM: Spart[z][c][d] = sum_a AT[c][a]*BT[d][a] (split-K 8) ----
__global__ __launch_bounds__(256, 4) void k_wgemm2(
    const short* __restrict__ tTw, const short* __restrict__ mvT,
    const short* __restrict__ vTw, const short* __restrict__ mtT,
    float* __restrict__ Spart) {
  __shared__ short As[2][128 * 32];
  __shared__ short Bs[2][64 * 32];
  int c0 = blockIdx.x * 128, d0 = blockIdx.y * 64;
  int z = blockIdx.z;                 // 0..15
  int which = z >> 3, slice = z & 7;
  const short* A = which ? vTw : tTw;
  const short* B = which ? mtT : mvT;
  int K = which ? MROWS_V : MROWS_T;
  int nch = (K >> 3) >> 5;            // 49 or 16 chunks of 32
  int a0 = slice * (K >> 3);
  int tid = threadIdx.x;
  int w = tid >> 6, lane = tid & 63, lg = lane >> 4, li = lane & 15;
  int fsw = (li + (li >> 2)) & 3;

  const short* aSrc[2];
#pragma unroll
  for (int uu = 0; uu < 2; ++uu) {
    int u = uu * 256 + w * 64 + lane;
    int row = u >> 2, seg = u & 3;
    int ss = seg ^ swz4(row);
    aSrc[uu] = A + (size_t)(c0 + row) * K + a0 + ss * 8;
  }
  const short* bSrc;
  {
    int u = w * 64 + lane;
    int row = u >> 2, seg = u & 3;
    int ss = seg ^ swz4(row);
    bSrc = B + (size_t)(d0 + row) * K + a0 + ss * 8;
  }

  auto stage = [&](int bb) {
    short* Ad = &As[bb][0];
    short* Bd = &Bs[bb][0];
#pragma unroll
    for (int uu = 0; uu < 2; ++uu) {
      gload16(aSrc[uu], Ad + (uu * 256 + w * 64) * 8);
      aSrc[uu] += 32;
    }
    gload16(bSrc, Bd + (w * 64) * 8);
    bSrc += 32;
  };

  f32x4 acc[2][4];
#pragma unroll
  for (int i = 0; i < 2; ++i)
#pragma unroll
    for (int j = 0; j < 4; ++j) acc[i][j] = (f32x4){0.f, 0.f, 0.f, 0.f};

  stage(0);
  int cur = 0;
  for (int ch = 0; ch < nch; ++ch) {
    __builtin_amdgcn_s_barrier();
    if (ch < nch - 1) {
      stage(cur ^ 1);
      asm volatile("s_waitcnt vmcnt(3)" ::: "memory");
    } else {
      asm volatile("s_waitcnt vmcnt(0)" ::: "memory");
    }
    __builtin_amdgcn_s_barrier();
    const short* Ab = &As[cur][0];
    const short* Bb = &Bs[cur][0];
    bf16x8 bfr[4];
#pragma unroll
    for (int j = 0; j < 4; ++j)
      bfr[j] = *(const bf16x8*)(Bb + (j * 16 + li) * 32 + (lg ^ fsw) * 8);
#pragma unroll
    for (int i = 0; i < 2; ++i) {
      bf16x8 afr = *(const bf16x8*)(Ab + ((w * 2 + i) * 16 + li) * 32 + (lg ^ fsw) * 8);
#pragma unroll
      for (int j = 0; j < 4; ++j)
        acc[i][j] = __builtin_amdgcn_mfma_f32_16x16x32_bf16(afr, bfr[j], acc[i][j], 0, 0, 0);
    }
    cur ^= 1;
  }
  float* outp = Spart + (size_t)z * 512 * 512;
#pragma unroll
  for (int j = 0; j < 4; ++j) {
    int d = d0 + j * 16 + li;
#pragma unroll
    for (int i = 0; i < 2; ++i)
#pragma unroll
      for (int reg = 0; reg < 4; ++reg)
        outp[(size_t)(c0 + (w * 2 + i) * 16 + lg * 4 + reg) * 512 + d] = acc[i][j][reg];
  }
}

// ---------------- assemble c = (c1+c2)/2 from closed form; loss partials ----------
__global__ void k_assemble(const float* __restrict__ Spart, const float* __restrict__ stats,
                           float* __restrict__ lossPart) {
  int c = blockIdx.x, tid = threadIdx.x;
  float muT = stats[0 * 512 + c], rsT = stats[1 * 512 + c], swT = stats[2 * 512 + c];
  float muV = stats[6 * 512 + c], rsV = stats[7 * 512 + c], swV = stats[8 * 512 + c];
  const float W = 64.0f, invB = 1.0f / 64.0f;
  float on = 0, off = 0;
  for (int d = tid; d < 512; d += 256) {
    float s1 = 0, s2 = 0;
    for (int sl = 0; sl < 8; sl++) {
      s1 += Spart[((size_t)sl * 512 + c) * 512 + d];
      s2 += Spart[((size_t)(8 + sl) * 512 + c) * 512 + d];
    }
    float muMV = stats[3 * 512 + d], rsMV = stats[4 * 512 + d], swMV = stats[5 * 512 + d];
    float muMT = stats[9 * 512 + d], rsMT = stats[10 * 512 + d], swMT = stats[11 * 512 + d];
    float c1 = (s1 - muT * swMV - muMV * swT + muT * muMV * W) * rsT * rsMV * invB;
    float c2 = (s2 - muV * swMT - muMT * swV + muV * muMT * W) * rsV * rsMT * invB;
    float cc = 0.5f * (c1 + c2);
    if (d == c) { float dd = cc - 1.0f; on += dd * dd; }
    else off += cc * cc;
  }
  __shared__ float r1[4], r2[4];
  for (int s = 1; s < 64; s <<= 1) { on += __shfl_xor(on, s); off += __shfl_xor(off, s); }
  if ((tid & 63) == 0) { r1[tid >> 6] = on; r2[tid >> 6] = off; }
  __syncthreads();
  if (tid == 0) {
    lossPart[c * 2] = r1[0] + r1[1] + r1[2] + r1[3];
    lossPart[c * 2 + 1] = r2[0] + r2[1] + r2[2] + r2[3];
  }
}

__global__ void k_loss(const float* __restrict__ lossPart, float* __restrict__ out) {
  int tid = threadIdx.x;
  float on = 0, off = 0;
  for (int i = tid; i < 512; i += 256) { on += lossPart[2 * i]; off += lossPart[2 * i + 1]; }
  __shared__ float r1[4], r2[4];
  for (int s = 1; s < 64; s <<= 1) { on += __shfl_xor(on, s); off += __shfl_xor(off, s); }
  if ((tid & 63) == 0) { r1[tid >> 6] = on; r2[tid >> 6] = off; }
  __syncthreads();
  if (tid == 0)
    out[8192] = 0.1f * ((r1[0] + r1[1] + r1[2] + r1[3]) +
                        0.06f * (r2[0] + r2[1] + r2[2] + r2[3]));
}

extern "C" void kernel_launch(void* const* d_in, const int* in_sizes, int n_in,
                              void* d_out, int out_size, void* d_ws, size_t ws_size,
                              hipStream_t stream) {
  (void)in_sizes; (void)n_in; (void)out_size; (void)ws_size;
  const float* v_tok  = (const float*)d_in[1];
  const float* t_tok  = (const float*)d_in[3];
  const float* Wv_tok = (const float*)d_in[8];
  const float* Wt_tok = (const float*)d_in[10];
  const float* bv_tok = (const float*)d_in[9];
  const float* bt_tok = (const float*)d_in[11];
  const float* wv_fc  = (const float*)d_in[12];
  const float* bv_fc  = (const float*)d_in[13];
  const float* wt_fc  = (const float*)d_in[14];
  const float* bt_fc  = (const float*)d_in[15];
  const int*   tlen   = (const int*)d_in[16];
  float* out = (float*)d_out;

  char* wsb = (char*)d_ws;
  short* v_tok_bf = (short*)wsb;                       // 9,633,792 sh
  short* t_tok_bf = v_tok_bf + (size_t)9633792;        // 3,145,728 sh
  short* WvT      = t_tok_bf + (size_t)3145728;        //   393,216 sh
  short* WtT      = WvT + (size_t)393216;              //   393,216 sh
  short* tTw = (short*)wsb;                            // 512*4096 (alias, phase2)
  short* mvT = tTw + (size_t)2097152;                  // 512*4096
  short* vTw = mvT + (size_t)2097152;                  // 512*12544
  short* ve_bf = (short*)(wsb + 27131904);             // 6,422,528 sh
  short* te_bf = ve_bf + (size_t)6422528;              // 2,097,152 sh
  float* Spart = (float*)(wsb + 27131904);             // 16*512*512 f (alias, phase-b)
  short* mtT = (short*)(wsb + 44171264);               // 512*12544
  float* vwf = (float*)(wsb + 57016320);               // 12544
  float* twf = vwf + 12544;                            // 4096
  int* gMT = (int*)(twf + 4096);                       // 12544
  int* gMV = gMT + 12544;                              // 4096
  float* statPart = (float*)(gMV + 4096);              // 520*512*3 f (3.2 MB)
  float* stats = statPart + (size_t)520 * 512 * 3;     // 12*512
  float* lossPart = stats + 6144;                      // 1024

  k_prep<<<7008, 256, 0, stream>>>(v_tok, v_tok_bf, 1204224, t_tok, t_tok_bf, 393216,
                                   Wv_tok, Wt_tok, WvT, WtT);
  k_proj_mfma2<<<dim3(8, 130), 256, 0, stream>>>(v_tok_bf, t_tok_bf, WvT, WtT,
                                                 bv_tok, bt_tok, ve_bf, te_bf);
  k_normfc2<<<4160, 256, 0, stream>>>(ve_bf, te_bf, wv_fc, wt_fc, bv_fc, bt_fc, vwf, twf);
  k_softmax<<<128, 256, 0, stream>>>(vwf, twf, tlen);
  k_sim<<<2048, 512, 0, stream>>>(ve_bf, te_bf, vwf, twf, out, gMT, gMV);
  k_materialize<<<dim3(196, 8, 4), 256, 0, stream>>>(ve_bf, te_bf, gMT, gMV, vwf, twf,
                                                     tTw, mvT, vTw, mtT, statPart);
  k_statfin<<<4, 512, 0, stream>>>(statPart, stats);
  k_wgemm2<<<dim3(4, 8, 16), 256, 0, stream>>>(tTw, mvT, vTw, mtT, Spart);
  k_assemble<<<512, 256, 0, stream>>>(Spart, stats, lossPart);
  k_loss<<<1, 256, 0, stream>>>(lossPart, out);
}

// Round 14
// 256.403 us; speedup vs baseline: 3.5097x; 1.0622x over previous
//
#include <hip/hip_runtime.h>
#include <cstddef>

#define EDIM 512
#define KDIM 768
#define NB 64
#define NV 196
#define NT 64
#define MROWS_V (NB * NV) /* 12544 */
#define MROWS_T (NB * NT) /* 4096  */

typedef __attribute__((ext_vector_type(8))) short bf16x8;
typedef __attribute__((ext_vector_type(4))) float f32x4;

static __device__ inline unsigned short f2bf(float f) {  // round-to-nearest-even
  unsigned u = __float_as_uint(f);
  unsigned r = (u + 0x7fff + ((u >> 16) & 1)) >> 16;
  return (unsigned short)r;
}
static __device__ inline float bf2f(short s) {
  return __uint_as_float(((unsigned)(unsigned short)s) << 16);
}
// seg swizzle: for row-tiles read at fixed li, spreads bank-starts
static __device__ __forceinline__ int swz4(int r) { return (r + (r >> 2)) & 3; }

// async global->LDS, 16B per lane; LDS dest = wave-uniform base + lane*16
static __device__ __forceinline__ void gload16(const void* g, void* l) {
  __builtin_amdgcn_global_load_lds(
      (const __attribute__((address_space(1))) void*)g,
      (__attribute__((address_space(3))) void*)l, 16, 0, 0);
}

// ------- merged prep: fp32->bf16 convert (v_tok,t_tok) + W transpose->bf16 -------
__global__ void k_prep(const float* __restrict__ va, short* __restrict__ vo, int na8,
                       const float* __restrict__ ta, short* __restrict__ to, int nb8,
                       const float* __restrict__ W0, const float* __restrict__ W1,
                       short* __restrict__ T0, short* __restrict__ T1) {
  __shared__ float tile[32][33];
  int blk = blockIdx.x;
  int tid = threadIdx.x;
  if (blk < 6240) {
    int i = blk * 256 + tid;
    const float* in; short* outp; int idx;
    if (i < na8) { in = va; outp = vo; idx = i; }
    else { idx = i - na8; if (idx >= nb8) return; in = ta; outp = to; }
    float4 a = *(const float4*)(in + (size_t)idx * 8);
    float4 b = *(const float4*)(in + (size_t)idx * 8 + 4);
    bf16x8 v;
    v[0] = (short)f2bf(a.x); v[1] = (short)f2bf(a.y);
    v[2] = (short)f2bf(a.z); v[3] = (short)f2bf(a.w);
    v[4] = (short)f2bf(b.x); v[5] = (short)f2bf(b.y);
    v[6] = (short)f2bf(b.z); v[7] = (short)f2bf(b.w);
    *(bf16x8*)(outp + (size_t)idx * 8) = v;
  } else {
    int z = blk - 6240;            // 0..767 = 24 x 16 x 2
    int bx = z % 24, by = (z / 24) % 16, bz = z / 384;
    const float* W = bz ? W1 : W0;
    short*       T = bz ? T1 : T0;
    int k0 = bx * 32, n0 = by * 32;
    int tx = tid & 31, ty = tid >> 5;
    for (int i = ty; i < 32; i += 8)
      tile[i][tx] = W[(size_t)(k0 + i) * EDIM + n0 + tx];
    __syncthreads();
    for (int i = ty; i < 32; i += 8)
      T[(size_t)(n0 + i) * KDIM + k0 + tx] = (short)f2bf(tile[tx][i]);
  }
}

// ---------- MFMA projection (merged v+t), 128x128 tile: 16 MFMA/wave/kc ----
// dbuf + counted vmcnt(4); per-lane src pointers hoisted, advance 64B/kc.
__global__ __launch_bounds__(256, 4) void k_proj_mfma2(
    const short* __restrict__ vX, const short* __restrict__ tX,
    const short* __restrict__ WvT, const short* __restrict__ WtT,
    const float* __restrict__ vb, const float* __restrict__ tb,
    short* __restrict__ vout, short* __restrict__ tout) {
  __shared__ short As[2][128 * 32];
  __shared__ short Bs[2][128 * 32];
  int y = blockIdx.y;
  const short* Xbf; const short* WT; const float* bias; short* Mbf; int r0;
  if (y < 98) { Xbf = vX; WT = WvT; bias = vb; Mbf = vout; r0 = y * 128; }
  else        { Xbf = tX; WT = WtT; bias = tb; Mbf = tout; r0 = (y - 98) * 128; }
  int n0 = blockIdx.x * 128;
  int tid = threadIdx.x;
  int w = tid >> 6, lane = tid & 63, lg = lane >> 4, li = lane & 15;
  int fsw = (li + (li >> 2)) & 3;

  const short* aSrc[2];
  const short* bSrc[2];
#pragma unroll
  for (int uu = 0; uu < 2; ++uu) {
    int u = uu * 256 + w * 64 + lane;
    int row = u >> 2, seg = u & 3;
    int ss = seg ^ swz4(row);
    aSrc[uu] = Xbf + (size_t)(r0 + row) * KDIM + ss * 8;
    bSrc[uu] = WT + (size_t)(n0 + row) * KDIM + ss * 8;
  }

  auto stage = [&](int bb) {
    short* Ad = &As[bb][0];
    short* Bd = &Bs[bb][0];
#pragma unroll
    for (int uu = 0; uu < 2; ++uu) {
      gload16(aSrc[uu], Ad + (uu * 256 + w * 64) * 8);
      aSrc[uu] += 32;
      gload16(bSrc[uu], Bd + (uu * 256 + w * 64) * 8);
      bSrc[uu] += 32;
    }
  };

  f32x4 acc[2][8];
#pragma unroll
  for (int i = 0; i < 2; ++i)
#pragma unroll
    for (int j = 0; j < 8; ++j) acc[i][j] = (f32x4){0.f, 0.f, 0.f, 0.f};

  stage(0);   // 4 loads in flight
  int cur = 0;
  const int NKC = KDIM / 32;  // 24
  for (int kc = 0; kc < NKC; ++kc) {
    __builtin_amdgcn_s_barrier();
    if (kc < NKC - 1) {
      stage(cur ^ 1);
      asm volatile("s_waitcnt vmcnt(4)" ::: "memory");
    } else {
      asm volatile("s_waitcnt vmcnt(0)" ::: "memory");
    }
    __builtin_amdgcn_s_barrier();
    const short* Ab = &As[cur][0];
    const short* Bb = &Bs[cur][0];
    bf16x8 bfr[8];
#pragma unroll
    for (int j = 0; j < 8; ++j)
      bfr[j] = *(const bf16x8*)(Bb + (j * 16 + li) * 32 + (lg ^ fsw) * 8);
    __builtin_amdgcn_s_setprio(1);
#pragma unroll
    for (int i = 0; i < 2; ++i) {
      bf16x8 afr = *(const bf16x8*)(Ab + ((w * 2 + i) * 16 + li) * 32 + (lg ^ fsw) * 8);
#pragma unroll
      for (int j = 0; j < 8; ++j)
        acc[i][j] = __builtin_amdgcn_mfma_f32_16x16x32_bf16(afr, bfr[j], acc[i][j], 0, 0, 0);
    }
    __builtin_amdgcn_s_setprio(0);
    cur ^= 1;
  }
#pragma unroll
  for (int j = 0; j < 8; ++j) {
    int n = n0 + j * 16 + li;
    float bb = bias[n];
#pragma unroll
    for (int i = 0; i < 2; ++i)
#pragma unroll
      for (int reg = 0; reg < 4; ++reg)
        Mbf[(size_t)(r0 + (w * 2 + i) * 16 + lg * 4 + reg) * EDIM + n] =
            (short)f2bf(acc[i][j][reg] + bb);
  }
}

// ------- per-row (bf16 in place): fc scalar + l2 normalize; merged v+t -------
__global__ void k_normfc2(short* __restrict__ vM, short* __restrict__ tM,
                          const float* __restrict__ vfcw, const float* __restrict__ tfcw,
                          const float* __restrict__ vfcb, const float* __restrict__ tfcb,
                          float* __restrict__ vwout, float* __restrict__ twout) {
  int blk = blockIdx.x;
  short* Mbf; const float* fcw; const float* fcb; float* wout; int row;
  if (blk < 3136) { Mbf = vM; fcw = vfcw; fcb = vfcb; wout = vwout;
                    row = blk * 4 + (threadIdx.x >> 6); if (row >= 12544) return; }
  else            { Mbf = tM; fcw = tfcw; fcb = tfcb; wout = twout;
                    row = (blk - 3136) * 4 + (threadIdx.x >> 6); if (row >= 4096) return; }
  int lane = threadIdx.x & 63;
  short* p = Mbf + (size_t)row * EDIM + lane * 8;
  bf16x8 v = *(bf16x8*)p;
  float4 w0 = *(const float4*)(fcw + lane * 8);
  float4 w1 = *(const float4*)(fcw + lane * 8 + 4);
  float a[8];
#pragma unroll
  for (int j = 0; j < 8; ++j) a[j] = bf2f(v[j]);
  float dot = a[0] * w0.x + a[1] * w0.y + a[2] * w0.z + a[3] * w0.w +
              a[4] * w1.x + a[5] * w1.y + a[6] * w1.z + a[7] * w1.w;
  float ss = a[0] * a[0] + a[1] * a[1] + a[2] * a[2] + a[3] * a[3] +
             a[4] * a[4] + a[5] * a[5] + a[6] * a[6] + a[7] * a[7];
  for (int s = 1; s < 64; s <<= 1) {
    dot += __shfl_xor(dot, s);
    ss += __shfl_xor(ss, s);
  }
  float inv = 1.0f / fmaxf(sqrtf(ss), 1e-12f);
#pragma unroll
  for (int j = 0; j < 8; ++j) v[j] = (short)f2bf(a[j] * inv);
  *(bf16x8*)p = v;
  if (lane == 0) wout[row] = dot + fcb[0];
}

// ---------------- softmax: blocks 0..63 vw rows (196), 64..127 tw rows (64, masked) ----
__global__ void k_softmax(float* __restrict__ vwf, float* __restrict__ twf,
                          const int* __restrict__ tlen) {
  __shared__ float red[8];
  int tid = threadIdx.x;
  if (blockIdx.x < 64) {
    int b = blockIdx.x;
    float x = (tid < NV) ? vwf[b * NV + tid] : -1e30f;
    float m = x;
    for (int s = 1; s < 64; s <<= 1) m = fmaxf(m, __shfl_xor(m, s));
    if ((tid & 63) == 0) red[tid >> 6] = m;
    __syncthreads();
    m = fmaxf(fmaxf(red[0], red[1]), fmaxf(red[2], red[3]));
    float e = (tid < NV) ? expf(x - m) : 0.0f;
    float s = e;
    for (int st = 1; st < 64; st <<= 1) s += __shfl_xor(s, st);
    if ((tid & 63) == 0) red[4 + (tid >> 6)] = s;
    __syncthreads();
    s = red[4] + red[5] + red[6] + red[7];
    if (tid < NV) vwf[b * NV + tid] = e / s;
  } else {
    int b = blockIdx.x - 64;
    if (tid < 64) {
      int len = tlen[b];
      float x = twf[b * NT + tid];
      bool valid = tid < len;
      float xv = valid ? x : -1e30f;
      float m = xv;
      for (int s = 1; s < 64; s <<= 1) m = fmaxf(m, __shfl_xor(m, s));
      float e = valid ? expf(x - m) : 0.0f;
      float s = e;
      for (int st = 1; st < 64; st <<= 1) s += __shfl_xor(s, st);
      twf[b * NT + tid] = e / s;
    }
  }
}

// ---------------- MFMA sim kernel: one block (8 waves) per (b, q-pair) --------------
// (r12-exact: measured session best 111 us)
__global__ __launch_bounds__(512, 4) void k_sim(
    const short* __restrict__ ve_bf, const short* __restrict__ te_bf,
    const float* __restrict__ vwf, const float* __restrict__ twf,
    float* __restrict__ out, int* __restrict__ gMT, int* __restrict__ gMV) {
  __shared__ short As[2][208 * 32];   // linear, 64B row stride
  __shared__ short Bs[2][128 * 32];
  __shared__ float colv[8][64];
  __shared__ int   coli[8][64];
  __shared__ float redp[8];
  int n = blockIdx.x;
  int xcd = n & 7, idx = n >> 3;
  int b = xcd * 8 + (idx & 7);     // b-fastest within XCD chunk (ve L2-resident)
  int qq = idx >> 3;               // 0..31
  int tid = threadIdx.x;
  int w = tid >> 6, lane = tid & 63, lg = lane >> 4, li = lane & 15;
  int qsel = w >> 2, wr = w & 3;
  int q = 2 * qq + qsel;
  const short* Abf = ve_bf + (size_t)b * NV * EDIM;
  const short* Bbf = te_bf + (size_t)qq * 128 * EDIM;  // rows 0-63: q0, 64-127: q1
  int fsw = (li + (li >> 2)) & 3;
  int nt = wr ? 3 : 4;
  int tbase = wr ? (1 + wr * 3) : 0;  // wr0:0-3, wr1:4-6, wr2:7-9, wr3:10-12

  const short* aSrc[2];
#pragma unroll
  for (int uu = 0; uu < 2; ++uu) {
    int u = uu * 512 + w * 64 + lane;
    int row = u >> 2;
    if (row > NV - 1) row = NV - 1;
    int seg = u & 3;
    int ss = seg ^ swz4(row);
    aSrc[uu] = Abf + (size_t)row * EDIM + ss * 8;
  }
  const short* bSrc;
  {
    int u = tid;                     // 512 units = 128 rows x 4 segs
    int row = u >> 2, seg = u & 3;
    int ss = seg ^ swz4(row);
    bSrc = Bbf + (size_t)row * EDIM + ss * 8;
  }

  auto stage = [&](int bb) {         // w0-4: 3 loads, w5-7: 2 loads
    short* Ad = &As[bb][0];
    short* Bd = &Bs[bb][0];
    gload16(bSrc, Bd + (w * 64) * 8);
    bSrc += 32;
#pragma unroll
    for (int uu = 0; uu < 2; ++uu) {
      int u0 = uu * 512 + w * 64;
      if (u0 < NV * 4) {
        gload16(aSrc[uu], Ad + u0 * 8);
        aSrc[uu] += 32;
      }
    }
  };

  f32x4 acc[4][4];
#pragma unroll
  for (int i = 0; i < 4; ++i)
#pragma unroll
    for (int j = 0; j < 4; ++j) acc[i][j] = (f32x4){0.f, 0.f, 0.f, 0.f};

  stage(0);
  int cur = 0;
  for (int kc = 0; kc < 16; ++kc) {
    __builtin_amdgcn_s_barrier();      // all waves done reading buf[cur^1]
    if (kc < 15) {
      stage(cur ^ 1);
      if (w <= 4) asm volatile("s_waitcnt vmcnt(3)" ::: "memory");
      else        asm volatile("s_waitcnt vmcnt(2)" ::: "memory");
    } else {
      asm volatile("s_waitcnt vmcnt(0)" ::: "memory");
    }
    __builtin_amdgcn_s_barrier();      // buf[cur] visible to all waves
    const short* Ab2 = &As[cur][0];
    const short* Bb2 = &Bs[cur][0];
    bf16x8 bfr[4];
#pragma unroll
    for (int j = 0; j < 4; ++j)
      bfr[j] = *(const bf16x8*)(Bb2 + (qsel * 64 + j * 16 + li) * 32 + (lg ^ fsw) * 8);
    __builtin_amdgcn_s_setprio(1);
#pragma unroll
    for (int i = 0; i < 4; ++i) {
      if (i < nt) {
        bf16x8 afr = *(const bf16x8*)(Ab2 + ((tbase + i) * 16 + li) * 32 + (lg ^ fsw) * 8);
#pragma unroll
        for (int j = 0; j < 4; ++j)
          acc[i][j] = __builtin_amdgcn_mfma_f32_16x16x32_bf16(afr, bfr[j], acc[i][j], 0, 0, 0);
      }
    }
    __builtin_amdgcn_s_setprio(0);
    cur ^= 1;
  }

  bool diag = (b == q);
  // ---- row (over t) max+argmax for this wave's q; C: row=T*16+lg*4+reg, col=j*16+li
  float ip = 0.f;
#pragma unroll
  for (int i = 0; i < 4; ++i) {
    if (i < nt) {
#pragma unroll
      for (int reg = 0; reg < 4; ++reg) {
        int v = (tbase + i) * 16 + lg * 4 + reg;
        float m = acc[i][0][reg];
        int ti = li;
#pragma unroll
        for (int j = 1; j < 4; ++j) {
          float vv = acc[i][j][reg];
          int t = j * 16 + li;
          if (vv > m) { m = vv; ti = t; }   // t ascending -> first-index kept
        }
        for (int d = 1; d < 16; d <<= 1) {  // within li-group (same row)
          float om = __shfl_xor(m, d);
          int oi = __shfl_xor(ti, d);
          if (om > m || (om == m && oi < ti)) { m = om; ti = oi; }
        }
        if (li == 0 && v < NV) {
          ip += vwf[b * NV + v] * m;
          if (diag) gMT[b * NV + v] = b * NT + ti;
        }
      }
    }
  }
  for (int d = 1; d < 64; d <<= 1) ip += __shfl_xor(ip, d);
  if (lane == 0) redp[w] = ip;
  // ---- col (over v) max+argmax for this wave's rows (its q's 64 cols)
  float cm[4]; int cv[4];
#pragma unroll
  for (int j = 0; j < 4; ++j) { cm[j] = -3.0e38f; cv[j] = 0; }
#pragma unroll
  for (int i = 0; i < 4; ++i) {
    if (i < nt) {
#pragma unroll
      for (int reg = 0; reg < 4; ++reg) {
        int v = (tbase + i) * 16 + lg * 4 + reg;
        bool ok = v < NV;
#pragma unroll
        for (int j = 0; j < 4; ++j) {
          float s = ok ? acc[i][j][reg] : -3.0e38f;
          if (s > cm[j]) { cm[j] = s; cv[j] = v; }  // v ascending per lane
        }
      }
    }
  }
#pragma unroll
  for (int j = 0; j < 4; ++j) {
    for (int d = 16; d < 64; d <<= 1) {   // mixes lg groups (same col)
      float om = __shfl_xor(cm[j], d);
      int ov = __shfl_xor(cv[j], d);
      if (om > cm[j] || (om == cm[j] && ov < cv[j])) { cm[j] = om; cv[j] = ov; }
    }
    if (lg == 0) { colv[w][j * 16 + li] = cm[j]; coli[w][j * 16 + li] = cv[j]; }
  }
  __syncthreads();
  if (tid < 128) {   // tid>>6==0 -> q0 (colv 0-3), ==1 -> q1 (colv 4-7)
    int qs = tid >> 6, t = tid & 63;
    int qe = 2 * qq + qs;
    float m = colv[qs * 4][t];
    int bi = coli[qs * 4][t];
#pragma unroll
    for (int w2 = 1; w2 < 4; ++w2) {
      float om = colv[qs * 4 + w2][t];
      int ov = coli[qs * 4 + w2][t];
      if (om > m || (om == m && ov < bi)) { m = om; bi = ov; }
    }
    if (b == qe) gMV[b * NT + t] = b * NV + bi;
    float p = twf[qe * NT + t] * m;
    for (int d = 1; d < 64; d <<= 1) p += __shfl_xor(p, d);
    if ((tid & 63) == 0) out[4096 + b * 64 + qe] = p;
  }
  if (tid == 0) {
    out[b * 64 + 2 * qq]     = redp[0] + redp[1] + redp[2] + redp[3];
    out[b * 64 + 2 * qq + 1] = redp[4] + redp[5] + redp[6] + redp[7];
  }
}

// ------- transpose-materialize + FUSED column stats (sum, sumsq, wsum) --------------
__global__ void k_materialize(const short* __restrict__ ve_bf, const short* __restrict__ te_bf,
                              const int* __restrict__ gMT, const int* __restrict__ gMV,
                              const float* __restrict__ vwf, const float* __restrict__ twf,
                              short* __restrict__ tTw, short* __restrict__ mvT,
                              short* __restrict__ vTw, short* __restrict__ mtT,
                              float* __restrict__ statPart) {
  int z = blockIdx.z;
  int at = blockIdx.x, ct = blockIdx.y;
  int K = (z == 2 || z == 3) ? MROWS_V : MROWS_T;
  if (at * 64 >= K) return;
  const short* src; const int* g = 0; short* dst;
  bool applyW;
  const float* wS = (z <= 1) ? twf : vwf;
  if (z == 0)      { src = te_bf; dst = tTw; applyW = true;  }
  else if (z == 1) { src = ve_bf; g = gMV; dst = mvT; applyW = false; }
  else if (z == 2) { src = ve_bf; dst = vTw; applyW = true;  }
  else             { src = te_bf; g = gMT; dst = mtT; applyW = false; }
  __shared__ float tile[64][67];
  __shared__ float wrow[64];
  int tid = threadIdx.x;
  for (int u = tid; u < 512; u += 256) {
    int a = u >> 3, cseg = (u & 7) << 3;
    int ga = at * 64 + a;
    int row = g ? g[ga] : ga;
    bf16x8 vv = *(const bf16x8*)(src + (size_t)row * EDIM + ct * 64 + cseg);
#pragma unroll
    for (int j = 0; j < 8; j++) tile[a][cseg + j] = bf2f(vv[j]);
    if ((u & 7) == 0) wrow[a] = wS[ga];
  }
  __syncthreads();
  for (int u = tid; u < 512; u += 256) {
    int c = u >> 3, aseg = (u & 7) << 3;
    bf16x8 ov;
#pragma unroll
    for (int j = 0; j < 8; j++) {
      float x = tile[aseg + j][c];
      if (applyW) x *= wrow[aseg + j];
      ov[j] = (short)f2bf(x);
    }
    *(bf16x8*)(dst + (size_t)(ct * 64 + c) * K + at * 64 + aseg) = ov;
  }
  // ---- fused stats partials: 4 threads per column, 16 a's each
  int cl = tid >> 2, part = tid & 3;
  float s = 0, ssq = 0, sw = 0;
  for (int a = part * 16; a < part * 16 + 16; ++a) {
    float x = tile[a][cl];
    s += x; ssq += x * x; sw += wrow[a] * x;
  }
  for (int d = 1; d < 4; d <<= 1) {   // 4 consecutive lanes share a column
    s += __shfl_xor(s, d); ssq += __shfl_xor(ssq, d); sw += __shfl_xor(sw, d);
  }
  if (part == 0) {
    int cbase = (z == 0) ? 0 : (z == 1) ? 64 : (z == 2) ? 128 : 324;
    size_t sidx = ((size_t)(cbase + at) * 512 + ct * 64 + cl) * 3;
    statPart[sidx] = s; statPart[sidx + 1] = ssq; statPart[sidx + 2] = sw;
  }
}

__global__ void k_statfin(const float* __restrict__ statPart, float* __restrict__ stats) {
  int m = blockIdx.x, c = threadIdx.x;
  int R = (m < 2) ? MROWS_T : MROWS_V;
  int nchunk = (m < 2) ? 64 : 196;
  int base = (m == 0) ? 0 : (m == 1) ? 64 : (m == 2) ? 128 : 324;
  float s = 0, ss = 0, sw = 0;
  for (int ch = 0; ch < nchunk; ch++) {
    size_t idx = ((size_t)(base + ch) * 512 + c) * 3;
    s += statPart[idx]; ss += statPart[idx + 1]; sw += statPart[idx + 2];
  }
  float mean = s / R;
  float var = (ss - s * mean) / (R - 1);  // ddof=1
  float rstd = 1.0f / sqrtf(var);
  stats[(m * 3 + 0) * 512 + c] = mean;
  stats[(m * 3 + 1) * 512 + c] = rstd;
  stats[(m * 3 + 2) * 512 + c] = sw;
}

// ------- MFMA weighted GEMM: Spart[z][c][d] = sum_a AT[c][a]*BT[d][a] (split-K 8) ----
__global__ __launch_bounds__(256, 4) void k_wgemm2(
    const short* __restrict__ tTw, const short* __restrict__ mvT,
    const short* __restrict__ vTw, const short* __restrict__ mtT,
    float* __restrict__ Spart) {
  __shared__ short As[2][128 * 32];
  __shared__ short Bs[2][64 * 32];
  int c0 = blockIdx.x * 128, d0 = blockIdx.y * 64;
  int z = blockIdx.z;                 // 0..15
  int which = z >> 3, slice = z & 7;
  const short* A = which ? vTw : tTw;
  const short* B = which ? mtT : mvT;
  int K = which ? MROWS_V : MROWS_T;
  int nch = (K >> 3) >> 5;            // 49 or 16 chunks of 32
  int a0 = slice * (K >> 3);
  int tid = threadIdx.x;
  int w = tid >> 6, lane = tid & 63, lg = lane >> 4, li = lane & 15;
  int fsw = (li + (li >> 2)) & 3;

  const short* aSrc[2];
#pragma unroll
  for (int uu = 0; uu < 2; ++uu) {
    int u = uu * 256 + w * 64 + lane;
    int row = u >> 2, seg = u & 3;
    int ss = seg ^ swz4(row);
    aSrc[uu] = A + (size_t)(c0 + row) * K + a0 + ss * 8;
  }
  const short* bSrc;
  {
    int u = w * 64 + lane;
    int row = u >> 2, seg = u & 3;
    int ss = seg ^ swz4(row);
    bSrc = B + (size_t)(d0 + row) * K + a0 + ss * 8;
  }

  auto stage = [&](int bb) {
    short* Ad = &As[bb][0];
    short* Bd = &Bs[bb][0];
#pragma unroll
    for (int uu = 0; uu < 2; ++uu) {
      gload16(aSrc[uu], Ad + (uu * 256 + w * 64) * 8);
      aSrc[uu] += 32;
    }
    gload16(bSrc, Bd + (w * 64) * 8);
    bSrc += 32;
  };

  f32x4 acc[2][4];
#pragma unroll
  for (int i = 0; i < 2; ++i)
#pragma unroll
    for (int j = 0; j < 4; ++j) acc[i][j] = (f32x4){0.f, 0.f, 0.f, 0.f};

  stage(0);
  int cur = 0;
  for (int ch = 0; ch < nch; ++ch) {
    __builtin_amdgcn_s_barrier();
    if (ch < nch - 1) {
      stage(cur ^ 1);
      asm volatile("s_waitcnt vmcnt(3)" ::: "memory");
    } else {
      asm volatile("s_waitcnt vmcnt(0)" ::: "memory");
    }
    __builtin_amdgcn_s_barrier();
    const short* Ab = &As[cur][0];
    const short* Bb = &Bs[cur][0];
    bf16x8 bfr[4];
#pragma unroll
    for (int j = 0; j < 4; ++j)
      bfr[j] = *(const bf16x8*)(Bb + (j * 16 + li) * 32 + (lg ^ fsw) * 8);
#pragma unroll
    for (int i = 0; i < 2; ++i) {
      bf16x8 afr = *(const bf16x8*)(Ab + ((w * 2 + i) * 16 + li) * 32 + (lg ^ fsw) * 8);
#pragma unroll
      for (int j = 0; j < 4; ++j)
        acc[i][j] = __builtin_amdgcn_mfma_f32_16x16x32_bf16(afr, bfr[j], acc[i][j], 0, 0, 0);
    }
    cur ^= 1;
  }
  float* outp = Spart + (size_t)z * 512 * 512;
#pragma unroll
  for (int j = 0; j < 4; ++j) {
    int d = d0 + j * 16 + li;
#pragma unroll
    for (int i = 0; i < 2; ++i)
#pragma unroll
      for (int reg = 0; reg < 4; ++reg)
        outp[(size_t)(c0 + (w * 2 + i) * 16 + lg * 4 + reg) * 512 + d] = acc[i][j][reg];
  }
}

// ---------------- assemble c = (c1+c2)/2 from closed form; loss partials ----------
__global__ void k_assemble(const float* __restrict__ Spart, const float* __restrict__ stats,
                           float* __restrict__ lossPart) {
  int c = blockIdx.x, tid = threadIdx.x;
  float muT = stats[0 * 512 + c], rsT = stats[1 * 512 + c], swT = stats[2 * 512 + c];
  float muV = stats[6 * 512 + c], rsV = stats[7 * 512 + c], swV = stats[8 * 512 + c];
  const float W = 64.0f, invB = 1.0f / 64.0f;
  float on = 0, off = 0;
  for (int d = tid; d < 512; d += 256) {
    float s1 = 0, s2 = 0;
    for (int sl = 0; sl < 8; sl++) {
      s1 += Spart[((size_t)sl * 512 + c) * 512 + d];
      s2 += Spart[((size_t)(8 + sl) * 512 + c) * 512 + d];
    }
    float muMV = stats[3 * 512 + d], rsMV = stats[4 * 512 + d], swMV = stats[5 * 512 + d];
    float muMT = stats[9 * 512 + d], rsMT = stats[10 * 512 + d], swMT = stats[11 * 512 + d];
    float c1 = (s1 - muT * swMV - muMV * swT + muT * muMV * W) * rsT * rsMV * invB;
    float c2 = (s2 - muV * swMT - muMT * swV + muV * muMT * W) * rsV * rsMT * invB;
    float cc = 0.5f * (c1 + c2);
    if (d == c) { float dd = cc - 1.0f; on += dd * dd; }
    else off += cc * cc;
  }
  __shared__ float r1[4], r2[4];
  for (int s = 1; s < 64; s <<= 1) { on += __shfl_xor(on, s); off += __shfl_xor(off, s); }
  if ((tid & 63) == 0) { r1[tid >> 6] = on; r2[tid >> 6] = off; }
  __syncthreads();
  if (tid == 0) {
    lossPart[c * 2] = r1[0] + r1[1] + r1[2] + r1[3];
    lossPart[c * 2 + 1] = r2[0] + r2[1] + r2[2] + r2[3];
  }
}

__global__ void k_loss(const float* __restrict__ lossPart, float* __restrict__ out) {
  int tid = threadIdx.x;
  float on = 0, off = 0;
  for (int i = tid; i < 512; i += 256) { on += lossPart[2 * i]; off += lossPart[2 * i + 1]; }
  __shared__ float r1[4], r2[4];
  for (int s = 1; s < 64; s <<= 1) { on += __shfl_xor(on, s); off += __shfl_xor(off, s); }
  if ((tid & 63) == 0) { r1[tid >> 6] = on; r2[tid >> 6] = off; }
  __syncthreads();
  if (tid == 0)
    out[8192] = 0.1f * ((r1[0] + r1[1] + r1[2] + r1[3]) +
                        0.06f * (r2[0] + r2[1] + r2[2] + r2[3]));
}

extern "C" void kernel_launch(void* const* d_in, const int* in_sizes, int n_in,
                              void* d_out, int out_size, void* d_ws, size_t ws_size,
                              hipStream_t stream) {
  (void)in_sizes; (void)n_in; (void)out_size; (void)ws_size;
  const float* v_tok  = (const float*)d_in[1];
  const float* t_tok  = (const float*)d_in[3];
  const float* Wv_tok = (const float*)d_in[8];
  const float* Wt_tok = (const float*)d_in[10];
  const float* bv_tok = (const float*)d_in[9];
  const float* bt_tok = (const float*)d_in[11];
  const float* wv_fc  = (const float*)d_in[12];
  const float* bv_fc  = (const float*)d_in[13];
  const float* wt_fc  = (const float*)d_in[14];
  const float* bt_fc  = (const float*)d_in[15];
  const int*   tlen   = (const int*)d_in[16];
  float* out = (float*)d_out;

  char* wsb = (char*)d_ws;
  short* v_tok_bf = (short*)wsb;                       // 9,633,792 sh
  short* t_tok_bf = v_tok_bf + (size_t)9633792;        // 3,145,728 sh
  short* WvT      = t_tok_bf + (size_t)3145728;        //   393,216 sh
  short* WtT      = WvT + (size_t)393216;              //   393,216 sh
  short* tTw = (short*)wsb;                            // 512*4096 (alias, phase2)
  short* mvT = tTw + (size_t)2097152;                  // 512*4096
  short* vTw = mvT + (size_t)2097152;                  // 512*12544
  short* ve_bf = (short*)(wsb + 27131904);             // 6,422,528 sh
  short* te_bf = ve_bf + (size_t)6422528;              // 2,097,152 sh
  float* Spart = (float*)(wsb + 27131904);             // 16*512*512 f (alias, phase-b)
  short* mtT = (short*)(wsb + 44171264);               // 512*12544
  float* vwf = (float*)(wsb + 57016320);               // 12544
  float* twf = vwf + 12544;                            // 4096
  int* gMT = (int*)(twf + 4096);                       // 12544
  int* gMV = gMT + 12544;                              // 4096
  float* statPart = (float*)(gMV + 4096);              // 520*512*3 f (3.2 MB)
  float* stats = statPart + (size_t)520 * 512 * 3;     // 12*512
  float* lossPart = stats + 6144;                      // 1024

  k_prep<<<7008, 256, 0, stream>>>(v_tok, v_tok_bf, 1204224, t_tok, t_tok_bf, 393216,
                                   Wv_tok, Wt_tok, WvT, WtT);
  k_proj_mfma2<<<dim3(4, 130), 256, 0, stream>>>(v_tok_bf, t_tok_bf, WvT, WtT,
                                                 bv_tok, bt_tok, ve_bf, te_bf);
  k_normfc2<<<4160, 256, 0, stream>>>(ve_bf, te_bf, wv_fc, wt_fc, bv_fc, bt_fc, vwf, twf);
  k_softmax<<<128, 256, 0, stream>>>(vwf, twf, tlen);
  k_sim<<<2048, 512, 0, stream>>>(ve_bf, te_bf, vwf, twf, out, gMT, gMV);
  k_materialize<<<dim3(196, 8, 4), 256, 0, stream>>>(ve_bf, te_bf, gMT, gMV, vwf, twf,
                                                     tTw, mvT, vTw, mtT, statPart);
  k_statfin<<<4, 512, 0, stream>>>(statPart, stats);
  k_wgemm2<<<dim3(4, 8, 16), 256, 0, stream>>>(tTw, mvT, vTw, mtT, Spart);
  k_assemble<<<512, 256, 0, stream>>>(Spart, stats, lossPart);
  k_loss<<<1, 256, 0, stream>>>(lossPart, out);
}

// Round 15
// 246.719 us; speedup vs baseline: 3.6475x; 1.0393x over previous
//
#include <hip/hip_runtime.h>
#include <cstddef>

#define EDIM 512
#define KDIM 768
#define NB 64
#define NV 196
#define NT 64
#define MROWS_V (NB * NV) /* 12544 */
#define MROWS_T (NB * NT) /* 4096  */

typedef __attribute__((ext_vector_type(8))) short bf16x8;
typedef __attribute__((ext_vector_type(4))) float f32x4;

static __device__ inline unsigned short f2bf(float f) {  // round-to-nearest-even
  unsigned u = __float_as_uint(f);
  unsigned r = (u + 0x7fff + ((u >> 16) & 1)) >> 16;
  return (unsigned short)r;
}
static __device__ inline float bf2f(short s) {
  return __uint_as_float(((unsigned)(unsigned short)s) << 16);
}
// seg swizzle: for row-tiles read at fixed li, spreads bank-starts
static __device__ __forceinline__ int swz4(int r) { return (r + (r >> 2)) & 3; }

// async global->LDS, 16B per lane; LDS dest = wave-uniform base + lane*16
static __device__ __forceinline__ void gload16(const void* g, void* l) {
  __builtin_amdgcn_global_load_lds(
      (const __attribute__((address_space(1))) void*)g,
      (__attribute__((address_space(3))) void*)l, 16, 0, 0);
}

// ------- merged prep: fp32->bf16 convert (v_tok,t_tok) + W transpose->bf16 -------
__global__ void k_prep(const float* __restrict__ va, short* __restrict__ vo, int na8,
                       const float* __restrict__ ta, short* __restrict__ to, int nb8,
                       const float* __restrict__ W0, const float* __restrict__ W1,
                       short* __restrict__ T0, short* __restrict__ T1) {
  __shared__ float tile[32][33];
  int blk = blockIdx.x;
  int tid = threadIdx.x;
  if (blk < 6240) {
    int i = blk * 256 + tid;
    const float* in; short* outp; int idx;
    if (i < na8) { in = va; outp = vo; idx = i; }
    else { idx = i - na8; if (idx >= nb8) return; in = ta; outp = to; }
    float4 a = *(const float4*)(in + (size_t)idx * 8);
    float4 b = *(const float4*)(in + (size_t)idx * 8 + 4);
    bf16x8 v;
    v[0] = (short)f2bf(a.x); v[1] = (short)f2bf(a.y);
    v[2] = (short)f2bf(a.z); v[3] = (short)f2bf(a.w);
    v[4] = (short)f2bf(b.x); v[5] = (short)f2bf(b.y);
    v[6] = (short)f2bf(b.z); v[7] = (short)f2bf(b.w);
    *(bf16x8*)(outp + (size_t)idx * 8) = v;
  } else {
    int z = blk - 6240;            // 0..767 = 24 x 16 x 2
    int bx = z % 24, by = (z / 24) % 16, bz = z / 384;
    const float* W = bz ? W1 : W0;
    short*       T = bz ? T1 : T0;
    int k0 = bx * 32, n0 = by * 32;
    int tx = tid & 31, ty = tid >> 5;
    for (int i = ty; i < 32; i += 8)
      tile[i][tx] = W[(size_t)(k0 + i) * EDIM + n0 + tx];
    __syncthreads();
    for (int i = ty; i < 32; i += 8)
      T[(size_t)(n0 + i) * KDIM + k0 + tx] = (short)f2bf(tile[tx][i]);
  }
}

// ---------- MFMA projection (merged v+t), 128x128 tile: 16 MFMA/wave/kc ----
__global__ __launch_bounds__(256, 4) void k_proj_mfma2(
    const short* __restrict__ vX, const short* __restrict__ tX,
    const short* __restrict__ WvT, const short* __restrict__ WtT,
    const float* __restrict__ vb, const float* __restrict__ tb,
    short* __restrict__ vout, short* __restrict__ tout) {
  __shared__ short As[2][128 * 32];
  __shared__ short Bs[2][128 * 32];
  int y = blockIdx.y;
  const short* Xbf; const short* WT; const float* bias; short* Mbf; int r0;
  if (y < 98) { Xbf = vX; WT = WvT; bias = vb; Mbf = vout; r0 = y * 128; }
  else        { Xbf = tX; WT = WtT; bias = tb; Mbf = tout; r0 = (y - 98) * 128; }
  int n0 = blockIdx.x * 128;
  int tid = threadIdx.x;
  int w = tid >> 6, lane = tid & 63, lg = lane >> 4, li = lane & 15;
  int fsw = (li + (li >> 2)) & 3;

  const short* aSrc[2];
  const short* bSrc[2];
#pragma unroll
  for (int uu = 0; uu < 2; ++uu) {
    int u = uu * 256 + w * 64 + lane;
    int row = u >> 2, seg = u & 3;
    int ss = seg ^ swz4(row);
    aSrc[uu] = Xbf + (size_t)(r0 + row) * KDIM + ss * 8;
    bSrc[uu] = WT + (size_t)(n0 + row) * KDIM + ss * 8;
  }

  auto stage = [&](int bb) {
    short* Ad = &As[bb][0];
    short* Bd = &Bs[bb][0];
#pragma unroll
    for (int uu = 0; uu < 2; ++uu) {
      gload16(aSrc[uu], Ad + (uu * 256 + w * 64) * 8);
      aSrc[uu] += 32;
      gload16(bSrc[uu], Bd + (uu * 256 + w * 64) * 8);
      bSrc[uu] += 32;
    }
  };

  f32x4 acc[2][8];
#pragma unroll
  for (int i = 0; i < 2; ++i)
#pragma unroll
    for (int j = 0; j < 8; ++j) acc[i][j] = (f32x4){0.f, 0.f, 0.f, 0.f};

  stage(0);   // 4 loads in flight
  int cur = 0;
  const int NKC = KDIM / 32;  // 24
  for (int kc = 0; kc < NKC; ++kc) {
    __builtin_amdgcn_s_barrier();
    if (kc < NKC - 1) {
      stage(cur ^ 1);
      asm volatile("s_waitcnt vmcnt(4)" ::: "memory");
    } else {
      asm volatile("s_waitcnt vmcnt(0)" ::: "memory");
    }
    __builtin_amdgcn_s_barrier();
    const short* Ab = &As[cur][0];
    const short* Bb = &Bs[cur][0];
    bf16x8 bfr[8];
#pragma unroll
    for (int j = 0; j < 8; ++j)
      bfr[j] = *(const bf16x8*)(Bb + (j * 16 + li) * 32 + (lg ^ fsw) * 8);
    __builtin_amdgcn_s_setprio(1);
#pragma unroll
    for (int i = 0; i < 2; ++i) {
      bf16x8 afr = *(const bf16x8*)(Ab + ((w * 2 + i) * 16 + li) * 32 + (lg ^ fsw) * 8);
#pragma unroll
      for (int j = 0; j < 8; ++j)
        acc[i][j] = __builtin_amdgcn_mfma_f32_16x16x32_bf16(afr, bfr[j], acc[i][j], 0, 0, 0);
    }
    __builtin_amdgcn_s_setprio(0);
    cur ^= 1;
  }
#pragma unroll
  for (int j = 0; j < 8; ++j) {
    int n = n0 + j * 16 + li;
    float bb = bias[n];
#pragma unroll
    for (int i = 0; i < 2; ++i)
#pragma unroll
      for (int reg = 0; reg < 4; ++reg)
        Mbf[(size_t)(r0 + (w * 2 + i) * 16 + lg * 4 + reg) * EDIM + n] =
            (short)f2bf(acc[i][j][reg] + bb);
  }
}

// ------- per-row (bf16 in place): fc scalar + l2 normalize; merged v+t -------
__global__ void k_normfc2(short* __restrict__ vM, short* __restrict__ tM,
                          const float* __restrict__ vfcw, const float* __restrict__ tfcw,
                          const float* __restrict__ vfcb, const float* __restrict__ tfcb,
                          float* __restrict__ vwout, float* __restrict__ twout) {
  int blk = blockIdx.x;
  short* Mbf; const float* fcw; const float* fcb; float* wout; int row;
  if (blk < 3136) { Mbf = vM; fcw = vfcw; fcb = vfcb; wout = vwout;
                    row = blk * 4 + (threadIdx.x >> 6); if (row >= 12544) return; }
  else            { Mbf = tM; fcw = tfcw; fcb = tfcb; wout = twout;
                    row = (blk - 3136) * 4 + (threadIdx.x >> 6); if (row >= 4096) return; }
  int lane = threadIdx.x & 63;
  short* p = Mbf + (size_t)row * EDIM + lane * 8;
  bf16x8 v = *(bf16x8*)p;
  float4 w0 = *(const float4*)(fcw + lane * 8);
  float4 w1 = *(const float4*)(fcw + lane * 8 + 4);
  float a[8];
#pragma unroll
  for (int j = 0; j < 8; ++j) a[j] = bf2f(v[j]);
  float dot = a[0] * w0.x + a[1] * w0.y + a[2] * w0.z + a[3] * w0.w +
              a[4] * w1.x + a[5] * w1.y + a[6] * w1.z + a[7] * w1.w;
  float ss = a[0] * a[0] + a[1] * a[1] + a[2] * a[2] + a[3] * a[3] +
             a[4] * a[4] + a[5] * a[5] + a[6] * a[6] + a[7] * a[7];
  for (int s = 1; s < 64; s <<= 1) {
    dot += __shfl_xor(dot, s);
    ss += __shfl_xor(ss, s);
  }
  float inv = 1.0f / fmaxf(sqrtf(ss), 1e-12f);
#pragma unroll
  for (int j = 0; j < 8; ++j) v[j] = (short)f2bf(a[j] * inv);
  *(bf16x8*)p = v;
  if (lane == 0) wout[row] = dot + fcb[0];
}

// ---------------- softmax: blocks 0..63 vw rows (196), 64..127 tw rows (64, masked) ----
__global__ void k_softmax(float* __restrict__ vwf, float* __restrict__ twf,
                          const int* __restrict__ tlen) {
  __shared__ float red[8];
  int tid = threadIdx.x;
  if (blockIdx.x < 64) {
    int b = blockIdx.x;
    float x = (tid < NV) ? vwf[b * NV + tid] : -1e30f;
    float m = x;
    for (int s = 1; s < 64; s <<= 1) m = fmaxf(m, __shfl_xor(m, s));
    if ((tid & 63) == 0) red[tid >> 6] = m;
    __syncthreads();
    m = fmaxf(fmaxf(red[0], red[1]), fmaxf(red[2], red[3]));
    float e = (tid < NV) ? expf(x - m) : 0.0f;
    float s = e;
    for (int st = 1; st < 64; st <<= 1) s += __shfl_xor(s, st);
    if ((tid & 63) == 0) red[4 + (tid >> 6)] = s;
    __syncthreads();
    s = red[4] + red[5] + red[6] + red[7];
    if (tid < NV) vwf[b * NV + tid] = e / s;
  } else {
    int b = blockIdx.x - 64;
    if (tid < 64) {
      int len = tlen[b];
      float x = twf[b * NT + tid];
      bool valid = tid < len;
      float xv = valid ? x : -1e30f;
      float m = xv;
      for (int s = 1; s < 64; s <<= 1) m = fmaxf(m, __shfl_xor(m, s));
      float e = valid ? expf(x - m) : 0.0f;
      float s = e;
      for (int st = 1; st < 64; st <<= 1) s += __shfl_xor(s, st);
      twf[b * NT + tid] = e / s;
    }
  }
}

// ---------------- MFMA sim kernel: one block (8 waves) per (b, q-pair) --------------
// r12 main loop; epilogue split: argmax (with indices) only for diag blocks (b==q),
// value-only fmax path for the other 97% of blocks.
__global__ __launch_bounds__(512, 4) void k_sim(
    const short* __restrict__ ve_bf, const short* __restrict__ te_bf,
    const float* __restrict__ vwf, const float* __restrict__ twf,
    float* __restrict__ out, int* __restrict__ gMT, int* __restrict__ gMV) {
  __shared__ short As[2][208 * 32];   // linear, 64B row stride
  __shared__ short Bs[2][128 * 32];
  __shared__ float colv[8][64];
  __shared__ int   coli[8][64];
  __shared__ float redp[8];
  int n = blockIdx.x;
  int xcd = n & 7, idx = n >> 3;
  int b = xcd * 8 + (idx & 7);     // b-fastest within XCD chunk (ve L2-resident)
  int qq = idx >> 3;               // 0..31
  int tid = threadIdx.x;
  int w = tid >> 6, lane = tid & 63, lg = lane >> 4, li = lane & 15;
  int qsel = w >> 2, wr = w & 3;
  int q = 2 * qq + qsel;
  const short* Abf = ve_bf + (size_t)b * NV * EDIM;
  const short* Bbf = te_bf + (size_t)qq * 128 * EDIM;  // rows 0-63: q0, 64-127: q1
  int fsw = (li + (li >> 2)) & 3;
  int nt = wr ? 3 : 4;
  int tbase = wr ? (1 + wr * 3) : 0;  // wr0:0-3, wr1:4-6, wr2:7-9, wr3:10-12

  const short* aSrc[2];
#pragma unroll
  for (int uu = 0; uu < 2; ++uu) {
    int u = uu * 512 + w * 64 + lane;
    int row = u >> 2;
    if (row > NV - 1) row = NV - 1;
    int seg = u & 3;
    int ss = seg ^ swz4(row);
    aSrc[uu] = Abf + (size_t)row * EDIM + ss * 8;
  }
  const short* bSrc;
  {
    int u = tid;                     // 512 units = 128 rows x 4 segs
    int row = u >> 2, seg = u & 3;
    int ss = seg ^ swz4(row);
    bSrc = Bbf + (size_t)row * EDIM + ss * 8;
  }

  auto stage = [&](int bb) {         // w0-4: 3 loads, w5-7: 2 loads
    short* Ad = &As[bb][0];
    short* Bd = &Bs[bb][0];
    gload16(bSrc, Bd + (w * 64) * 8);
    bSrc += 32;
#pragma unroll
    for (int uu = 0; uu < 2; ++uu) {
      int u0 = uu * 512 + w * 64;
      if (u0 < NV * 4) {
        gload16(aSrc[uu], Ad + u0 * 8);
        aSrc[uu] += 32;
      }
    }
  };

  f32x4 acc[4][4];
#pragma unroll
  for (int i = 0; i < 4; ++i)
#pragma unroll
    for (int j = 0; j < 4; ++j) acc[i][j] = (f32x4){0.f, 0.f, 0.f, 0.f};

  stage(0);
  int cur = 0;
  for (int kc = 0; kc < 16; ++kc) {
    __builtin_amdgcn_s_barrier();      // all waves done reading buf[cur^1]
    if (kc < 15) {
      stage(cur ^ 1);
      if (w <= 4) asm volatile("s_waitcnt vmcnt(3)" ::: "memory");
      else        asm volatile("s_waitcnt vmcnt(2)" ::: "memory");
    } else {
      asm volatile("s_waitcnt vmcnt(0)" ::: "memory");
    }
    __builtin_amdgcn_s_barrier();      // buf[cur] visible to all waves
    const short* Ab2 = &As[cur][0];
    const short* Bb2 = &Bs[cur][0];
    bf16x8 bfr[4];
#pragma unroll
    for (int j = 0; j < 4; ++j)
      bfr[j] = *(const bf16x8*)(Bb2 + (qsel * 64 + j * 16 + li) * 32 + (lg ^ fsw) * 8);
    __builtin_amdgcn_s_setprio(1);
#pragma unroll
    for (int i = 0; i < 4; ++i) {
      if (i < nt) {
        bf16x8 afr = *(const bf16x8*)(Ab2 + ((tbase + i) * 16 + li) * 32 + (lg ^ fsw) * 8);
#pragma unroll
        for (int j = 0; j < 4; ++j)
          acc[i][j] = __builtin_amdgcn_mfma_f32_16x16x32_bf16(afr, bfr[j], acc[i][j], 0, 0, 0);
      }
    }
    __builtin_amdgcn_s_setprio(0);
    cur ^= 1;
  }

  bool diag = (b == q);    // b == 2qq+qsel; per-wave uniform
  bool diagblk = (b >> 1) == qq;  // block contains a diagonal q (block-uniform)
  float ip = 0.f;

  if (diagblk) {
    // ---- full argmax path (indices + tie-break); only 64/2048 blocks
#pragma unroll
    for (int i = 0; i < 4; ++i) {
      if (i < nt) {
#pragma unroll
        for (int reg = 0; reg < 4; ++reg) {
          int v = (tbase + i) * 16 + lg * 4 + reg;
          float m = acc[i][0][reg];
          int ti = li;
#pragma unroll
          for (int j = 1; j < 4; ++j) {
            float vv = acc[i][j][reg];
            int t = j * 16 + li;
            if (vv > m) { m = vv; ti = t; }   // t ascending -> first-index kept
          }
          for (int d = 1; d < 16; d <<= 1) {  // within li-group (same row)
            float om = __shfl_xor(m, d);
            int oi = __shfl_xor(ti, d);
            if (om > m || (om == m && oi < ti)) { m = om; ti = oi; }
          }
          if (li == 0 && v < NV) {
            ip += vwf[b * NV + v] * m;
            if (diag) gMT[b * NV + v] = b * NT + ti;
          }
        }
      }
    }
    // col (over v) max+argmax
    float cm[4]; int cv[4];
#pragma unroll
    for (int j = 0; j < 4; ++j) { cm[j] = -3.0e38f; cv[j] = 0; }
#pragma unroll
    for (int i = 0; i < 4; ++i) {
      if (i < nt) {
#pragma unroll
        for (int reg = 0; reg < 4; ++reg) {
          int v = (tbase + i) * 16 + lg * 4 + reg;
          bool ok = v < NV;
#pragma unroll
          for (int j = 0; j < 4; ++j) {
            float s = ok ? acc[i][j][reg] : -3.0e38f;
            if (s > cm[j]) { cm[j] = s; cv[j] = v; }  // v ascending per lane
          }
        }
      }
    }
#pragma unroll
    for (int j = 0; j < 4; ++j) {
      for (int d = 16; d < 64; d <<= 1) {   // mixes lg groups (same col)
        float om = __shfl_xor(cm[j], d);
        int ov = __shfl_xor(cv[j], d);
        if (om > cm[j] || (om == cm[j] && ov < cv[j])) { cm[j] = om; cv[j] = ov; }
      }
      if (lg == 0) { colv[w][j * 16 + li] = cm[j]; coli[w][j * 16 + li] = cv[j]; }
    }
  } else {
    // ---- value-only path (fmax trees, no index juggling)
#pragma unroll
    for (int i = 0; i < 4; ++i) {
      if (i < nt) {
#pragma unroll
        for (int reg = 0; reg < 4; ++reg) {
          int v = (tbase + i) * 16 + lg * 4 + reg;
          float m = fmaxf(fmaxf(acc[i][0][reg], acc[i][1][reg]),
                          fmaxf(acc[i][2][reg], acc[i][3][reg]));
          for (int d = 1; d < 16; d <<= 1) m = fmaxf(m, __shfl_xor(m, d));
          if (li == 0 && v < NV) ip += vwf[b * NV + v] * m;
        }
      }
    }
    float cm[4];
#pragma unroll
    for (int j = 0; j < 4; ++j) cm[j] = -3.0e38f;
#pragma unroll
    for (int i = 0; i < 4; ++i) {
      if (i < nt) {
#pragma unroll
      for (int reg = 0; reg < 4; ++reg) {
          int v = (tbase + i) * 16 + lg * 4 + reg;
          bool ok = v < NV;
#pragma unroll
          for (int j = 0; j < 4; ++j)
            cm[j] = fmaxf(cm[j], ok ? acc[i][j][reg] : -3.0e38f);
        }
      }
    }
#pragma unroll
    for (int j = 0; j < 4; ++j) {
      for (int d = 16; d < 64; d <<= 1) cm[j] = fmaxf(cm[j], __shfl_xor(cm[j], d));
      if (lg == 0) colv[w][j * 16 + li] = cm[j];
    }
  }
  for (int d = 1; d < 64; d <<= 1) ip += __shfl_xor(ip, d);
  if (lane == 0) redp[w] = ip;
  __syncthreads();
  if (tid < 128) {   // tid>>6==0 -> q0 (colv 0-3), ==1 -> q1 (colv 4-7)
    int qs = tid >> 6, t = tid & 63;
    int qe = 2 * qq + qs;
    float m = colv[qs * 4][t];
    if (diagblk) {
      int bi = coli[qs * 4][t];
#pragma unroll
      for (int w2 = 1; w2 < 4; ++w2) {
        float om = colv[qs * 4 + w2][t];
        int ov = coli[qs * 4 + w2][t];
        if (om > m || (om == m && ov < bi)) { m = om; bi = ov; }
      }
      if (b == qe) gMV[b * NT + t] = b * NV + bi;
    } else {
#pragma unroll
      for (int w2 = 1; w2 < 4; ++w2) m = fmaxf(m, colv[qs * 4 + w2][t]);
    }
    float p = twf[qe * NT + t] * m;
    for (int d = 1; d < 64; d <<= 1) p += __shfl_xor(p, d);
    if ((tid & 63) == 0) out[4096 + b * 64 + qe] = p;
  }
  if (tid == 0) {
    out[b * 64 + 2 * qq]     = redp[0] + redp[1] + redp[2] + redp[3];
    out[b * 64 + 2 * qq + 1] = redp[4] + redp[5] + redp[6] + redp[7];
  }
}

// ------- transpose-materialize + FUSED column stats (sum, sumsq, wsum) --------------
__global__ void k_materialize(const short* __restrict__ ve_bf, const short* __restrict__ te_bf,
                              const int* __restrict__ gMT, const int* __restrict__ gMV,
                              const float* __restrict__ vwf, const float* __restrict__ twf,
                              short* __restrict__ tTw, short* __restrict__ mvT,
                              short* __restrict__ vTw, short* __restrict__ mtT,
                              float* __restrict__ statPart) {
  int z = blockIdx.z;
  int at = blockIdx.x, ct = blockIdx.y;
  int K = (z == 2 || z == 3) ? MROWS_V : MROWS_T;
  if (at * 64 >= K) return;
  const short* src; const int* g = 0; short* dst;
  bool applyW;
  const float* wS = (z <= 1) ? twf : vwf;
  if (z == 0)      { src = te_bf; dst = tTw; applyW = true;  }
  else if (z == 1) { src = ve_bf; g = gMV; dst = mvT; applyW = false; }
  else if (z == 2) { src = ve_bf; dst = vTw; applyW = true;  }
  else             { src = te_bf; g = gMT; dst = mtT; applyW = false; }
  __shared__ float tile[64][67];
  __shared__ float wrow[64];
  int tid = threadIdx.x;
  for (int u = tid; u < 512; u += 256) {
    int a = u >> 3, cseg = (u & 7) << 3;
    int ga = at * 64 + a;
    int row = g ? g[ga] : ga;
    bf16x8 vv = *(const bf16x8*)(src + (size_t)row * EDIM + ct * 64 + cseg);
#pragma unroll
    for (int j = 0; j < 8; j++) tile[a][cseg + j] = bf2f(vv[j]);
    if ((u & 7) == 0) wrow[a] = wS[ga];
  }
  __syncthreads();
  for (int u = tid; u < 512; u += 256) {
    int c = u >> 3, aseg = (u & 7) << 3;
    bf16x8 ov;
#pragma unroll
    for (int j = 0; j < 8; j++) {
      float x = tile[aseg + j][c];
      if (applyW) x *= wrow[aseg + j];
      ov[j] = (short)f2bf(x);
    }
    *(bf16x8*)(dst + (size_t)(ct * 64 + c) * K + at * 64 + aseg) = ov;
  }
  // ---- fused stats partials: 4 threads per column, 16 a's each
  int cl = tid >> 2, part = tid & 3;
  float s = 0, ssq = 0, sw = 0;
  for (int a = part * 16; a < part * 16 + 16; ++a) {
    float x = tile[a][cl];
    s += x; ssq += x * x; sw += wrow[a] * x;
  }
  for (int d = 1; d < 4; d <<= 1) {   // 4 consecutive lanes share a column
    s += __shfl_xor(s, d); ssq += __shfl_xor(ssq, d); sw += __shfl_xor(sw, d);
  }
  if (part == 0) {
    int cbase = (z == 0) ? 0 : (z == 1) ? 64 : (z == 2) ? 128 : 324;
    size_t sidx = ((size_t)(cbase + at) * 512 + ct * 64 + cl) * 3;
    statPart[sidx] = s; statPart[sidx + 1] = ssq; statPart[sidx + 2] = sw;
  }
}

__global__ void k_statfin(const float* __restrict__ statPart, float* __restrict__ stats) {
  int m = blockIdx.x, c = threadIdx.x;
  int R = (m < 2) ? MROWS_T : MROWS_V;
  int nchunk = (m < 2) ? 64 : 196;
  int base = (m == 0) ? 0 : (m == 1) ? 64 : (m == 2) ? 128 : 324;
  float s = 0, ss = 0, sw = 0;
  for (int ch = 0; ch < nchunk; ch++) {
    size_t idx = ((size_t)(base + ch) * 512 + c) * 3;
    s += statPart[idx]; ss += statPart[idx + 1]; sw += statPart[idx + 2];
  }
  float mean = s / R;
  float var = (ss - s * mean) / (R - 1);  // ddof=1
  float rstd = 1.0f / sqrtf(var);
  stats[(m * 3 + 0) * 512 + c] = mean;
  stats[(m * 3 + 1) * 512 + c] = rstd;
  stats[(m * 3 + 2) * 512 + c] = sw;
}

// ------- MFMA weighted GEMM, 128x128 tile: Spart[z][c][d] = sum_a AT[c][a]*BT[d][a] ----
__global__ __launch_bounds__(256, 4) void k_wgemm2(
    const short* __restrict__ tTw, const short* __restrict__ mvT,
    const short* __restrict__ vTw, const short* __restrict__ mtT,
    float* __restrict__ Spart) {
  __shared__ short As[2][128 * 32];
  __shared__ short Bs[2][128 * 32];
  int c0 = blockIdx.x * 128, d0 = blockIdx.y * 128;
  int z = blockIdx.z;                 // 0..15
  int which = z >> 3, slice = z & 7;
  const short* A = which ? vTw : tTw;
  const short* B = which ? mtT : mvT;
  int K = which ? MROWS_V : MROWS_T;
  int nch = (K >> 3) >> 5;            // 49 or 16 chunks of 32
  int a0 = slice * (K >> 3);
  int tid = threadIdx.x;
  int w = tid >> 6, lane = tid & 63, lg = lane >> 4, li = lane & 15;
  int fsw = (li + (li >> 2)) & 3;

  const short* aSrc[2];
  const short* bSrc[2];
#pragma unroll
  for (int uu = 0; uu < 2; ++uu) {
    int u = uu * 256 + w * 64 + lane;
    int row = u >> 2, seg = u & 3;
    int ss = seg ^ swz4(row);
    aSrc[uu] = A + (size_t)(c0 + row) * K + a0 + ss * 8;
    bSrc[uu] = B + (size_t)(d0 + row) * K + a0 + ss * 8;
  }

  auto stage = [&](int bb) {
    short* Ad = &As[bb][0];
    short* Bd = &Bs[bb][0];
#pragma unroll
    for (int uu = 0; uu < 2; ++uu) {
      gload16(aSrc[uu], Ad + (uu * 256 + w * 64) * 8);
      aSrc[uu] += 32;
      gload16(bSrc[uu], Bd + (uu * 256 + w * 64) * 8);
      bSrc[uu] += 32;
    }
  };

  f32x4 acc[2][8];
#pragma unroll
  for (int i = 0; i < 2; ++i)
#pragma unroll
    for (int j = 0; j < 8; ++j) acc[i][j] = (f32x4){0.f, 0.f, 0.f, 0.f};

  stage(0);
  int cur = 0;
  for (int ch = 0; ch < nch; ++ch) {
    __builtin_amdgcn_s_barrier();
    if (ch < nch - 1) {
      stage(cur ^ 1);
      asm volatile("s_waitcnt vmcnt(4)" ::: "memory");
    } else {
      asm volatile("s_waitcnt vmcnt(0)" ::: "memory");
    }
    __builtin_amdgcn_s_barrier();
    const short* Ab = &As[cur][0];
    const short* Bb = &Bs[cur][0];
    bf16x8 bfr[8];
#pragma unroll
    for (int j = 0; j < 8; ++j)
      bfr[j] = *(const bf16x8*)(Bb + (j * 16 + li) * 32 + (lg ^ fsw) * 8);
    __builtin_amdgcn_s_setprio(1);
#pragma unroll
    for (int i = 0; i < 2; ++i) {
      bf16x8 afr = *(const bf16x8*)(Ab + ((w * 2 + i) * 16 + li) * 32 + (lg ^ fsw) * 8);
#pragma unroll
      for (int j = 0; j < 8; ++j)
        acc[i][j] = __builtin_amdgcn_mfma_f32_16x16x32_bf16(afr, bfr[j], acc[i][j], 0, 0, 0);
    }
    __builtin_amdgcn_s_setprio(0);
    cur ^= 1;
  }
  float* outp = Spart + (size_t)z * 512 * 512;
#pragma unroll
  for (int j = 0; j < 8; ++j) {
    int d = d0 + j * 16 + li;
#pragma unroll
    for (int i = 0; i < 2; ++i)
#pragma unroll
      for (int reg = 0; reg < 4; ++reg)
        outp[(size_t)(c0 + (w * 2 + i) * 16 + lg * 4 + reg) * 512 + d] = acc[i][j][reg];
  }
}

// ---------------- assemble c = (c1+c2)/2 from closed form; loss partials ----------
__global__ void k_assemble(const float* __restrict__ Spart, const float* __restrict__ stats,
                           float* __restrict__ lossPart) {
  int c = blockIdx.x, tid = threadIdx.x;
  float muT = stats[0 * 512 + c], rsT = stats[1 * 512 + c], swT = stats[2 * 512 + c];
  float muV = stats[6 * 512 + c], rsV = stats[7 * 512 + c], swV = stats[8 * 512 + c];
  const float W = 64.0f, invB = 1.0f / 64.0f;
  float on = 0, off = 0;
  for (int d = tid; d < 512; d += 256) {
    float s1 = 0, s2 = 0;
    for (int sl = 0; sl < 8; sl++) {
      s1 += Spart[((size_t)sl * 512 + c) * 512 + d];
      s2 += Spart[((size_t)(8 + sl) * 512 + c) * 512 + d];
    }
    float muMV = stats[3 * 512 + d], rsMV = stats[4 * 512 + d], swMV = stats[5 * 512 + d];
    float muMT = stats[9 * 512 + d], rsMT = stats[10 * 512 + d], swMT = stats[11 * 512 + d];
    float c1 = (s1 - muT * swMV - muMV * swT + muT * muMV * W) * rsT * rsMV * invB;
    float c2 = (s2 - muV * swMT - muMT * swV + muV * muMT * W) * rsV * rsMT * invB;
    float cc = 0.5f * (c1 + c2);
    if (d == c) { float dd = cc - 1.0f; on += dd * dd; }
    else off += cc * cc;
  }
  __shared__ float r1[4], r2[4];
  for (int s = 1; s < 64; s <<= 1) { on += __shfl_xor(on, s); off += __shfl_xor(off, s); }
  if ((tid & 63) == 0) { r1[tid >> 6] = on; r2[tid >> 6] = off; }
  __syncthreads();
  if (tid == 0) {
    lossPart[c * 2] = r1[0] + r1[1] + r1[2] + r1[3];
    lossPart[c * 2 + 1] = r2[0] + r2[1] + r2[2] + r2[3];
  }
}

__global__ void k_loss(const float* __restrict__ lossPart, float* __restrict__ out) {
  int tid = threadIdx.x;
  float on = 0, off = 0;
  for (int i = tid; i < 512; i += 256) { on += lossPart[2 * i]; off += lossPart[2 * i + 1]; }
  __shared__ float r1[4], r2[4];
  for (int s = 1; s < 64; s <<= 1) { on += __shfl_xor(on, s); off += __shfl_xor(off, s); }
  if ((tid & 63) == 0) { r1[tid >> 6] = on; r2[tid >> 6] = off; }
  __syncthreads();
  if (tid == 0)
    out[8192] = 0.1f * ((r1[0] + r1[1] + r1[2] + r1[3]) +
                        0.06f * (r2[0] + r2[1] + r2[2] + r2[3]));
}

extern "C" void kernel_launch(void* const* d_in, const int* in_sizes, int n_in,
                              void* d_out, int out_size, void* d_ws, size_t ws_size,
                              hipStream_t stream) {
  (void)in_sizes; (void)n_in; (void)out_size; (void)ws_size;
  const float* v_tok  = (const float*)d_in[1];
  const float* t_tok  = (const float*)d_in[3];
  const float* Wv_tok = (const float*)d_in[8];
  const float* Wt_tok = (const float*)d_in[10];
  const float* bv_tok = (const float*)d_in[9];
  const float* bt_tok = (const float*)d_in[11];
  const float* wv_fc  = (const float*)d_in[12];
  const float* bv_fc  = (const float*)d_in[13];
  const float* wt_fc  = (const float*)d_in[14];
  const float* bt_fc  = (const float*)d_in[15];
  const int*   tlen   = (const int*)d_in[16];
  float* out = (float*)d_out;

  char* wsb = (char*)d_ws;
  short* v_tok_bf = (short*)wsb;                       // 9,633,792 sh
  short* t_tok_bf = v_tok_bf + (size_t)9633792;        // 3,145,728 sh
  short* WvT      = t_tok_bf + (size_t)3145728;        //   393,216 sh
  short* WtT      = WvT + (size_t)393216;              //   393,216 sh
  short* tTw = (short*)wsb;                            // 512*4096 (alias, phase2)
  short* mvT = tTw + (size_t)2097152;                  // 512*4096
  short* vTw = mvT + (size_t)2097152;                  // 512*12544
  short* ve_bf = (short*)(wsb + 27131904);             // 6,422,528 sh
  short* te_bf = ve_bf + (size_t)6422528;              // 2,097,152 sh
  float* Spart = (float*)(wsb + 27131904);             // 16*512*512 f (alias, phase-b)
  short* mtT = (short*)(wsb + 44171264);               // 512*12544
  float* vwf = (float*)(wsb + 57016320);               // 12544
  float* twf = vwf + 12544;                            // 4096
  int* gMT = (int*)(twf + 4096);                       // 12544
  int* gMV = gMT + 12544;                              // 4096
  float* statPart = (float*)(gMV + 4096);              // 520*512*3 f (3.2 MB)
  float* stats = statPart + (size_t)520 * 512 * 3;     // 12*512
  float* lossPart = stats + 6144;                      // 1024

  k_prep<<<7008, 256, 0, stream>>>(v_tok, v_tok_bf, 1204224, t_tok, t_tok_bf, 393216,
                                   Wv_tok, Wt_tok, WvT, WtT);
  k_proj_mfma2<<<dim3(4, 130), 256, 0, stream>>>(v_tok_bf, t_tok_bf, WvT, WtT,
                                                 bv_tok, bt_tok, ve_bf, te_bf);
  k_normfc2<<<4160, 256, 0, stream>>>(ve_bf, te_bf, wv_fc, wt_fc, bv_fc, bt_fc, vwf, twf);
  k_softmax<<<128, 256, 0, stream>>>(vwf, twf, tlen);
  k_sim<<<2048, 512, 0, stream>>>(ve_bf, te_bf, vwf, twf, out, gMT, gMV);
  k_materialize<<<dim3(196, 8, 4), 256, 0, stream>>>(ve_bf, te_bf, gMT, gMV, vwf, twf,
                                                     tTw, mvT, vTw, mtT, statPart);
  k_statfin<<<4, 512, 0, stream>>>(statPart, stats);
  k_wgemm2<<<dim3(4, 4, 16), 256, 0, stream>>>(tTw, mvT, vTw, mtT, Spart);
  k_assemble<<<512, 256, 0, stream>>>(Spart, stats, lossPart);
  k_loss<<<1, 256, 0, stream>>>(lossPart, out);
}